// Round 4
// baseline (3844.040 us; speedup 1.0000x reference)
//
#include <hip/hip_runtime.h>
#include <hip/hip_bf16.h>
#include <math.h>

typedef __hip_bfloat16 bf16;
typedef _Float16 f16;
typedef _Float16 f16x2 __attribute__((ext_vector_type(2)));
typedef _Float16 f16x8 __attribute__((ext_vector_type(8)));
typedef float f32x4 __attribute__((ext_vector_type(4)));

struct Sched { int tt[5]; int fi[5]; int jj[5]; };
struct CvtF32 { const void* src[4]; float* dst[4]; int n[4]; int blk0[5]; };
struct CvtF16 { const void* src[6]; f16* dst[6]; int n[6]; int blk0[7]; };
struct W2J { const void* wd[5]; const void* wf[5]; f16* dst[5]; int mid[5]; int cin[5]; int n[5]; int blk0[6]; };

// ---------------------------------------------------------------- dtype detect
__global__ void k_detect(const unsigned int* __restrict__ w, int nwords, int* __restrict__ flag){
  __shared__ int cnt;
  if(threadIdx.x==0) cnt=0;
  __syncthreads();
  int local=0;
  for(int i=threadIdx.x;i<nwords;i+=256){
    unsigned int v=w[i];
    int e=(v>>7)&0xFF;
    if(e>=0xC0) local++;
  }
  atomicAdd(&cnt, local);
  __syncthreads();
  if(threadIdx.x==0) flag[0] = (cnt > (nwords>>3)) ? 1 : 0;
}

__device__ inline float ldmix(const void* p, size_t i, bool f32m){
  return f32m ? ((const float*)p)[i] : __bfloat162float(((const bf16*)p)[i]);
}

// ---------------------------------------------------------------- fused converts
__global__ void k_cvt_all(CvtF32 J, const int* __restrict__ flag){
  int b=blockIdx.x;
  int j=0;
  while(j<3 && J.blk0[j+1]<=b) j++;
  int i=(b-J.blk0[j])*256+threadIdx.x;
  if(i>=J.n[j]) return;
  bool f32m=*flag!=0;
  J.dst[j][i]=ldmix(J.src[j],i,f32m);
}

__global__ void k_cvth_all(CvtF16 J, const int* __restrict__ flag){
  int b=blockIdx.x;
  int j=0;
  while(j<5 && J.blk0[j+1]<=b) j++;
  int i=(b-J.blk0[j])*256+threadIdx.x;
  if(i>=J.n[j]) return;
  bool f32m=*flag!=0;
  J.dst[j][i]=(f16)ldmix(J.src[j],i,f32m);
}

__global__ void k_zero(float* __restrict__ p, int n){
  int i = blockIdx.x*256 + threadIdx.x;
  if(i<n) p[i]=0.f;
}

// W2[o, a*cin+c] = Wd[o,a]*Wf[o,c], all 5 layers in one launch
__global__ void k_w2all(W2J J, const int* __restrict__ flag){
  int b=blockIdx.x;
  int j=0;
  while(j<4 && J.blk0[j+1]<=b) j++;
  int i=(b-J.blk0[j])*256+threadIdx.x;
  if(i>=J.n[j]) return;
  int cin=J.cin[j]; int K3=3*cin;
  int o=i/K3; int rem=i-o*K3; int a=rem/cin; int c=rem-a*cin;
  float v=0.f;
  if(o<J.mid[j]){
    bool f32m=*flag!=0;
    v=ldmix(J.wd[j],(size_t)3*o+a,f32m)*ldmix(J.wf[j],(size_t)o*cin+c,f32m);
  }
  J.dst[j][i]=(f16)v;
}

// ---------------------------------------------------------------- FPS: 256 threads, DPP in-wave argmax
// Round-9: round-2 structure (proven 571us l0) with ONE change: the per-iter
// __syncthreads (s_waitcnt+s_barrier, ~150-300 cyc) is replaced by an LDS
// seq-tag spin merged with the key exchange. Protocol safety:
//  * keyS double-buffered by it&1: slot [it&1] is only overwritten at it+2,
//    and no wave reaches it+2's write before ALL waves published it+1
//    (each poll requires all 4 seq tags) -> >=1 full iteration of slack.
//  * writer orders key-write before seq-write via s_waitcnt lgkmcnt(0).
//  * readers poll volatile seqS (>= it, monotonic), then compiler memory
//    barrier, then volatile key reads.
//  * no barrier in the loop -> deadlock impossible (pure progress).
// Update loop / DPP / tree / ptsS[wi] read are byte-identical to round-2
// (round-1 lesson: touch one phase at a time; multi-assign ifs are radioactive).
template<int P>
__global__ __launch_bounds__(256) void k_fps2(
    const float* __restrict__ xyz, int L, int N, int m,
    int c0,int c1,int c2,int c3, int T, float* __restrict__ anchors)
{
  __shared__ float4 ptsS[P*256];
  __shared__ unsigned long long keyS[2][4];
  __shared__ unsigned int seqS[4];
  __shared__ float ancS[3*1024];
  int prob=blockIdx.x;
  int b=prob/T, tt=prob%T;
  int f=(tt==0)?c0:(tt==1)?c1:(tt==2)?c2:c3;
  const float* src = xyz + ((size_t)(b*L+f))*N*3;
  float* anc = anchors + ((size_t)(b*T+tt))*m*3;
  int tid=threadIdx.x;
  if(tid<4) seqS[tid]=0u;
  for(int t=tid;t<N;t+=256)
    ptsS[t]=make_float4(src[3*t],src[3*t+1],src[3*t+2],0.f);
  __syncthreads();
  float px[P],py[P],pz[P],mind[P];
#pragma unroll
  for(int j=0;j<P;j++){
    float4 v=ptsS[tid+j*256];
    px[j]=v.x; py[j]=v.y; pz[j]=v.z; mind[j]=1e10f;
  }
  float4 p0=ptsS[0];
  float lx=p0.x, ly=p0.y, lz=p0.z;
  if(tid==0){ ancS[0]=lx; ancS[1]=ly; ancS[2]=lz; }
  int w=tid>>6;
  for(int it=1; it<m; ++it){
    float bv=-1.f; int bi=0;
#pragma unroll
    for(int j=0;j<P;j++){
#pragma clang fp contract(off)
      float dx=px[j]-lx, dy=py[j]-ly, dz=pz[j]-lz;
      float d2=dx*dx+dy*dy+dz*dz;
      float mv=mind[j]; if(d2<mv) mv=d2; mind[j]=mv;
      if(mv>bv){ bv=mv; bi=tid+j*256; }
    }
    unsigned int hi=__float_as_uint(bv);
    unsigned int lo=0xFFFFFFFFu-(unsigned)bi;
#define DPPSTEP(CTRL) { \
    unsigned int shi=(unsigned)__builtin_amdgcn_update_dpp(0,(int)hi,CTRL,0xF,0xF,true); \
    unsigned int slo=(unsigned)__builtin_amdgcn_update_dpp(0,(int)lo,CTRL,0xF,0xF,true); \
    bool g=(shi>hi)||(shi==hi&&slo>lo); \
    hi=g?shi:hi; lo=g?slo:lo; }
    DPPSTEP(0x111) DPPSTEP(0x112) DPPSTEP(0x114) DPPSTEP(0x118) DPPSTEP(0x142) DPPSTEP(0x143)
#undef DPPSTEP
    if((tid&63)==63){
      keyS[it&1][w]=((unsigned long long)hi<<32)|lo;
      asm volatile("s_waitcnt lgkmcnt(0)" ::: "memory");
      seqS[w]=(unsigned int)it;
    }
    { // spin until all 4 waves published iteration it (first poll usually hits)
      volatile unsigned int* sq=(volatile unsigned int*)seqS;
      unsigned int u=(unsigned int)it;
      while(sq[0]<u || sq[1]<u || sq[2]<u || sq[3]<u){ }
      asm volatile("" ::: "memory");
    }
    volatile unsigned long long* kv=&keyS[it&1][0];
    unsigned long long k0=kv[0], k1=kv[1];
    unsigned long long k2=kv[2], k3=kv[3];
    unsigned long long ka = k0>k1?k0:k1;
    unsigned long long kb = k2>k3?k2:k3;
    unsigned long long kk = ka>kb?ka:kb;
    int wi = (int)(0xFFFFFFFFu - (unsigned)(kk & 0xFFFFFFFFull));
    float4 wc = ptsS[wi];
    lx=wc.x; ly=wc.y; lz=wc.z;
    if(tid==0){ ancS[3*it]=lx; ancS[3*it+1]=ly; ancS[3*it+2]=lz; }
  }
  __syncthreads();
  for(int t=tid;t<3*m;t+=256) anc[t]=ancS[t];
}

// ---------------------------------------------------------------- ball query, batched over all slots of a layer
__global__ __launch_bounds__(256) void k_bq(
    const float* __restrict__ Xin, const float* __restrict__ Xout,
    int* __restrict__ bqAll, int N, int m, float r2, int Lin, size_t aBS, int M, Sched S)
{
  int chunks=(m+255)>>8;
  int b=blockIdx.x/chunks;
  int a=(blockIdx.x%chunks)*256+threadIdx.x;
  int s=blockIdx.y;
  int tt=S.tt[s], fr=S.fi[s];
  const float* Pb = Xin + ((size_t)b*Lin + fr)*(size_t)N*3;
  bool act = a<m;
  float ax=0,ay=0,az=0;
  int* o = bqAll + ((size_t)s*M + (size_t)b*m + (size_t)(act?a:0))*9;
  if(act){
    const float* A=Xout+(size_t)b*aBS+(size_t)tt*m*3+(size_t)a*3;
    ax=A[0]; ay=A[1]; az=A[2];
  }
  int cnt = act?0:9, first=0;
  __shared__ float sp[768];
  for(int base=0; base<N; base+=256){
    for(int t=threadIdx.x; t<768; t+=256) sp[t]=Pb[(size_t)base*3+t];
    __syncthreads();
    for(int q=0;q<256;q++){
#pragma clang fp contract(off)
      float dx=sp[3*q]-ax, dy=sp[3*q+1]-ay, dz=sp[3*q+2]-az;
      float d2=dx*dx+dy*dy+dz*dz;
      if(d2<r2 && cnt<9){
        int p=base+q;
        if(cnt==0) first=p;
        o[cnt]=p; cnt++;
      }
    }
    if(__syncthreads_and(cnt>=9)) break;
  }
  if(act){ for(int k=cnt;k<9;k++) o[k]=first; }
}

// ---------------------------------------------------------------- layer 0 (cin=0): nf = sum_k disp_k . Wd  (batched over tt)
__global__ void k_part0(
    const float* __restrict__ Xin, const float* __restrict__ Xout,
    const int* __restrict__ bqAll, const float* __restrict__ Wd,
    f16* __restrict__ nfh, int m, int mid, int ld, int nmask,
    size_t aBS, int N, int Lin, int M, Sched S)
{
  int row = blockIdx.x;
  int tt = blockIdx.y;                      // l0: slot == tt
  int b = row/m, mm = row - b*m;
  const float* A = Xout + (size_t)b*aBS + (size_t)tt*m*3 + (size_t)mm*3;
  float ax=A[0], ay=A[1], az=A[2];
  int o = threadIdx.x;
  float w0=0,w1=0,w2=0;
  if(o<mid){ w0=Wd[3*o]; w1=Wd[3*o+1]; w2=Wd[3*o+2]; }
  int fr=S.fi[tt];
  const int* id = bqAll + ((size_t)tt*M + row)*9;
  const float* Pb = Xin + ((size_t)b*Lin+fr)*(size_t)N*3;
  float acc=0.f;
  for(int k=0;k<9;k++){
    int p=id[k] & nmask;
    const float* q = Pb + (size_t)p*3;
    float dx=q[0]-ax, dy=q[1]-ay, dz=q[2]-az;
    acc += dx*w0+dy*w1+dz*w2;
  }
  if(o<mid) nfh[(size_t)tt*M*ld + (size_t)row*ld + o] = (f16)acc;
}

// ---------------------------------------------------------------- G[r, a*cin+c] = sum_k disp[r,k,a]*fg[r,k,c]  (batched)
__global__ __launch_bounds__(256) void k_outer(
    const f16* __restrict__ feats, const float* __restrict__ Xin,
    const float* __restrict__ Xout, const int* __restrict__ bqAll,
    f16* __restrict__ Gh, int m, int cin, int N, int Lin,
    size_t aBS, int nmask, int M, Sched S)
{
  int cw2 = cin>>1; if(cw2>256) cw2=256;
  int rpb = 256/cw2;
  int tid=threadIdx.x;
  int sub=tid/cw2, lc=tid-sub*cw2;
  int r=blockIdx.x*rpb+sub;
  int Kp=3*cin;
  int s=r/M, mrow=r-s*M;
  int b=mrow/m, mm=mrow-b*m;
  int tt=S.tt[s], fr=S.fi[s];
  const float* A0=Xout+(size_t)b*aBS+(size_t)tt*m*3+(size_t)mm*3;
  float ax=A0[0],ay=A0[1],az=A0[2];
  const float* Pb=Xin+((size_t)b*Lin+fr)*(size_t)N*3;
  const f16* Fb=feats+(((size_t)b*Lin+fr)*(size_t)N)*(size_t)cin;
  const int* id=bqAll+(size_t)r*9;
  int idx[9]; float d0[9],d1[9],d2a[9];
#pragma unroll
  for(int k=0;k<9;k++){
    int p=id[k]&nmask; idx[k]=p;
    const float* q=Pb+(size_t)p*3;
    d0[k]=q[0]-ax; d1[k]=q[1]-ay; d2a[k]=q[2]-az;
  }
  f16* Gr=Gh+(size_t)r*Kp;
  for(int cc=2*lc; cc<cin; cc+=2*cw2){
    float a0=0,a1=0,a2=0,b0=0,b1=0,b2=0;
#pragma unroll
    for(int k=0;k<9;k++){
      f16x2 fv=*(const f16x2*)(Fb+(size_t)idx[k]*cin+cc);
      float f0=(float)fv[0], f1=(float)fv[1];
      a0=fmaf(d0[k],f0,a0); b0=fmaf(d0[k],f1,b0);
      a1=fmaf(d1[k],f0,a1); b1=fmaf(d1[k],f1,b1);
      a2=fmaf(d2a[k],f0,a2); b2=fmaf(d2a[k],f1,b2);
    }
    f16x2 o0={(f16)a0,(f16)b0}, o1={(f16)a1,(f16)b1}, o2={(f16)a2,(f16)b2};
    *(f16x2*)(Gr+cc)=o0; *(f16x2*)(Gr+cin+cc)=o1; *(f16x2*)(Gr+2*cin+cc)=o2;
  }
}

// ---------------------------------------------------------------- pair GEMM: nf[tt][mrow, j*mid+col] = G @ W2^T (batched)
__global__ __launch_bounds__(256) void k_pg(
    const f16* __restrict__ Gh, const f16* __restrict__ W2,
    f16* __restrict__ nfh, int Kp, int mid, int C, int M, Sched S)
{
  __shared__ f16 As[128*40];
  __shared__ f16 Bs[128*40];
  int tid=threadIdx.x;
  int lane=tid&63, w=tid>>6;
  int quad=lane>>4, l15=lane&15;
  int rowOff=(w>>1)*64, colOff=(w&1)*64;
  int rowBase=blockIdx.x*128, colBase=blockIdx.y*128;
  f32x4 acc[4][4];
#pragma unroll
  for(int i=0;i<4;i++)
#pragma unroll
    for(int j=0;j<4;j++) acc[i][j]=(f32x4){0.f,0.f,0.f,0.f};
  int nct=Kp>>5;
  int srow=tid>>1, shalf=tid&1;
  for(int ct=0;ct<nct;ct++){
    __syncthreads();
    {
      const uint4* s=(const uint4*)(Gh+(size_t)(rowBase+srow)*Kp+(ct<<5)+(shalf<<4));
      uint4 u0=s[0], u1=s[1];
      *(uint4*)(As + srow*40 + (shalf<<4))     = u0;
      *(uint4*)(As + srow*40 + (shalf<<4) + 8) = u1;
    }
    {
      const uint4* s=(const uint4*)(W2+(size_t)(colBase+srow)*Kp+(ct<<5)+(shalf<<4));
      uint4 u0=s[0], u1=s[1];
      *(uint4*)(Bs + srow*40 + (shalf<<4))     = u0;
      *(uint4*)(Bs + srow*40 + (shalf<<4) + 8) = u1;
    }
    __syncthreads();
    f16x8 af[4], bf4[4];
#pragma unroll
    for(int rt=0;rt<4;rt++) af[rt]=*(const f16x8*)(As + (rowOff+rt*16+l15)*40 + quad*8);
#pragma unroll
    for(int ctl=0;ctl<4;ctl++) bf4[ctl]=*(const f16x8*)(Bs + (colOff+ctl*16+l15)*40 + quad*8);
#pragma unroll
    for(int rt=0;rt<4;rt++)
#pragma unroll
      for(int ctl=0;ctl<4;ctl++)
        acc[rt][ctl]=__builtin_amdgcn_mfma_f32_16x16x32_f16(af[rt],bf4[ctl],acc[rt][ctl],0,0,0);
  }
#pragma unroll
  for(int rt=0;rt<4;rt++){
#pragma unroll
    for(int r=0;r<4;r++){
      int row=rowBase+rowOff+rt*16+quad*4+r;
      int s=row/M, mrow=row-s*M;
      int tt=S.tt[s], j=S.jj[s];
      f16* base = nfh + (size_t)tt*M*C + (size_t)mrow*C + j*mid;
#pragma unroll
      for(int ctl=0;ctl<4;ctl++){
        int col=colBase+colOff+ctl*16+l15;
        if(col<mid) base[col]=(f16)acc[rt][ctl][r];
      }
    }
  }
}

// ---------------------------------------------------------------- BN stats (batched over tt, jmask skips unwritten slices)
__global__ void k_bnstat(const f16* __restrict__ nfh, int M, int C, float* __restrict__ sumsL,
                         int mid, int4 jm, int sumStride){
  int c = blockIdx.x*256 + threadIdx.x;
  if(c>=C) return;
  int tt=blockIdx.z;
  int jmask = (tt==0)?jm.x:(tt==1)?jm.y:(tt==2)?jm.z:jm.w;
  int j=c/mid;
  if(!((jmask>>j)&1)) return;
  const f16* base=nfh+(size_t)tt*M*C;
  int rows = M>>5;
  int r0 = blockIdx.y*rows, r1 = r0+rows;
  float s=0.f, s2=0.f;
  for(int r=r0;r<r1;r++){
    float v=(float)base[(size_t)r*C+c];
    s+=v; s2+=v*v;
  }
  atomicAdd(&sumsL[tt*sumStride+c], s);
  atomicAdd(&sumsL[tt*sumStride+C+c], s2);
}

__global__ void k_bnfin(const float* __restrict__ sumsL, float* __restrict__ scbAll,
                        int C, int M, int mid, int4 jm, int sumStride, int scbStride){
  int c = blockIdx.x*256 + threadIdx.x;
  if(c>=C) return;
  int tt=blockIdx.y;
  int jmask = (tt==0)?jm.x:(tt==1)?jm.y:(tt==2)?jm.z:jm.w;
  float* scb=scbAll+(size_t)tt*scbStride;
  int j=c/mid;
  if(!((jmask>>j)&1)){ scb[c]=0.f; scb[C+c]=0.f; return; }
  float mean=sumsL[tt*sumStride+c]/(float)M;
  float var=sumsL[tt*sumStride+C+c]/(float)M - mean*mean;
  if(var<0.f) var=0.f;
  float rs=1.0f/sqrtf(var+1e-5f);
  scb[c]=rs; scb[C+c]=-mean*rs;
}

// ---------------------------------------------------------------- MFMA GEMM, A=f16 (opt fused BN+ReLU on A), batched over tt
template<bool RELU, bool DYN, bool BNA>
__global__ __launch_bounds__(256) void k_gemm_mfma(
    const f16* __restrict__ Ag, const f16* __restrict__ Bh,
    const float* __restrict__ bias, void* __restrict__ out,
    int K, int N, int mloc, size_t oBS, size_t ttA, size_t ttO,
    const int* __restrict__ oflag, const float* __restrict__ scbAll, int scbStride)
{
  __shared__ f16 As[128*40];
  __shared__ f16 Bs[128*40];
  int tid=threadIdx.x;
  int lane=tid&63, w=tid>>6;
  int quad=lane>>4, l15=lane&15;
  int rowOff=(w>>1)*64, colOff=(w&1)*64;
  int rowBase=blockIdx.x*128, colBase=blockIdx.y*128;
  int tt=blockIdx.z;
  const f16* A0=Ag+(size_t)tt*ttA;
  const float* scb = BNA ? (scbAll+(size_t)tt*scbStride) : nullptr;
  f32x4 acc[4][4];
#pragma unroll
  for(int i=0;i<4;i++)
#pragma unroll
    for(int j=0;j<4;j++) acc[i][j]=(f32x4){0.f,0.f,0.f,0.f};
  int nct=K>>5;
  int srow=tid>>1, shalf=tid&1;
  for(int ct=0;ct<nct;ct++){
    __syncthreads();
    {
      int c0g=(ct<<5)+(shalf<<4);
      const f16* src=A0+(size_t)(rowBase+srow)*K+c0g;
      if(BNA){
        f16x8 x0=((const f16x8*)src)[0], x1=((const f16x8*)src)[1];
        f16x8 h0,h1;
#pragma unroll
        for(int q=0;q<8;q++){
          h0[q]=(f16)fmaxf(fmaf((float)x0[q],scb[c0g+q],scb[K+c0g+q]),0.f);
          h1[q]=(f16)fmaxf(fmaf((float)x1[q],scb[c0g+8+q],scb[K+c0g+8+q]),0.f);
        }
        *(f16x8*)(As+srow*40+(shalf<<4))=h0;
        *(f16x8*)(As+srow*40+(shalf<<4)+8)=h1;
      } else {
        const uint4* s=(const uint4*)src;
        uint4 u0=s[0],u1=s[1];
        *(uint4*)(As+srow*40+(shalf<<4))=u0;
        *(uint4*)(As+srow*40+(shalf<<4)+8)=u1;
      }
    }
    {
      const uint4* s=(const uint4*)(Bh+(size_t)(colBase+srow)*K+(ct<<5)+(shalf<<4));
      uint4 u0=s[0], u1=s[1];
      *(uint4*)(Bs + srow*40 + (shalf<<4))     = u0;
      *(uint4*)(Bs + srow*40 + (shalf<<4) + 8) = u1;
    }
    __syncthreads();
    f16x8 af[4], bf4[4];
#pragma unroll
    for(int rt=0;rt<4;rt++) af[rt]=*(const f16x8*)(As + (rowOff+rt*16+l15)*40 + quad*8);
#pragma unroll
    for(int ctl=0;ctl<4;ctl++) bf4[ctl]=*(const f16x8*)(Bs + (colOff+ctl*16+l15)*40 + quad*8);
#pragma unroll
    for(int rt=0;rt<4;rt++)
#pragma unroll
      for(int ctl=0;ctl<4;ctl++)
        acc[rt][ctl]=__builtin_amdgcn_mfma_f32_16x16x32_f16(af[rt],bf4[ctl],acc[rt][ctl],0,0,0);
  }
  bool f32m = DYN ? (*oflag!=0) : true;
#pragma unroll
  for(int rt=0;rt<4;rt++){
#pragma unroll
    for(int r=0;r<4;r++){
      int row=rowBase+rowOff+rt*16+quad*4+r;
      int rb=row/mloc, rm=row-rb*mloc;
      size_t obase=(size_t)rb*oBS + (size_t)tt*ttO + (size_t)rm*N;
#pragma unroll
      for(int ctl=0;ctl<4;ctl++){
        int col=colBase+colOff+ctl*16+l15;
        float v=acc[rt][ctl][r];
        if(bias) v+=bias[col];
        if(RELU) v=fmaxf(v,0.f);
        if(DYN){
          if(!f32m) ((bf16*)out)[obase+col]=__float2bfloat16(v);
          else      ((float*)out)[obase+col]=v;
        } else {
          ((f16*)out)[obase+col]=(f16)v;
        }
      }
    }
  }
}

// ---------------------------------------------------------------- f32 GEMM (layer 0 temporal, K=45), BN fused, batched over tt
__global__ __launch_bounds__(256) void k_gemm0(
    const f16* __restrict__ nfh, const float* __restrict__ Wg,
    f16* __restrict__ out, int M, int K, int N, int mloc, size_t oBS, size_t ttO,
    const float* __restrict__ scbAll, int scbStride)
{
  __shared__ alignas(16) float As[16][64];
  __shared__ alignas(16) float Bs[16][64];
  int tid=threadIdx.x, tx=tid&15, ty=tid>>4;
  int rowBase=blockIdx.x*64, colBase=blockIdx.y*64;
  int tt=blockIdx.z;
  const f16* A0=nfh+(size_t)tt*M*K;
  const float* scb=scbAll+(size_t)tt*scbStride;
  float acc[4][4];
#pragma unroll
  for(int i=0;i<4;i++)
#pragma unroll
    for(int j=0;j<4;j++) acc[i][j]=0.f;
  int lrow=tid&63, lcq=tid>>6;
  int nct=(K+15)>>4;
  for(int ct=0;ct<nct;ct++){
    __syncthreads();
    {
      int r=rowBase+lrow, c0=(ct<<4)+(lcq<<2);
#pragma unroll
      for(int q=0;q<4;q++){
        int c=c0+q;
        As[(lcq<<2)+q][lrow] = (c<K)? fmaxf(fmaf((float)A0[(size_t)r*K+c],scb[c],scb[K+c]),0.f) : 0.f;
      }
    }
    {
      int og=colBase+lrow, c0=(ct<<4)+(lcq<<2);
#pragma unroll
      for(int q=0;q<4;q++){
        int c=c0+q;
        Bs[(lcq<<2)+q][lrow] = (c<K)? Wg[(size_t)og*K+c] : 0.f;
      }
    }
    __syncthreads();
#pragma unroll
    for(int c=0;c<16;c++){
      float4 a4=*(const float4*)&As[c][ty<<2];
      float av[4]={a4.x,a4.y,a4.z,a4.w};
      float4 b4=*(const float4*)&Bs[c][tx<<2];
      float bw[4]={b4.x,b4.y,b4.z,b4.w};
#pragma unroll
      for(int i=0;i<4;i++)
#pragma unroll
        for(int j=0;j<4;j++) acc[i][j]+=av[i]*bw[j];
    }
  }
#pragma unroll
  for(int i=0;i<4;i++){
    int r=rowBase+(ty<<2)+i;
    int rb=r/mloc, rm=r-rb*mloc;
    size_t obase=(size_t)rb*oBS + (size_t)blockIdx.z*ttO + (size_t)rm*N;
#pragma unroll
    for(int j=0;j<4;j++){
      int o=colBase+(tx<<2)+j;
      out[obase+o]=(f16)fmaxf(acc[i][j],0.f);
    }
  }
}

// ---------------------------------------------------------------- host
extern "C" void kernel_launch(void* const* d_in, const int* in_sizes, int n_in,
                              void* d_out, int out_size, void* d_ws, size_t ws_size,
                              hipStream_t stream) {
  (void)in_sizes; (void)n_in; (void)out_size; (void)ws_size;

  const int di[6] = {2,4,7,10,13,16};
  const int fi6[6] = {-1,5,8,11,14,17};
  const int ti[6] = {3,6,9,12,15,18};

  const int midv[6]={45,96,192,384,768,1536};
  const int midp[6]={0,128,256,384,768,1536};
  const int cinv[6]={0,64,128,256,512,1024};
  const int coutv[6]={64,128,256,512,1024,2048};
  const int tkv[6]={1,3,3,3,3,1};
  const int Nv[6]={2048,1024,512,512,256,256};
  const int mv[6]={1024,512,512,256,256,128};
  const int Lv[6]={4,4,2,2,1,1};
  const int Tv[6]={4,2,2,1,1,1};
  const float rrv[6]={1.5f,3.f,3.f,6.f,6.f,6.f};

  float* ws=(float*)d_ws;
  size_t off=0;
  auto A=[&](size_t n)->float*{ float* p=ws+off; off+=(n+63)&~(size_t)63; return p; };
  auto Ah=[&](size_t n)->f16*{ return (f16*)A((n+1)/2); };

  int* flag=(int*)A(64);

  f16* W2h[6]; W2h[0]=nullptr;
  for(int l=1;l<6;l++) W2h[l]=Ah((size_t)midp[l]*3*cinv[l]);
  f16* Wth[6]; Wth[0]=nullptr;
  for(int l=1;l<6;l++) Wth[l]=Ah((size_t)coutv[l]*tkv[l]*midv[l]);
  float* Wd0=A(135);
  float* Wt0=A(2880);
  f16* fcwh=Ah(2097152);
  float* fcb=A(1024);

  float* X[7];
  X[0]=A(786432);
  for(int l=0;l<6;l++) X[l+1]=A((size_t)32*Tv[l]*mv[l]*3);

  f16* FA=Ah(8388608);
  f16* FB=Ah(8388608);
  f16* F[7]; F[0]=nullptr;
  for(int l=0;l<6;l++) F[l+1]=(l%2==0)?FA:FB;

  f16* nfh=Ah(18874368);           // max T*M*C (l2/l4: 18.87M)
  float* sumsAll=A(11*4608);
  float* scbAll=A(4*4608);
  f16* Gh=Ah(25165824);            // max SLOTS*M*Kp (l2: 25.2M)
  int* bqAll=(int*)A(1179648);     // max SLOTS*M*9 (l0: 1.18M)

  // ---- setup: detect + converts + W2 + zero sums (5 dispatches)
  k_detect<<<dim3(1),dim3(256),0,stream>>>((const unsigned int*)d_in[0], 4096, flag);
  {
    CvtF32 J;
    J.src[0]=d_in[0];  J.dst[0]=X[0];  J.n[0]=786432;
    J.src[1]=d_in[3];  J.dst[1]=Wt0;   J.n[1]=2880;
    J.src[2]=d_in[20]; J.dst[2]=fcb;   J.n[2]=1024;
    J.src[3]=d_in[2];  J.dst[3]=Wd0;   J.n[3]=135;
    J.blk0[0]=0; J.blk0[1]=3072; J.blk0[2]=3084; J.blk0[3]=3088; J.blk0[4]=3089;
    k_cvt_all<<<dim3(3089),dim3(256),0,stream>>>(J,flag);
  }
  {
    CvtF16 J;
    int ns[6]={36864,147456,589824,2359296,3145728,2097152};
    const void* ss[6]={d_in[ti[1]],d_in[ti[2]],d_in[ti[3]],d_in[ti[4]],d_in[ti[5]],d_in[19]};
    f16* ds[6]={Wth[1],Wth[2],Wth[3],Wth[4],Wth[5],fcwh};
    int bp=0;
    for(int j2=0;j2<6;j2++){ J.src[j2]=ss[j2]; J.dst[j2]=ds[j2]; J.n[j2]=ns[j2]; J.blk0[j2]=bp; bp+=(ns[j2]+255)/256; }
    J.blk0[6]=bp;
    k_cvth_all<<<dim3((unsigned)bp),dim3(256),0,stream>>>(J,flag);
  }
  {
    W2J J;
    int bp=0;
    for(int l=1;l<6;l++){
      int j2=l-1;
      J.wd[j2]=d_in[di[l]]; J.wf[j2]=d_in[fi6[l]]; J.dst[j2]=W2h[l];
      J.mid[j2]=midv[l]; J.cin[j2]=cinv[l]; J.n[j2]=midp[l]*3*cinv[l];
      J.blk0[j2]=bp; bp+=(J.n[j2]+255)/256;
    }
    J.blk0[5]=bp;
    k_w2all<<<dim3((unsigned)bp),dim3(256),0,stream>>>(J,flag);
  }
  k_zero<<<dim3((11*4608+255)/256),256,0,stream>>>(sumsAll,11*4608);

  // ---- schedule tables
  const int SLOTS[6]={4,5,4,2,1,1};
  const int sTT[6][5]={{0,1,2,3,0},{0,0,1,1,1},{0,0,1,1,0},{0,0,0,0,0},{0,0,0,0,0},{0,0,0,0,0}};
  const int sFI[6][5]={{0,1,2,3,0},{0,1,1,2,3},{0,1,0,1,0},{0,1,0,0,0},{0,0,0,0,0},{0,0,0,0,0}};
  const int sJJ[6][5]={{0,0,0,0,0},{1,2,0,1,2},{1,2,0,1,0},{1,2,0,0,0},{1,0,0,0,0},{0,0,0,0,0}};
  const int4 jm4[6]={{1,1,1,1},{6,7,0,0},{6,3,0,0},{6,0,0,0},{2,0,0,0},{1,0,0,0}};
  const int Tcenters[6][4]={{0,1,2,3},{0,2,0,0},{0,1,0,0},{0,0,0,0},{0,0,0,0},{0,0,0,0}};
  const int slotBase[6]={0,4,6,8,9,10};

  for(int l=0;l<6;l++){
    int N=Nv[l], m=mv[l], Lin=Lv[l], T=Tv[l], cin=cinv[l], mid=midv[l];
    int C=tkv[l]*midv[l], M=32*m, cout=coutv[l];
    float r2=rrv[l]*rrv[l];
    const float* Xin=X[l]; float* Xout=X[l+1];

    { // FPS
      dim3 g(32*T), blk(256);
      int a0=Tcenters[l][0],a1=Tcenters[l][1],a2=Tcenters[l][2],a3=Tcenters[l][3];
      if(N==2048)      k_fps2<8><<<g,blk,0,stream>>>(Xin,Lin,N,m,a0,a1,a2,a3,T,Xout);
      else if(N==1024) k_fps2<4><<<g,blk,0,stream>>>(Xin,Lin,N,m,a0,a1,a2,a3,T,Xout);
      else if(N==512)  k_fps2<2><<<g,blk,0,stream>>>(Xin,Lin,N,m,a0,a1,a2,a3,T,Xout);
      else             k_fps2<1><<<g,blk,0,stream>>>(Xin,Lin,N,m,a0,a1,a2,a3,T,Xout);
    }

    Sched S;
    for(int s=0;s<5;s++){ S.tt[s]=sTT[l][s]; S.fi[s]=sFI[l][s]; S.jj[s]=sJJ[l][s]; }
    size_t aBS=(size_t)T*m*3;
    int chunks=(m+255)>>8;

    k_bq<<<dim3(32*chunks,SLOTS[l]),256,0,stream>>>(Xin,Xout,bqAll,N,m,r2,Lin,aBS,M,S);

    if(l==0){
      k_part0<<<dim3(M,4),64,0,stream>>>(Xin,Xout,bqAll,Wd0,nfh,m,mid,C,N-1,aBS,N,Lin,M,S);
    } else {
      int cw2=cin>>1; if(cw2>256) cw2=256;
      int rpb=256/cw2;
      k_outer<<<dim3((unsigned)(SLOTS[l]*M/rpb)),256,0,stream>>>(
          F[l],Xin,Xout,bqAll,Gh,m,cin,N,Lin,aBS,N-1,M,S);
      k_pg<<<dim3((unsigned)(SLOTS[l]*M/128),(unsigned)(midp[l]/128)),256,0,stream>>>(
          Gh,W2h[l],nfh,3*cin,mid,C,M,S);
    }

    float* sumsL=sumsAll+(size_t)slotBase[l]*4608;
    k_bnstat<<<dim3((C+255)/256,32,T),256,0,stream>>>(nfh,M,C,sumsL,mid,jm4[l],4608);
    k_bnfin<<<dim3((C+255)/256,T),256,0,stream>>>(sumsL,scbAll,C,M,mid,jm4[l],4608,4608);

    size_t oBS=(size_t)T*m*cout;
    size_t ttO=(size_t)m*cout;
    if(l==0)
      k_gemm0<<<dim3(M/64,1,4),256,0,stream>>>(nfh,Wt0,F[1],M,C,cout,m,oBS,ttO,scbAll,4608);
    else if(l<5)
      k_gemm_mfma<true,false,true><<<dim3(M/128,cout/128,T),256,0,stream>>>(
          nfh,Wth[l],nullptr,F[l+1],C,cout,m,oBS,(size_t)M*C,ttO,nullptr,scbAll,4608);
    else
      k_gemm_mfma<false,false,true><<<dim3(M/128,cout/128,T),256,0,stream>>>(
          nfh,Wth[l],nullptr,F[l+1],C,cout,m,oBS,(size_t)M*C,ttO,nullptr,scbAll,4608);
  }

  // final FC (A=F[6] f16, contiguous 4096x2048) -> d_out (bf16 or f32 per flag)
  k_gemm_mfma<false,true,false><<<dim3(4096/128,1024/128,1),256,0,stream>>>(
      F[6],fcwh,fcb,d_out,2048,1024,128,(size_t)128*1024,0,0,flag,nullptr,0);
}

// Round 6
// 3243.535 us; speedup vs baseline: 1.1851x; 1.1851x over previous
//
#include <hip/hip_runtime.h>
#include <hip/hip_bf16.h>
#include <math.h>

typedef __hip_bfloat16 bf16;
typedef _Float16 f16;
typedef _Float16 f16x2 __attribute__((ext_vector_type(2)));
typedef _Float16 f16x8 __attribute__((ext_vector_type(8)));
typedef float f32x4 __attribute__((ext_vector_type(4)));

struct Sched { int tt[5]; int fi[5]; int jj[5]; };
struct CvtF32 { const void* src[4]; float* dst[4]; int n[4]; int blk0[5]; };
struct CvtF16 { const void* src[6]; f16* dst[6]; int n[6]; int blk0[7]; };
struct W2J { const void* wd[5]; const void* wf[5]; f16* dst[5]; int mid[5]; int cin[5]; int n[5]; int blk0[6]; };

// ---------------------------------------------------------------- dtype detect + zero sums (fused, saves a launch)
__global__ void k_detect(const unsigned int* __restrict__ w, int nwords, int* __restrict__ flag,
                         float* __restrict__ zp, int zn){
  if(blockIdx.x==0){
    __shared__ int cnt;
    if(threadIdx.x==0) cnt=0;
    __syncthreads();
    int local=0;
    for(int i=threadIdx.x;i<nwords;i+=256){
      unsigned int v=w[i];
      int e=(v>>7)&0xFF;
      if(e>=0xC0) local++;
    }
    atomicAdd(&cnt, local);
    __syncthreads();
    if(threadIdx.x==0) flag[0] = (cnt > (nwords>>3)) ? 1 : 0;
  } else {
    int i=(blockIdx.x-1)*256+threadIdx.x;
    if(i<zn) zp[i]=0.f;
  }
}

__device__ inline float ldmix(const void* p, size_t i, bool f32m){
  return f32m ? ((const float*)p)[i] : __bfloat162float(((const bf16*)p)[i]);
}

// ---------------------------------------------------------------- fused converts
__global__ void k_cvt_all(CvtF32 J, const int* __restrict__ flag){
  int b=blockIdx.x;
  int j=0;
  while(j<3 && J.blk0[j+1]<=b) j++;
  int i=(b-J.blk0[j])*256+threadIdx.x;
  if(i>=J.n[j]) return;
  bool f32m=*flag!=0;
  J.dst[j][i]=ldmix(J.src[j],i,f32m);
}

__global__ void k_cvth_all(CvtF16 J, const int* __restrict__ flag){
  int b=blockIdx.x;
  int j=0;
  while(j<5 && J.blk0[j+1]<=b) j++;
  int i=(b-J.blk0[j])*256+threadIdx.x;
  if(i>=J.n[j]) return;
  bool f32m=*flag!=0;
  J.dst[j][i]=(f16)ldmix(J.src[j],i,f32m);
}

// W2[o, a*cin+c] = Wd[o,a]*Wf[o,c], all 5 layers in one launch
__global__ void k_w2all(W2J J, const int* __restrict__ flag){
  int b=blockIdx.x;
  int j=0;
  while(j<4 && J.blk0[j+1]<=b) j++;
  int i=(b-J.blk0[j])*256+threadIdx.x;
  if(i>=J.n[j]) return;
  int cin=J.cin[j]; int K3=3*cin;
  int o=i/K3; int rem=i-o*K3; int a=rem/cin; int c=rem-a*cin;
  float v=0.f;
  if(o<J.mid[j]){
    bool f32m=*flag!=0;
    v=ldmix(J.wd[j],(size_t)3*o+a,f32m)*ldmix(J.wf[j],(size_t)o*cin+c,f32m);
  }
  J.dst[j][i]=(f16)v;
}

// ---------------------------------------------------------------- FPS: 256 threads, DPP in-wave argmax (round-2 proven, 571us l0)
// FPS floor established empirically (rounds 1/3/4): coord-carry DPP +38%,
// 1-wave no-barrier +61%, LDS spin sync +50%. The 4-wave barrier structure is
// the floor: the barrier's cost is genuine wave re-sync (waves drift via
// memory-latency variance), and no cheaper cross-wave path exists. DO NOT
// touch the inner loop.
template<int P>
__global__ __launch_bounds__(256) void k_fps2(
    const float* __restrict__ xyz, int L, int N, int m,
    int c0,int c1,int c2,int c3, int T, float* __restrict__ anchors)
{
  __shared__ float4 ptsS[P*256];
  __shared__ unsigned long long keyS[2][4];
  __shared__ float ancS[3*1024];
  int prob=blockIdx.x;
  int b=prob/T, tt=prob%T;
  int f=(tt==0)?c0:(tt==1)?c1:(tt==2)?c2:c3;
  const float* src = xyz + ((size_t)(b*L+f))*N*3;
  float* anc = anchors + ((size_t)(b*T+tt))*m*3;
  int tid=threadIdx.x;
  for(int t=tid;t<N;t+=256)
    ptsS[t]=make_float4(src[3*t],src[3*t+1],src[3*t+2],0.f);
  __syncthreads();
  float px[P],py[P],pz[P],mind[P];
#pragma unroll
  for(int j=0;j<P;j++){
    float4 v=ptsS[tid+j*256];
    px[j]=v.x; py[j]=v.y; pz[j]=v.z; mind[j]=1e10f;
  }
  float4 p0=ptsS[0];
  float lx=p0.x, ly=p0.y, lz=p0.z;
  if(tid==0){ ancS[0]=lx; ancS[1]=ly; ancS[2]=lz; }
  int w=tid>>6;
  for(int it=1; it<m; ++it){
    float bv=-1.f; int bi=0;
#pragma unroll
    for(int j=0;j<P;j++){
#pragma clang fp contract(off)
      float dx=px[j]-lx, dy=py[j]-ly, dz=pz[j]-lz;
      float d2=dx*dx+dy*dy+dz*dz;
      float mv=mind[j]; if(d2<mv) mv=d2; mind[j]=mv;
      if(mv>bv){ bv=mv; bi=tid+j*256; }
    }
    unsigned int hi=__float_as_uint(bv);
    unsigned int lo=0xFFFFFFFFu-(unsigned)bi;
#define DPPSTEP(CTRL) { \
    unsigned int shi=(unsigned)__builtin_amdgcn_update_dpp(0,(int)hi,CTRL,0xF,0xF,true); \
    unsigned int slo=(unsigned)__builtin_amdgcn_update_dpp(0,(int)lo,CTRL,0xF,0xF,true); \
    bool g=(shi>hi)||(shi==hi&&slo>lo); \
    hi=g?shi:hi; lo=g?slo:lo; }
    DPPSTEP(0x111) DPPSTEP(0x112) DPPSTEP(0x114) DPPSTEP(0x118) DPPSTEP(0x142) DPPSTEP(0x143)
#undef DPPSTEP
    if((tid&63)==63)
      keyS[it&1][w]=((unsigned long long)hi<<32)|lo;
    __syncthreads();
    unsigned long long k0=keyS[it&1][0], k1=keyS[it&1][1];
    unsigned long long k2=keyS[it&1][2], k3=keyS[it&1][3];
    unsigned long long ka = k0>k1?k0:k1;
    unsigned long long kb = k2>k3?k2:k3;
    unsigned long long kk = ka>kb?ka:kb;
    int wi = (int)(0xFFFFFFFFu - (unsigned)(kk & 0xFFFFFFFFull));
    float4 wc = ptsS[wi];
    lx=wc.x; ly=wc.y; lz=wc.z;
    if(tid==0){ ancS[3*it]=lx; ancS[3*it+1]=ly; ancS[3*it+2]=lz; }
  }
  __syncthreads();
  for(int t=tid;t<3*m;t+=256) anc[t]=ancS[t];
}

// ---------------------------------------------------------------- ball query, batched over all slots of a layer
// Round-11: per-thread early break once 9 neighbors found (first-9 semantics
// preserved exactly; also spares the inactive pad threads the full scan).
// fp-contract pragma wrapped in a nested block (round-10 compile fix).
__global__ __launch_bounds__(256) void k_bq(
    const float* __restrict__ Xin, const float* __restrict__ Xout,
    int* __restrict__ bqAll, int N, int m, float r2, int Lin, size_t aBS, int M, Sched S)
{
  int chunks=(m+255)>>8;
  int b=blockIdx.x/chunks;
  int a=(blockIdx.x%chunks)*256+threadIdx.x;
  int s=blockIdx.y;
  int tt=S.tt[s], fr=S.fi[s];
  const float* Pb = Xin + ((size_t)b*Lin + fr)*(size_t)N*3;
  bool act = a<m;
  float ax=0,ay=0,az=0;
  int* o = bqAll + ((size_t)s*M + (size_t)b*m + (size_t)(act?a:0))*9;
  if(act){
    const float* A=Xout+(size_t)b*aBS+(size_t)tt*m*3+(size_t)a*3;
    ax=A[0]; ay=A[1]; az=A[2];
  }
  int cnt = act?0:9, first=0;
  __shared__ float sp[768];
  for(int base=0; base<N; base+=256){
    for(int t=threadIdx.x; t<768; t+=256) sp[t]=Pb[(size_t)base*3+t];
    __syncthreads();
    for(int q=0;q<256;q++){
      if(cnt>=9) break;
      {
#pragma clang fp contract(off)
        float dx=sp[3*q]-ax, dy=sp[3*q+1]-ay, dz=sp[3*q+2]-az;
        float d2=dx*dx+dy*dy+dz*dz;
        if(d2<r2){
          int p=base+q;
          if(cnt==0) first=p;
          o[cnt]=p; cnt++;
        }
      }
    }
    if(__syncthreads_and(cnt>=9)) break;
  }
  if(act){ for(int k=cnt;k<9;k++) o[k]=first; }
}

// ---------------------------------------------------------------- layer 0 (cin=0): nf = sum_k disp_k . Wd  (batched over tt)
// Round-11: repacked 4 rows per 256-thread block (was 1 row per 64-thread
// block): identical loads/stores per row, 4x fewer dispatched blocks.
__global__ __launch_bounds__(256) void k_part0(
    const float* __restrict__ Xin, const float* __restrict__ Xout,
    const int* __restrict__ bqAll, const float* __restrict__ Wd,
    f16* __restrict__ nfh, int m, int mid, int ld, int nmask,
    size_t aBS, int N, int Lin, int M, Sched S)
{
  int sub = threadIdx.x>>6;
  int o = threadIdx.x&63;
  int row = blockIdx.x*4 + sub;
  int tt = blockIdx.y;                      // l0: slot == tt
  int b = row/m, mm = row - b*m;
  const float* A = Xout + (size_t)b*aBS + (size_t)tt*m*3 + (size_t)mm*3;
  float ax=A[0], ay=A[1], az=A[2];
  float w0=0,w1=0,w2=0;
  if(o<mid){ w0=Wd[3*o]; w1=Wd[3*o+1]; w2=Wd[3*o+2]; }
  int fr=S.fi[tt];
  const int* id = bqAll + ((size_t)tt*M + row)*9;
  const float* Pb = Xin + ((size_t)b*Lin+fr)*(size_t)N*3;
  float acc=0.f;
  for(int k=0;k<9;k++){
    int p=id[k] & nmask;
    const float* q = Pb + (size_t)p*3;
    float dx=q[0]-ax, dy=q[1]-ay, dz=q[2]-az;
    acc += dx*w0+dy*w1+dz*w2;
  }
  if(o<mid) nfh[(size_t)tt*M*ld + (size_t)row*ld + o] = (f16)acc;
}

// ---------------------------------------------------------------- G[r, a*cin+c] = sum_k disp[r,k,a]*fg[r,k,c]  (batched)
__global__ __launch_bounds__(256) void k_outer(
    const f16* __restrict__ feats, const float* __restrict__ Xin,
    const float* __restrict__ Xout, const int* __restrict__ bqAll,
    f16* __restrict__ Gh, int m, int cin, int N, int Lin,
    size_t aBS, int nmask, int M, Sched S)
{
  int cw2 = cin>>1; if(cw2>256) cw2=256;
  int rpb = 256/cw2;
  int tid=threadIdx.x;
  int sub=tid/cw2, lc=tid-sub*cw2;
  int r=blockIdx.x*rpb+sub;
  int Kp=3*cin;
  int s=r/M, mrow=r-s*M;
  int b=mrow/m, mm=mrow-b*m;
  int tt=S.tt[s], fr=S.fi[s];
  const float* A0=Xout+(size_t)b*aBS+(size_t)tt*m*3+(size_t)mm*3;
  float ax=A0[0],ay=A0[1],az=A0[2];
  const float* Pb=Xin+((size_t)b*Lin+fr)*(size_t)N*3;
  const f16* Fb=feats+(((size_t)b*Lin+fr)*(size_t)N)*(size_t)cin;
  const int* id=bqAll+(size_t)r*9;
  int idx[9]; float d0[9],d1[9],d2a[9];
#pragma unroll
  for(int k=0;k<9;k++){
    int p=id[k]&nmask; idx[k]=p;
    const float* q=Pb+(size_t)p*3;
    d0[k]=q[0]-ax; d1[k]=q[1]-ay; d2a[k]=q[2]-az;
  }
  f16* Gr=Gh+(size_t)r*Kp;
  for(int cc=2*lc; cc<cin; cc+=2*cw2){
    float a0=0,a1=0,a2=0,b0=0,b1=0,b2=0;
#pragma unroll
    for(int k=0;k<9;k++){
      f16x2 fv=*(const f16x2*)(Fb+(size_t)idx[k]*cin+cc);
      float f0=(float)fv[0], f1=(float)fv[1];
      a0=fmaf(d0[k],f0,a0); b0=fmaf(d0[k],f1,b0);
      a1=fmaf(d1[k],f0,a1); b1=fmaf(d1[k],f1,b1);
      a2=fmaf(d2a[k],f0,a2); b2=fmaf(d2a[k],f1,b2);
    }
    f16x2 o0={(f16)a0,(f16)b0}, o1={(f16)a1,(f16)b1}, o2={(f16)a2,(f16)b2};
    *(f16x2*)(Gr+cc)=o0; *(f16x2*)(Gr+cin+cc)=o1; *(f16x2*)(Gr+2*cin+cc)=o2;
  }
}

// ---------------------------------------------------------------- pair GEMM: nf[tt][mrow, j*mid+col] = G @ W2^T (batched)
__global__ __launch_bounds__(256) void k_pg(
    const f16* __restrict__ Gh, const f16* __restrict__ W2,
    f16* __restrict__ nfh, int Kp, int mid, int C, int M, Sched S)
{
  __shared__ f16 As[128*40];
  __shared__ f16 Bs[128*40];
  int tid=threadIdx.x;
  int lane=tid&63, w=tid>>6;
  int quad=lane>>4, l15=lane&15;
  int rowOff=(w>>1)*64, colOff=(w&1)*64;
  int rowBase=blockIdx.x*128, colBase=blockIdx.y*128;
  f32x4 acc[4][4];
#pragma unroll
  for(int i=0;i<4;i++)
#pragma unroll
    for(int j=0;j<4;j++) acc[i][j]=(f32x4){0.f,0.f,0.f,0.f};
  int nct=Kp>>5;
  int srow=tid>>1, shalf=tid&1;
  for(int ct=0;ct<nct;ct++){
    __syncthreads();
    {
      const uint4* s=(const uint4*)(Gh+(size_t)(rowBase+srow)*Kp+(ct<<5)+(shalf<<4));
      uint4 u0=s[0], u1=s[1];
      *(uint4*)(As + srow*40 + (shalf<<4))     = u0;
      *(uint4*)(As + srow*40 + (shalf<<4) + 8) = u1;
    }
    {
      const uint4* s=(const uint4*)(W2+(size_t)(colBase+srow)*Kp+(ct<<5)+(shalf<<4));
      uint4 u0=s[0], u1=s[1];
      *(uint4*)(Bs + srow*40 + (shalf<<4))     = u0;
      *(uint4*)(Bs + srow*40 + (shalf<<4) + 8) = u1;
    }
    __syncthreads();
    f16x8 af[4], bf4[4];
#pragma unroll
    for(int rt=0;rt<4;rt++) af[rt]=*(const f16x8*)(As + (rowOff+rt*16+l15)*40 + quad*8);
#pragma unroll
    for(int ctl=0;ctl<4;ctl++) bf4[ctl]=*(const f16x8*)(Bs + (colOff+ctl*16+l15)*40 + quad*8);
#pragma unroll
    for(int rt=0;rt<4;rt++)
#pragma unroll
      for(int ctl=0;ctl<4;ctl++)
        acc[rt][ctl]=__builtin_amdgcn_mfma_f32_16x16x32_f16(af[rt],bf4[ctl],acc[rt][ctl],0,0,0);
  }
#pragma unroll
  for(int rt=0;rt<4;rt++){
#pragma unroll
    for(int r=0;r<4;r++){
      int row=rowBase+rowOff+rt*16+quad*4+r;
      int s=row/M, mrow=row-s*M;
      int tt=S.tt[s], j=S.jj[s];
      f16* base = nfh + (size_t)tt*M*C + (size_t)mrow*C + j*mid;
#pragma unroll
      for(int ctl=0;ctl<4;ctl++){
        int col=colBase+colOff+ctl*16+l15;
        if(col<mid) base[col]=(f16)acc[rt][ctl][r];
      }
    }
  }
}

// ---------------------------------------------------------------- BN stats (batched over tt, jmask skips unwritten slices)
__global__ void k_bnstat(const f16* __restrict__ nfh, int M, int C, float* __restrict__ sumsL,
                         int mid, int4 jm, int sumStride){
  int c = blockIdx.x*256 + threadIdx.x;
  if(c>=C) return;
  int tt=blockIdx.z;
  int jmask = (tt==0)?jm.x:(tt==1)?jm.y:(tt==2)?jm.z:jm.w;
  int j=c/mid;
  if(!((jmask>>j)&1)) return;
  const f16* base=nfh+(size_t)tt*M*C;
  int rows = M>>5;
  int r0 = blockIdx.y*rows, r1 = r0+rows;
  float s=0.f, s2=0.f;
  for(int r=r0;r<r1;r++){
    float v=(float)base[(size_t)r*C+c];
    s+=v; s2+=v*v;
  }
  atomicAdd(&sumsL[tt*sumStride+c], s);
  atomicAdd(&sumsL[tt*sumStride+C+c], s2);
}

__global__ void k_bnfin(const float* __restrict__ sumsL, float* __restrict__ scbAll,
                        int C, int M, int mid, int4 jm, int sumStride, int scbStride){
  int c = blockIdx.x*256 + threadIdx.x;
  if(c>=C) return;
  int tt=blockIdx.y;
  int jmask = (tt==0)?jm.x:(tt==1)?jm.y:(tt==2)?jm.z:jm.w;
  float* scb=scbAll+(size_t)tt*scbStride;
  int j=c/mid;
  if(!((jmask>>j)&1)){ scb[c]=0.f; scb[C+c]=0.f; return; }
  float mean=sumsL[tt*sumStride+c]/(float)M;
  float var=sumsL[tt*sumStride+C+c]/(float)M - mean*mean;
  if(var<0.f) var=0.f;
  float rs=1.0f/sqrtf(var+1e-5f);
  scb[c]=rs; scb[C+c]=-mean*rs;
}

// ---------------------------------------------------------------- MFMA GEMM, A=f16 (opt fused BN+ReLU on A), batched over tt
template<bool RELU, bool DYN, bool BNA>
__global__ __launch_bounds__(256) void k_gemm_mfma(
    const f16* __restrict__ Ag, const f16* __restrict__ Bh,
    const float* __restrict__ bias, void* __restrict__ out,
    int K, int N, int mloc, size_t oBS, size_t ttA, size_t ttO,
    const int* __restrict__ oflag, const float* __restrict__ scbAll, int scbStride)
{
  __shared__ f16 As[128*40];
  __shared__ f16 Bs[128*40];
  int tid=threadIdx.x;
  int lane=tid&63, w=tid>>6;
  int quad=lane>>4, l15=lane&15;
  int rowOff=(w>>1)*64, colOff=(w&1)*64;
  int rowBase=blockIdx.x*128, colBase=blockIdx.y*128;
  int tt=blockIdx.z;
  const f16* A0=Ag+(size_t)tt*ttA;
  const float* scb = BNA ? (scbAll+(size_t)tt*scbStride) : nullptr;
  f32x4 acc[4][4];
#pragma unroll
  for(int i=0;i<4;i++)
#pragma unroll
    for(int j=0;j<4;j++) acc[i][j]=(f32x4){0.f,0.f,0.f,0.f};
  int nct=K>>5;
  int srow=tid>>1, shalf=tid&1;
  for(int ct=0;ct<nct;ct++){
    __syncthreads();
    {
      int c0g=(ct<<5)+(shalf<<4);
      const f16* src=A0+(size_t)(rowBase+srow)*K+c0g;
      if(BNA){
        f16x8 x0=((const f16x8*)src)[0], x1=((const f16x8*)src)[1];
        f16x8 h0,h1;
#pragma unroll
        for(int q=0;q<8;q++){
          h0[q]=(f16)fmaxf(fmaf((float)x0[q],scb[c0g+q],scb[K+c0g+q]),0.f);
          h1[q]=(f16)fmaxf(fmaf((float)x1[q],scb[c0g+8+q],scb[K+c0g+8+q]),0.f);
        }
        *(f16x8*)(As+srow*40+(shalf<<4))=h0;
        *(f16x8*)(As+srow*40+(shalf<<4)+8)=h1;
      } else {
        const uint4* s=(const uint4*)src;
        uint4 u0=s[0],u1=s[1];
        *(uint4*)(As+srow*40+(shalf<<4))=u0;
        *(uint4*)(As+srow*40+(shalf<<4)+8)=u1;
      }
    }
    {
      const uint4* s=(const uint4*)(Bh+(size_t)(colBase+srow)*K+(ct<<5)+(shalf<<4));
      uint4 u0=s[0], u1=s[1];
      *(uint4*)(Bs + srow*40 + (shalf<<4))     = u0;
      *(uint4*)(Bs + srow*40 + (shalf<<4) + 8) = u1;
    }
    __syncthreads();
    f16x8 af[4], bf4[4];
#pragma unroll
    for(int rt=0;rt<4;rt++) af[rt]=*(const f16x8*)(As + (rowOff+rt*16+l15)*40 + quad*8);
#pragma unroll
    for(int ctl=0;ctl<4;ctl++) bf4[ctl]=*(const f16x8*)(Bs + (colOff+ctl*16+l15)*40 + quad*8);
#pragma unroll
    for(int rt=0;rt<4;rt++)
#pragma unroll
      for(int ctl=0;ctl<4;ctl++)
        acc[rt][ctl]=__builtin_amdgcn_mfma_f32_16x16x32_f16(af[rt],bf4[ctl],acc[rt][ctl],0,0,0);
  }
  bool f32m = DYN ? (*oflag!=0) : true;
#pragma unroll
  for(int rt=0;rt<4;rt++){
#pragma unroll
    for(int r=0;r<4;r++){
      int row=rowBase+rowOff+rt*16+quad*4+r;
      int rb=row/mloc, rm=row-rb*mloc;
      size_t obase=(size_t)rb*oBS + (size_t)tt*ttO + (size_t)rm*N;
#pragma unroll
      for(int ctl=0;ctl<4;ctl++){
        int col=colBase+colOff+ctl*16+l15;
        float v=acc[rt][ctl][r];
        if(bias) v+=bias[col];
        if(RELU) v=fmaxf(v,0.f);
        if(DYN){
          if(!f32m) ((bf16*)out)[obase+col]=__float2bfloat16(v);
          else      ((float*)out)[obase+col]=v;
        } else {
          ((f16*)out)[obase+col]=(f16)v;
        }
      }
    }
  }
}

// ---------------------------------------------------------------- f32 GEMM (layer 0 temporal, K=45), BN fused, batched over tt
__global__ __launch_bounds__(256) void k_gemm0(
    const f16* __restrict__ nfh, const float* __restrict__ Wg,
    f16* __restrict__ out, int M, int K, int N, int mloc, size_t oBS, size_t ttO,
    const float* __restrict__ scbAll, int scbStride)
{
  __shared__ alignas(16) float As[16][64];
  __shared__ alignas(16) float Bs[16][64];
  int tid=threadIdx.x, tx=tid&15, ty=tid>>4;
  int rowBase=blockIdx.x*64, colBase=blockIdx.y*64;
  int tt=blockIdx.z;
  const f16* A0=nfh+(size_t)tt*M*K;
  const float* scb=scbAll+(size_t)tt*scbStride;
  float acc[4][4];
#pragma unroll
  for(int i=0;i<4;i++)
#pragma unroll
    for(int j=0;j<4;j++) acc[i][j]=0.f;
  int lrow=tid&63, lcq=tid>>6;
  int nct=(K+15)>>4;
  for(int ct=0;ct<nct;ct++){
    __syncthreads();
    {
      int r=rowBase+lrow, c0=(ct<<4)+(lcq<<2);
#pragma unroll
      for(int q=0;q<4;q++){
        int c=c0+q;
        As[(lcq<<2)+q][lrow] = (c<K)? fmaxf(fmaf((float)A0[(size_t)r*K+c],scb[c],scb[K+c]),0.f) : 0.f;
      }
    }
    {
      int og=colBase+lrow, c0=(ct<<4)+(lcq<<2);
#pragma unroll
      for(int q=0;q<4;q++){
        int c=c0+q;
        Bs[(lcq<<2)+q][lrow] = (c<K)? Wg[(size_t)og*K+c] : 0.f;
      }
    }
    __syncthreads();
#pragma unroll
    for(int c=0;c<16;c++){
      float4 a4=*(const float4*)&As[c][ty<<2];
      float av[4]={a4.x,a4.y,a4.z,a4.w};
      float4 b4=*(const float4*)&Bs[c][tx<<2];
      float bw[4]={b4.x,b4.y,b4.z,b4.w};
#pragma unroll
      for(int i=0;i<4;i++)
#pragma unroll
        for(int j=0;j<4;j++) acc[i][j]+=av[i]*bw[j];
    }
  }
#pragma unroll
  for(int i=0;i<4;i++){
    int r=rowBase+(ty<<2)+i;
    int rb=r/mloc, rm=r-rb*mloc;
    size_t obase=(size_t)rb*oBS + (size_t)blockIdx.z*ttO + (size_t)rm*N;
#pragma unroll
    for(int j=0;j<4;j++){
      int o=colBase+(tx<<2)+j;
      out[obase+o]=(f16)fmaxf(acc[i][j],0.f);
    }
  }
}

// ---------------------------------------------------------------- host
extern "C" void kernel_launch(void* const* d_in, const int* in_sizes, int n_in,
                              void* d_out, int out_size, void* d_ws, size_t ws_size,
                              hipStream_t stream) {
  (void)in_sizes; (void)n_in; (void)out_size; (void)ws_size;

  const int di[6] = {2,4,7,10,13,16};
  const int fi6[6] = {-1,5,8,11,14,17};
  const int ti[6] = {3,6,9,12,15,18};

  const int midv[6]={45,96,192,384,768,1536};
  const int midp[6]={0,128,256,384,768,1536};
  const int cinv[6]={0,64,128,256,512,1024};
  const int coutv[6]={64,128,256,512,1024,2048};
  const int tkv[6]={1,3,3,3,3,1};
  const int Nv[6]={2048,1024,512,512,256,256};
  const int mv[6]={1024,512,512,256,256,128};
  const int Lv[6]={4,4,2,2,1,1};
  const int Tv[6]={4,2,2,1,1,1};
  const float rrv[6]={1.5f,3.f,3.f,6.f,6.f,6.f};

  float* ws=(float*)d_ws;
  size_t off=0;
  auto A=[&](size_t n)->float*{ float* p=ws+off; off+=(n+63)&~(size_t)63; return p; };
  auto Ah=[&](size_t n)->f16*{ return (f16*)A((n+1)/2); };

  int* flag=(int*)A(64);

  f16* W2h[6]; W2h[0]=nullptr;
  for(int l=1;l<6;l++) W2h[l]=Ah((size_t)midp[l]*3*cinv[l]);
  f16* Wth[6]; Wth[0]=nullptr;
  for(int l=1;l<6;l++) Wth[l]=Ah((size_t)coutv[l]*tkv[l]*midv[l]);
  float* Wd0=A(135);
  float* Wt0=A(2880);
  f16* fcwh=Ah(2097152);
  float* fcb=A(1024);

  float* X[7];
  X[0]=A(786432);
  for(int l=0;l<6;l++) X[l+1]=A((size_t)32*Tv[l]*mv[l]*3);

  f16* FA=Ah(8388608);
  f16* FB=Ah(8388608);
  f16* F[7]; F[0]=nullptr;
  for(int l=0;l<6;l++) F[l+1]=(l%2==0)?FA:FB;

  f16* nfh=Ah(18874368);           // max T*M*C (l2/l4: 18.87M)
  float* sumsAll=A(11*4608);
  float* scbAll=A(4*4608);
  f16* Gh=Ah(25165824);            // max SLOTS*M*Kp (l2: 25.2M)
  int* bqAll=(int*)A(1179648);     // max SLOTS*M*9 (l0: 1.18M)

  // ---- setup: detect+zero (fused) + converts + W2 (4 dispatches)
  {
    int zn=11*4608;
    int zb=(zn+255)/256;
    k_detect<<<dim3(1+zb),dim3(256),0,stream>>>((const unsigned int*)d_in[0], 4096, flag, sumsAll, zn);
  }
  {
    CvtF32 J;
    J.src[0]=d_in[0];  J.dst[0]=X[0];  J.n[0]=786432;
    J.src[1]=d_in[3];  J.dst[1]=Wt0;   J.n[1]=2880;
    J.src[2]=d_in[20]; J.dst[2]=fcb;   J.n[2]=1024;
    J.src[3]=d_in[2];  J.dst[3]=Wd0;   J.n[3]=135;
    J.blk0[0]=0; J.blk0[1]=3072; J.blk0[2]=3084; J.blk0[3]=3088; J.blk0[4]=3089;
    k_cvt_all<<<dim3(3089),dim3(256),0,stream>>>(J,flag);
  }
  {
    CvtF16 J;
    int ns[6]={36864,147456,589824,2359296,3145728,2097152};
    const void* ss[6]={d_in[ti[1]],d_in[ti[2]],d_in[ti[3]],d_in[ti[4]],d_in[ti[5]],d_in[19]};
    f16* ds[6]={Wth[1],Wth[2],Wth[3],Wth[4],Wth[5],fcwh};
    int bp=0;
    for(int j2=0;j2<6;j2++){ J.src[j2]=ss[j2]; J.dst[j2]=ds[j2]; J.n[j2]=ns[j2]; J.blk0[j2]=bp; bp+=(ns[j2]+255)/256; }
    J.blk0[6]=bp;
    k_cvth_all<<<dim3((unsigned)bp),dim3(256),0,stream>>>(J,flag);
  }
  {
    W2J J;
    int bp=0;
    for(int l=1;l<6;l++){
      int j2=l-1;
      J.wd[j2]=d_in[di[l]]; J.wf[j2]=d_in[fi6[l]]; J.dst[j2]=W2h[l];
      J.mid[j2]=midv[l]; J.cin[j2]=cinv[l]; J.n[j2]=midp[l]*3*cinv[l];
      J.blk0[j2]=bp; bp+=(J.n[j2]+255)/256;
    }
    J.blk0[5]=bp;
    k_w2all<<<dim3((unsigned)bp),dim3(256),0,stream>>>(J,flag);
  }

  // ---- schedule tables
  const int SLOTS[6]={4,5,4,2,1,1};
  const int sTT[6][5]={{0,1,2,3,0},{0,0,1,1,1},{0,0,1,1,0},{0,0,0,0,0},{0,0,0,0,0},{0,0,0,0,0}};
  const int sFI[6][5]={{0,1,2,3,0},{0,1,1,2,3},{0,1,0,1,0},{0,1,0,0,0},{0,0,0,0,0},{0,0,0,0,0}};
  const int sJJ[6][5]={{0,0,0,0,0},{1,2,0,1,2},{1,2,0,1,0},{1,2,0,0,0},{1,0,0,0,0},{0,0,0,0,0}};
  const int4 jm4[6]={{1,1,1,1},{6,7,0,0},{6,3,0,0},{6,0,0,0},{2,0,0,0},{1,0,0,0}};
  const int Tcenters[6][4]={{0,1,2,3},{0,2,0,0},{0,1,0,0},{0,0,0,0},{0,0,0,0},{0,0,0,0}};
  const int slotBase[6]={0,4,6,8,9,10};

  for(int l=0;l<6;l++){
    int N=Nv[l], m=mv[l], Lin=Lv[l], T=Tv[l], cin=cinv[l], mid=midv[l];
    int C=tkv[l]*midv[l], M=32*m, cout=coutv[l];
    float r2=rrv[l]*rrv[l];
    const float* Xin=X[l]; float* Xout=X[l+1];

    { // FPS
      dim3 g(32*T), blk(256);
      int a0=Tcenters[l][0],a1=Tcenters[l][1],a2=Tcenters[l][2],a3=Tcenters[l][3];
      if(N==2048)      k_fps2<8><<<g,blk,0,stream>>>(Xin,Lin,N,m,a0,a1,a2,a3,T,Xout);
      else if(N==1024) k_fps2<4><<<g,blk,0,stream>>>(Xin,Lin,N,m,a0,a1,a2,a3,T,Xout);
      else if(N==512)  k_fps2<2><<<g,blk,0,stream>>>(Xin,Lin,N,m,a0,a1,a2,a3,T,Xout);
      else             k_fps2<1><<<g,blk,0,stream>>>(Xin,Lin,N,m,a0,a1,a2,a3,T,Xout);
    }

    Sched S;
    for(int s=0;s<5;s++){ S.tt[s]=sTT[l][s]; S.fi[s]=sFI[l][s]; S.jj[s]=sJJ[l][s]; }
    size_t aBS=(size_t)T*m*3;
    int chunks=(m+255)>>8;

    k_bq<<<dim3(32*chunks,SLOTS[l]),256,0,stream>>>(Xin,Xout,bqAll,N,m,r2,Lin,aBS,M,S);

    if(l==0){
      k_part0<<<dim3(M/4,4),256,0,stream>>>(Xin,Xout,bqAll,Wd0,nfh,m,mid,C,N-1,aBS,N,Lin,M,S);
    } else {
      int cw2=cin>>1; if(cw2>256) cw2=256;
      int rpb=256/cw2;
      k_outer<<<dim3((unsigned)(SLOTS[l]*M/rpb)),256,0,stream>>>(
          F[l],Xin,Xout,bqAll,Gh,m,cin,N,Lin,aBS,N-1,M,S);
      k_pg<<<dim3((unsigned)(SLOTS[l]*M/128),(unsigned)(midp[l]/128)),256,0,stream>>>(
          Gh,W2h[l],nfh,3*cin,mid,C,M,S);
    }

    float* sumsL=sumsAll+(size_t)slotBase[l]*4608;
    k_bnstat<<<dim3((C+255)/256,32,T),256,0,stream>>>(nfh,M,C,sumsL,mid,jm4[l],4608);
    k_bnfin<<<dim3((C+255)/256,T),256,0,stream>>>(sumsL,scbAll,C,M,mid,jm4[l],4608,4608);

    size_t oBS=(size_t)T*m*cout;
    size_t ttO=(size_t)m*cout;
    if(l==0)
      k_gemm0<<<dim3(M/64,1,4),256,0,stream>>>(nfh,Wt0,F[1],M,C,cout,m,oBS,ttO,scbAll,4608);
    else if(l<5)
      k_gemm_mfma<true,false,true><<<dim3(M/128,cout/128,T),256,0,stream>>>(
          nfh,Wth[l],nullptr,F[l+1],C,cout,m,oBS,(size_t)M*C,ttO,nullptr,scbAll,4608);
    else
      k_gemm_mfma<false,false,true><<<dim3(M/128,cout/128,T),256,0,stream>>>(
          nfh,Wth[l],nullptr,F[l+1],C,cout,m,oBS,(size_t)M*C,ttO,nullptr,scbAll,4608);
  }

  // final FC (A=F[6] f16, contiguous 4096x2048) -> d_out (bf16 or f32 per flag)
  k_gemm_mfma<false,true,false><<<dim3(4096/128,1024/128,1),256,0,stream>>>(
      F[6],fcwh,fcb,d_out,2048,1024,128,(size_t)128*1024,0,0,flag,nullptr,0);
}

// Round 7
// 3175.149 us; speedup vs baseline: 1.2107x; 1.0215x over previous
//
#include <hip/hip_runtime.h>
#include <hip/hip_bf16.h>
#include <math.h>

typedef __hip_bfloat16 bf16;
typedef _Float16 f16;
typedef _Float16 f16x2 __attribute__((ext_vector_type(2)));
typedef _Float16 f16x8 __attribute__((ext_vector_type(8)));
typedef float f32x4 __attribute__((ext_vector_type(4)));

struct Sched { int tt[5]; int fi[5]; int jj[5]; };
struct CvtF32 { const void* src[4]; float* dst[4]; int n[4]; int blk0[5]; };
struct CvtF16 { const void* src[6]; f16* dst[6]; int n[6]; int blk0[7]; };
struct W2J { const void* wd[5]; const void* wf[5]; f16* dst[5]; int mid[5]; int cin[5]; int n[5]; int blk0[6]; };

// ---------------------------------------------------------------- dtype detect + zero sums (fused, saves a launch)
__global__ void k_detect(const unsigned int* __restrict__ w, int nwords, int* __restrict__ flag,
                         float* __restrict__ zp, int zn){
  if(blockIdx.x==0){
    __shared__ int cnt;
    if(threadIdx.x==0) cnt=0;
    __syncthreads();
    int local=0;
    for(int i=threadIdx.x;i<nwords;i+=256){
      unsigned int v=w[i];
      int e=(v>>7)&0xFF;
      if(e>=0xC0) local++;
    }
    atomicAdd(&cnt, local);
    __syncthreads();
    if(threadIdx.x==0) flag[0] = (cnt > (nwords>>3)) ? 1 : 0;
  } else {
    int i=(blockIdx.x-1)*256+threadIdx.x;
    if(i<zn) zp[i]=0.f;
  }
}

__device__ inline float ldmix(const void* p, size_t i, bool f32m){
  return f32m ? ((const float*)p)[i] : __bfloat162float(((const bf16*)p)[i]);
}

// ---------------------------------------------------------------- fused converts
__global__ void k_cvt_all(CvtF32 J, const int* __restrict__ flag){
  int b=blockIdx.x;
  int j=0;
  while(j<3 && J.blk0[j+1]<=b) j++;
  int i=(b-J.blk0[j])*256+threadIdx.x;
  if(i>=J.n[j]) return;
  bool f32m=*flag!=0;
  J.dst[j][i]=ldmix(J.src[j],i,f32m);
}

__global__ void k_cvth_all(CvtF16 J, const int* __restrict__ flag){
  int b=blockIdx.x;
  int j=0;
  while(j<5 && J.blk0[j+1]<=b) j++;
  int i=(b-J.blk0[j])*256+threadIdx.x;
  if(i>=J.n[j]) return;
  bool f32m=*flag!=0;
  J.dst[j][i]=(f16)ldmix(J.src[j],i,f32m);
}

// W2[o, a*cin+c] = Wd[o,a]*Wf[o,c], all 5 layers in one launch
__global__ void k_w2all(W2J J, const int* __restrict__ flag){
  int b=blockIdx.x;
  int j=0;
  while(j<4 && J.blk0[j+1]<=b) j++;
  int i=(b-J.blk0[j])*256+threadIdx.x;
  if(i>=J.n[j]) return;
  int cin=J.cin[j]; int K3=3*cin;
  int o=i/K3; int rem=i-o*K3; int a=rem/cin; int c=rem-a*cin;
  float v=0.f;
  if(o<J.mid[j]){
    bool f32m=*flag!=0;
    v=ldmix(J.wd[j],(size_t)3*o+a,f32m)*ldmix(J.wf[j],(size_t)o*cin+c,f32m);
  }
  J.dst[j][i]=(f16)v;
}

// ---------------------------------------------------------------- FPS: 256 threads, DPP in-wave argmax (round-2 proven, 571us l0)
// FPS floor established empirically (rounds 1/3/4): coord-carry DPP +38%,
// 1-wave no-barrier +61%, LDS spin sync +50%. The 4-wave barrier structure is
// the floor: the barrier's cost is genuine wave re-sync (waves drift via
// memory-latency variance), and no cheaper cross-wave path exists. DO NOT
// touch the inner loop.
template<int P>
__global__ __launch_bounds__(256) void k_fps2(
    const float* __restrict__ xyz, int L, int N, int m,
    int c0,int c1,int c2,int c3, int T, float* __restrict__ anchors)
{
  __shared__ float4 ptsS[P*256];
  __shared__ unsigned long long keyS[2][4];
  __shared__ float ancS[3*1024];
  int prob=blockIdx.x;
  int b=prob/T, tt=prob%T;
  int f=(tt==0)?c0:(tt==1)?c1:(tt==2)?c2:c3;
  const float* src = xyz + ((size_t)(b*L+f))*N*3;
  float* anc = anchors + ((size_t)(b*T+tt))*m*3;
  int tid=threadIdx.x;
  for(int t=tid;t<N;t+=256)
    ptsS[t]=make_float4(src[3*t],src[3*t+1],src[3*t+2],0.f);
  __syncthreads();
  float px[P],py[P],pz[P],mind[P];
#pragma unroll
  for(int j=0;j<P;j++){
    float4 v=ptsS[tid+j*256];
    px[j]=v.x; py[j]=v.y; pz[j]=v.z; mind[j]=1e10f;
  }
  float4 p0=ptsS[0];
  float lx=p0.x, ly=p0.y, lz=p0.z;
  if(tid==0){ ancS[0]=lx; ancS[1]=ly; ancS[2]=lz; }
  int w=tid>>6;
  for(int it=1; it<m; ++it){
    float bv=-1.f; int bi=0;
#pragma unroll
    for(int j=0;j<P;j++){
#pragma clang fp contract(off)
      float dx=px[j]-lx, dy=py[j]-ly, dz=pz[j]-lz;
      float d2=dx*dx+dy*dy+dz*dz;
      float mv=mind[j]; if(d2<mv) mv=d2; mind[j]=mv;
      if(mv>bv){ bv=mv; bi=tid+j*256; }
    }
    unsigned int hi=__float_as_uint(bv);
    unsigned int lo=0xFFFFFFFFu-(unsigned)bi;
#define DPPSTEP(CTRL) { \
    unsigned int shi=(unsigned)__builtin_amdgcn_update_dpp(0,(int)hi,CTRL,0xF,0xF,true); \
    unsigned int slo=(unsigned)__builtin_amdgcn_update_dpp(0,(int)lo,CTRL,0xF,0xF,true); \
    bool g=(shi>hi)||(shi==hi&&slo>lo); \
    hi=g?shi:hi; lo=g?slo:lo; }
    DPPSTEP(0x111) DPPSTEP(0x112) DPPSTEP(0x114) DPPSTEP(0x118) DPPSTEP(0x142) DPPSTEP(0x143)
#undef DPPSTEP
    if((tid&63)==63)
      keyS[it&1][w]=((unsigned long long)hi<<32)|lo;
    __syncthreads();
    unsigned long long k0=keyS[it&1][0], k1=keyS[it&1][1];
    unsigned long long k2=keyS[it&1][2], k3=keyS[it&1][3];
    unsigned long long ka = k0>k1?k0:k1;
    unsigned long long kb = k2>k3?k2:k3;
    unsigned long long kk = ka>kb?ka:kb;
    int wi = (int)(0xFFFFFFFFu - (unsigned)(kk & 0xFFFFFFFFull));
    float4 wc = ptsS[wi];
    lx=wc.x; ly=wc.y; lz=wc.z;
    if(tid==0){ ancS[3*it]=lx; ancS[3*it+1]=ly; ancS[3*it+2]=lz; }
  }
  __syncthreads();
  for(int t=tid;t<3*m;t+=256) anc[t]=ancS[t];
}

// ---------------------------------------------------------------- ball query, batched over all slots of a layer
// Round-12: reverted to round-2 predicated inner loop (no early break).
// Round-6's per-iteration `break` regressed ~90us total: it turned a fully
// unrolled predicated 256-candidate scan into a loop-carried branch.
// Predication beats control flow here -- the break only skipped VALU work.
__global__ __launch_bounds__(256) void k_bq(
    const float* __restrict__ Xin, const float* __restrict__ Xout,
    int* __restrict__ bqAll, int N, int m, float r2, int Lin, size_t aBS, int M, Sched S)
{
  int chunks=(m+255)>>8;
  int b=blockIdx.x/chunks;
  int a=(blockIdx.x%chunks)*256+threadIdx.x;
  int s=blockIdx.y;
  int tt=S.tt[s], fr=S.fi[s];
  const float* Pb = Xin + ((size_t)b*Lin + fr)*(size_t)N*3;
  bool act = a<m;
  float ax=0,ay=0,az=0;
  int* o = bqAll + ((size_t)s*M + (size_t)b*m + (size_t)(act?a:0))*9;
  if(act){
    const float* A=Xout+(size_t)b*aBS+(size_t)tt*m*3+(size_t)a*3;
    ax=A[0]; ay=A[1]; az=A[2];
  }
  int cnt = act?0:9, first=0;
  __shared__ float sp[768];
  for(int base=0; base<N; base+=256){
    for(int t=threadIdx.x; t<768; t+=256) sp[t]=Pb[(size_t)base*3+t];
    __syncthreads();
    for(int q=0;q<256;q++){
#pragma clang fp contract(off)
      float dx=sp[3*q]-ax, dy=sp[3*q+1]-ay, dz=sp[3*q+2]-az;
      float d2=dx*dx+dy*dy+dz*dz;
      if(d2<r2 && cnt<9){
        int p=base+q;
        if(cnt==0) first=p;
        o[cnt]=p; cnt++;
      }
    }
    if(__syncthreads_and(cnt>=9)) break;
  }
  if(act){ for(int k=cnt;k<9;k++) o[k]=first; }
}

// ---------------------------------------------------------------- layer 0 (cin=0): nf = sum_k disp_k . Wd  (batched over tt)
// Round-11: repacked 4 rows per 256-thread block (was 1 row per 64-thread
// block): identical loads/stores per row, 4x fewer dispatched blocks.
__global__ __launch_bounds__(256) void k_part0(
    const float* __restrict__ Xin, const float* __restrict__ Xout,
    const int* __restrict__ bqAll, const float* __restrict__ Wd,
    f16* __restrict__ nfh, int m, int mid, int ld, int nmask,
    size_t aBS, int N, int Lin, int M, Sched S)
{
  int sub = threadIdx.x>>6;
  int o = threadIdx.x&63;
  int row = blockIdx.x*4 + sub;
  int tt = blockIdx.y;                      // l0: slot == tt
  int b = row/m, mm = row - b*m;
  const float* A = Xout + (size_t)b*aBS + (size_t)tt*m*3 + (size_t)mm*3;
  float ax=A[0], ay=A[1], az=A[2];
  float w0=0,w1=0,w2=0;
  if(o<mid){ w0=Wd[3*o]; w1=Wd[3*o+1]; w2=Wd[3*o+2]; }
  int fr=S.fi[tt];
  const int* id = bqAll + ((size_t)tt*M + row)*9;
  const float* Pb = Xin + ((size_t)b*Lin+fr)*(size_t)N*3;
  float acc=0.f;
  for(int k=0;k<9;k++){
    int p=id[k] & nmask;
    const float* q = Pb + (size_t)p*3;
    float dx=q[0]-ax, dy=q[1]-ay, dz=q[2]-az;
    acc += dx*w0+dy*w1+dz*w2;
  }
  if(o<mid) nfh[(size_t)tt*M*ld + (size_t)row*ld + o] = (f16)acc;
}

// ---------------------------------------------------------------- G[r, a*cin+c] = sum_k disp[r,k,a]*fg[r,k,c]  (batched)
__global__ __launch_bounds__(256) void k_outer(
    const f16* __restrict__ feats, const float* __restrict__ Xin,
    const float* __restrict__ Xout, const int* __restrict__ bqAll,
    f16* __restrict__ Gh, int m, int cin, int N, int Lin,
    size_t aBS, int nmask, int M, Sched S)
{
  int cw2 = cin>>1; if(cw2>256) cw2=256;
  int rpb = 256/cw2;
  int tid=threadIdx.x;
  int sub=tid/cw2, lc=tid-sub*cw2;
  int r=blockIdx.x*rpb+sub;
  int Kp=3*cin;
  int s=r/M, mrow=r-s*M;
  int b=mrow/m, mm=mrow-b*m;
  int tt=S.tt[s], fr=S.fi[s];
  const float* A0=Xout+(size_t)b*aBS+(size_t)tt*m*3+(size_t)mm*3;
  float ax=A0[0],ay=A0[1],az=A0[2];
  const float* Pb=Xin+((size_t)b*Lin+fr)*(size_t)N*3;
  const f16* Fb=feats+(((size_t)b*Lin+fr)*(size_t)N)*(size_t)cin;
  const int* id=bqAll+(size_t)r*9;
  int idx[9]; float d0[9],d1[9],d2a[9];
#pragma unroll
  for(int k=0;k<9;k++){
    int p=id[k]&nmask; idx[k]=p;
    const float* q=Pb+(size_t)p*3;
    d0[k]=q[0]-ax; d1[k]=q[1]-ay; d2a[k]=q[2]-az;
  }
  f16* Gr=Gh+(size_t)r*Kp;
  for(int cc=2*lc; cc<cin; cc+=2*cw2){
    float a0=0,a1=0,a2=0,b0=0,b1=0,b2=0;
#pragma unroll
    for(int k=0;k<9;k++){
      f16x2 fv=*(const f16x2*)(Fb+(size_t)idx[k]*cin+cc);
      float f0=(float)fv[0], f1=(float)fv[1];
      a0=fmaf(d0[k],f0,a0); b0=fmaf(d0[k],f1,b0);
      a1=fmaf(d1[k],f0,a1); b1=fmaf(d1[k],f1,b1);
      a2=fmaf(d2a[k],f0,a2); b2=fmaf(d2a[k],f1,b2);
    }
    f16x2 o0={(f16)a0,(f16)b0}, o1={(f16)a1,(f16)b1}, o2={(f16)a2,(f16)b2};
    *(f16x2*)(Gr+cc)=o0; *(f16x2*)(Gr+cin+cc)=o1; *(f16x2*)(Gr+2*cin+cc)=o2;
  }
}

// ---------------------------------------------------------------- pair GEMM: nf[tt][mrow, j*mid+col] = G @ W2^T (batched)
__global__ __launch_bounds__(256) void k_pg(
    const f16* __restrict__ Gh, const f16* __restrict__ W2,
    f16* __restrict__ nfh, int Kp, int mid, int C, int M, Sched S)
{
  __shared__ f16 As[128*40];
  __shared__ f16 Bs[128*40];
  int tid=threadIdx.x;
  int lane=tid&63, w=tid>>6;
  int quad=lane>>4, l15=lane&15;
  int rowOff=(w>>1)*64, colOff=(w&1)*64;
  int rowBase=blockIdx.x*128, colBase=blockIdx.y*128;
  f32x4 acc[4][4];
#pragma unroll
  for(int i=0;i<4;i++)
#pragma unroll
    for(int j=0;j<4;j++) acc[i][j]=(f32x4){0.f,0.f,0.f,0.f};
  int nct=Kp>>5;
  int srow=tid>>1, shalf=tid&1;
  for(int ct=0;ct<nct;ct++){
    __syncthreads();
    {
      const uint4* s=(const uint4*)(Gh+(size_t)(rowBase+srow)*Kp+(ct<<5)+(shalf<<4));
      uint4 u0=s[0], u1=s[1];
      *(uint4*)(As + srow*40 + (shalf<<4))     = u0;
      *(uint4*)(As + srow*40 + (shalf<<4) + 8) = u1;
    }
    {
      const uint4* s=(const uint4*)(W2+(size_t)(colBase+srow)*Kp+(ct<<5)+(shalf<<4));
      uint4 u0=s[0], u1=s[1];
      *(uint4*)(Bs + srow*40 + (shalf<<4))     = u0;
      *(uint4*)(Bs + srow*40 + (shalf<<4) + 8) = u1;
    }
    __syncthreads();
    f16x8 af[4], bf4[4];
#pragma unroll
    for(int rt=0;rt<4;rt++) af[rt]=*(const f16x8*)(As + (rowOff+rt*16+l15)*40 + quad*8);
#pragma unroll
    for(int ctl=0;ctl<4;ctl++) bf4[ctl]=*(const f16x8*)(Bs + (colOff+ctl*16+l15)*40 + quad*8);
#pragma unroll
    for(int rt=0;rt<4;rt++)
#pragma unroll
      for(int ctl=0;ctl<4;ctl++)
        acc[rt][ctl]=__builtin_amdgcn_mfma_f32_16x16x32_f16(af[rt],bf4[ctl],acc[rt][ctl],0,0,0);
  }
#pragma unroll
  for(int rt=0;rt<4;rt++){
#pragma unroll
    for(int r=0;r<4;r++){
      int row=rowBase+rowOff+rt*16+quad*4+r;
      int s=row/M, mrow=row-s*M;
      int tt=S.tt[s], j=S.jj[s];
      f16* base = nfh + (size_t)tt*M*C + (size_t)mrow*C + j*mid;
#pragma unroll
      for(int ctl=0;ctl<4;ctl++){
        int col=colBase+colOff+ctl*16+l15;
        if(col<mid) base[col]=(f16)acc[rt][ctl][r];
      }
    }
  }
}

// ---------------------------------------------------------------- BN stats (batched over tt, jmask skips unwritten slices)
__global__ void k_bnstat(const f16* __restrict__ nfh, int M, int C, float* __restrict__ sumsL,
                         int mid, int4 jm, int sumStride){
  int c = blockIdx.x*256 + threadIdx.x;
  if(c>=C) return;
  int tt=blockIdx.z;
  int jmask = (tt==0)?jm.x:(tt==1)?jm.y:(tt==2)?jm.z:jm.w;
  int j=c/mid;
  if(!((jmask>>j)&1)) return;
  const f16* base=nfh+(size_t)tt*M*C;
  int rows = M>>5;
  int r0 = blockIdx.y*rows, r1 = r0+rows;
  float s=0.f, s2=0.f;
  for(int r=r0;r<r1;r++){
    float v=(float)base[(size_t)r*C+c];
    s+=v; s2+=v*v;
  }
  atomicAdd(&sumsL[tt*sumStride+c], s);
  atomicAdd(&sumsL[tt*sumStride+C+c], s2);
}

__global__ void k_bnfin(const float* __restrict__ sumsL, float* __restrict__ scbAll,
                        int C, int M, int mid, int4 jm, int sumStride, int scbStride){
  int c = blockIdx.x*256 + threadIdx.x;
  if(c>=C) return;
  int tt=blockIdx.y;
  int jmask = (tt==0)?jm.x:(tt==1)?jm.y:(tt==2)?jm.z:jm.w;
  float* scb=scbAll+(size_t)tt*scbStride;
  int j=c/mid;
  if(!((jmask>>j)&1)){ scb[c]=0.f; scb[C+c]=0.f; return; }
  float mean=sumsL[tt*sumStride+c]/(float)M;
  float var=sumsL[tt*sumStride+C+c]/(float)M - mean*mean;
  if(var<0.f) var=0.f;
  float rs=1.0f/sqrtf(var+1e-5f);
  scb[c]=rs; scb[C+c]=-mean*rs;
}

// ---------------------------------------------------------------- MFMA GEMM, A=f16 (opt fused BN+ReLU on A), batched over tt
template<bool RELU, bool DYN, bool BNA>
__global__ __launch_bounds__(256) void k_gemm_mfma(
    const f16* __restrict__ Ag, const f16* __restrict__ Bh,
    const float* __restrict__ bias, void* __restrict__ out,
    int K, int N, int mloc, size_t oBS, size_t ttA, size_t ttO,
    const int* __restrict__ oflag, const float* __restrict__ scbAll, int scbStride)
{
  __shared__ f16 As[128*40];
  __shared__ f16 Bs[128*40];
  int tid=threadIdx.x;
  int lane=tid&63, w=tid>>6;
  int quad=lane>>4, l15=lane&15;
  int rowOff=(w>>1)*64, colOff=(w&1)*64;
  int rowBase=blockIdx.x*128, colBase=blockIdx.y*128;
  int tt=blockIdx.z;
  const f16* A0=Ag+(size_t)tt*ttA;
  const float* scb = BNA ? (scbAll+(size_t)tt*scbStride) : nullptr;
  f32x4 acc[4][4];
#pragma unroll
  for(int i=0;i<4;i++)
#pragma unroll
    for(int j=0;j<4;j++) acc[i][j]=(f32x4){0.f,0.f,0.f,0.f};
  int nct=K>>5;
  int srow=tid>>1, shalf=tid&1;
  for(int ct=0;ct<nct;ct++){
    __syncthreads();
    {
      int c0g=(ct<<5)+(shalf<<4);
      const f16* src=A0+(size_t)(rowBase+srow)*K+c0g;
      if(BNA){
        f16x8 x0=((const f16x8*)src)[0], x1=((const f16x8*)src)[1];
        f16x8 h0,h1;
#pragma unroll
        for(int q=0;q<8;q++){
          h0[q]=(f16)fmaxf(fmaf((float)x0[q],scb[c0g+q],scb[K+c0g+q]),0.f);
          h1[q]=(f16)fmaxf(fmaf((float)x1[q],scb[c0g+8+q],scb[K+c0g+8+q]),0.f);
        }
        *(f16x8*)(As+srow*40+(shalf<<4))=h0;
        *(f16x8*)(As+srow*40+(shalf<<4)+8)=h1;
      } else {
        const uint4* s=(const uint4*)src;
        uint4 u0=s[0],u1=s[1];
        *(uint4*)(As+srow*40+(shalf<<4))=u0;
        *(uint4*)(As+srow*40+(shalf<<4)+8)=u1;
      }
    }
    {
      const uint4* s=(const uint4*)(Bh+(size_t)(colBase+srow)*K+(ct<<5)+(shalf<<4));
      uint4 u0=s[0], u1=s[1];
      *(uint4*)(Bs + srow*40 + (shalf<<4))     = u0;
      *(uint4*)(Bs + srow*40 + (shalf<<4) + 8) = u1;
    }
    __syncthreads();
    f16x8 af[4], bf4[4];
#pragma unroll
    for(int rt=0;rt<4;rt++) af[rt]=*(const f16x8*)(As + (rowOff+rt*16+l15)*40 + quad*8);
#pragma unroll
    for(int ctl=0;ctl<4;ctl++) bf4[ctl]=*(const f16x8*)(Bs + (colOff+ctl*16+l15)*40 + quad*8);
#pragma unroll
    for(int rt=0;rt<4;rt++)
#pragma unroll
      for(int ctl=0;ctl<4;ctl++)
        acc[rt][ctl]=__builtin_amdgcn_mfma_f32_16x16x32_f16(af[rt],bf4[ctl],acc[rt][ctl],0,0,0);
  }
  bool f32m = DYN ? (*oflag!=0) : true;
#pragma unroll
  for(int rt=0;rt<4;rt++){
#pragma unroll
    for(int r=0;r<4;r++){
      int row=rowBase+rowOff+rt*16+quad*4+r;
      int rb=row/mloc, rm=row-rb*mloc;
      size_t obase=(size_t)rb*oBS + (size_t)tt*ttO + (size_t)rm*N;
#pragma unroll
      for(int ctl=0;ctl<4;ctl++){
        int col=colBase+colOff+ctl*16+l15;
        float v=acc[rt][ctl][r];
        if(bias) v+=bias[col];
        if(RELU) v=fmaxf(v,0.f);
        if(DYN){
          if(!f32m) ((bf16*)out)[obase+col]=__float2bfloat16(v);
          else      ((float*)out)[obase+col]=v;
        } else {
          ((f16*)out)[obase+col]=(f16)v;
        }
      }
    }
  }
}

// ---------------------------------------------------------------- f32 GEMM (layer 0 temporal, K=45), BN fused, batched over tt
__global__ __launch_bounds__(256) void k_gemm0(
    const f16* __restrict__ nfh, const float* __restrict__ Wg,
    f16* __restrict__ out, int M, int K, int N, int mloc, size_t oBS, size_t ttO,
    const float* __restrict__ scbAll, int scbStride)
{
  __shared__ alignas(16) float As[16][64];
  __shared__ alignas(16) float Bs[16][64];
  int tid=threadIdx.x, tx=tid&15, ty=tid>>4;
  int rowBase=blockIdx.x*64, colBase=blockIdx.y*64;
  int tt=blockIdx.z;
  const f16* A0=nfh+(size_t)tt*M*K;
  const float* scb=scbAll+(size_t)tt*scbStride;
  float acc[4][4];
#pragma unroll
  for(int i=0;i<4;i++)
#pragma unroll
    for(int j=0;j<4;j++) acc[i][j]=0.f;
  int lrow=tid&63, lcq=tid>>6;
  int nct=(K+15)>>4;
  for(int ct=0;ct<nct;ct++){
    __syncthreads();
    {
      int r=rowBase+lrow, c0=(ct<<4)+(lcq<<2);
#pragma unroll
      for(int q=0;q<4;q++){
        int c=c0+q;
        As[(lcq<<2)+q][lrow] = (c<K)? fmaxf(fmaf((float)A0[(size_t)r*K+c],scb[c],scb[K+c]),0.f) : 0.f;
      }
    }
    {
      int og=colBase+lrow, c0=(ct<<4)+(lcq<<2);
#pragma unroll
      for(int q=0;q<4;q++){
        int c=c0+q;
        Bs[(lcq<<2)+q][lrow] = (c<K)? Wg[(size_t)og*K+c] : 0.f;
      }
    }
    __syncthreads();
#pragma unroll
    for(int c=0;c<16;c++){
      float4 a4=*(const float4*)&As[c][ty<<2];
      float av[4]={a4.x,a4.y,a4.z,a4.w};
      float4 b4=*(const float4*)&Bs[c][tx<<2];
      float bw[4]={b4.x,b4.y,b4.z,b4.w};
#pragma unroll
      for(int i=0;i<4;i++)
#pragma unroll
        for(int j=0;j<4;j++) acc[i][j]+=av[i]*bw[j];
    }
  }
#pragma unroll
  for(int i=0;i<4;i++){
    int r=rowBase+(ty<<2)+i;
    int rb=r/mloc, rm=r-rb*mloc;
    size_t obase=(size_t)rb*oBS + (size_t)blockIdx.z*ttO + (size_t)rm*N;
#pragma unroll
    for(int j=0;j<4;j++){
      int o=colBase+(tx<<2)+j;
      out[obase+o]=(f16)fmaxf(acc[i][j],0.f);
    }
  }
}

// ---------------------------------------------------------------- host
extern "C" void kernel_launch(void* const* d_in, const int* in_sizes, int n_in,
                              void* d_out, int out_size, void* d_ws, size_t ws_size,
                              hipStream_t stream) {
  (void)in_sizes; (void)n_in; (void)out_size; (void)ws_size;

  const int di[6] = {2,4,7,10,13,16};
  const int fi6[6] = {-1,5,8,11,14,17};
  const int ti[6] = {3,6,9,12,15,18};

  const int midv[6]={45,96,192,384,768,1536};
  const int midp[6]={0,128,256,384,768,1536};
  const int cinv[6]={0,64,128,256,512,1024};
  const int coutv[6]={64,128,256,512,1024,2048};
  const int tkv[6]={1,3,3,3,3,1};
  const int Nv[6]={2048,1024,512,512,256,256};
  const int mv[6]={1024,512,512,256,256,128};
  const int Lv[6]={4,4,2,2,1,1};
  const int Tv[6]={4,2,2,1,1,1};
  const float rrv[6]={1.5f,3.f,3.f,6.f,6.f,6.f};

  float* ws=(float*)d_ws;
  size_t off=0;
  auto A=[&](size_t n)->float*{ float* p=ws+off; off+=(n+63)&~(size_t)63; return p; };
  auto Ah=[&](size_t n)->f16*{ return (f16*)A((n+1)/2); };

  int* flag=(int*)A(64);

  f16* W2h[6]; W2h[0]=nullptr;
  for(int l=1;l<6;l++) W2h[l]=Ah((size_t)midp[l]*3*cinv[l]);
  f16* Wth[6]; Wth[0]=nullptr;
  for(int l=1;l<6;l++) Wth[l]=Ah((size_t)coutv[l]*tkv[l]*midv[l]);
  float* Wd0=A(135);
  float* Wt0=A(2880);
  f16* fcwh=Ah(2097152);
  float* fcb=A(1024);

  float* X[7];
  X[0]=A(786432);
  for(int l=0;l<6;l++) X[l+1]=A((size_t)32*Tv[l]*mv[l]*3);

  f16* FA=Ah(8388608);
  f16* FB=Ah(8388608);
  f16* F[7]; F[0]=nullptr;
  for(int l=0;l<6;l++) F[l+1]=(l%2==0)?FA:FB;

  f16* nfh=Ah(18874368);           // max T*M*C (l2/l4: 18.87M)
  float* sumsAll=A(11*4608);
  float* scbAll=A(4*4608);
  f16* Gh=Ah(25165824);            // max SLOTS*M*Kp (l2: 25.2M)
  int* bqAll=(int*)A(1179648);     // max SLOTS*M*9 (l0: 1.18M)

  // ---- setup: detect+zero (fused) + converts + W2 (4 dispatches)
  {
    int zn=11*4608;
    int zb=(zn+255)/256;
    k_detect<<<dim3(1+zb),dim3(256),0,stream>>>((const unsigned int*)d_in[0], 4096, flag, sumsAll, zn);
  }
  {
    CvtF32 J;
    J.src[0]=d_in[0];  J.dst[0]=X[0];  J.n[0]=786432;
    J.src[1]=d_in[3];  J.dst[1]=Wt0;   J.n[1]=2880;
    J.src[2]=d_in[20]; J.dst[2]=fcb;   J.n[2]=1024;
    J.src[3]=d_in[2];  J.dst[3]=Wd0;   J.n[3]=135;
    J.blk0[0]=0; J.blk0[1]=3072; J.blk0[2]=3084; J.blk0[3]=3088; J.blk0[4]=3089;
    k_cvt_all<<<dim3(3089),dim3(256),0,stream>>>(J,flag);
  }
  {
    CvtF16 J;
    int ns[6]={36864,147456,589824,2359296,3145728,2097152};
    const void* ss[6]={d_in[ti[1]],d_in[ti[2]],d_in[ti[3]],d_in[ti[4]],d_in[ti[5]],d_in[19]};
    f16* ds[6]={Wth[1],Wth[2],Wth[3],Wth[4],Wth[5],fcwh};
    int bp=0;
    for(int j2=0;j2<6;j2++){ J.src[j2]=ss[j2]; J.dst[j2]=ds[j2]; J.n[j2]=ns[j2]; J.blk0[j2]=bp; bp+=(ns[j2]+255)/256; }
    J.blk0[6]=bp;
    k_cvth_all<<<dim3((unsigned)bp),dim3(256),0,stream>>>(J,flag);
  }
  {
    W2J J;
    int bp=0;
    for(int l=1;l<6;l++){
      int j2=l-1;
      J.wd[j2]=d_in[di[l]]; J.wf[j2]=d_in[fi6[l]]; J.dst[j2]=W2h[l];
      J.mid[j2]=midv[l]; J.cin[j2]=cinv[l]; J.n[j2]=midp[l]*3*cinv[l];
      J.blk0[j2]=bp; bp+=(J.n[j2]+255)/256;
    }
    J.blk0[5]=bp;
    k_w2all<<<dim3((unsigned)bp),dim3(256),0,stream>>>(J,flag);
  }

  // ---- schedule tables
  const int SLOTS[6]={4,5,4,2,1,1};
  const int sTT[6][5]={{0,1,2,3,0},{0,0,1,1,1},{0,0,1,1,0},{0,0,0,0,0},{0,0,0,0,0},{0,0,0,0,0}};
  const int sFI[6][5]={{0,1,2,3,0},{0,1,1,2,3},{0,1,0,1,0},{0,1,0,0,0},{0,0,0,0,0},{0,0,0,0,0}};
  const int sJJ[6][5]={{0,0,0,0,0},{1,2,0,1,2},{1,2,0,1,0},{1,2,0,0,0},{1,0,0,0,0},{0,0,0,0,0}};
  const int4 jm4[6]={{1,1,1,1},{6,7,0,0},{6,3,0,0},{6,0,0,0},{2,0,0,0},{1,0,0,0}};
  const int Tcenters[6][4]={{0,1,2,3},{0,2,0,0},{0,1,0,0},{0,0,0,0},{0,0,0,0},{0,0,0,0}};
  const int slotBase[6]={0,4,6,8,9,10};

  for(int l=0;l<6;l++){
    int N=Nv[l], m=mv[l], Lin=Lv[l], T=Tv[l], cin=cinv[l], mid=midv[l];
    int C=tkv[l]*midv[l], M=32*m, cout=coutv[l];
    float r2=rrv[l]*rrv[l];
    const float* Xin=X[l]; float* Xout=X[l+1];

    { // FPS
      dim3 g(32*T), blk(256);
      int a0=Tcenters[l][0],a1=Tcenters[l][1],a2=Tcenters[l][2],a3=Tcenters[l][3];
      if(N==2048)      k_fps2<8><<<g,blk,0,stream>>>(Xin,Lin,N,m,a0,a1,a2,a3,T,Xout);
      else if(N==1024) k_fps2<4><<<g,blk,0,stream>>>(Xin,Lin,N,m,a0,a1,a2,a3,T,Xout);
      else if(N==512)  k_fps2<2><<<g,blk,0,stream>>>(Xin,Lin,N,m,a0,a1,a2,a3,T,Xout);
      else             k_fps2<1><<<g,blk,0,stream>>>(Xin,Lin,N,m,a0,a1,a2,a3,T,Xout);
    }

    Sched S;
    for(int s=0;s<5;s++){ S.tt[s]=sTT[l][s]; S.fi[s]=sFI[l][s]; S.jj[s]=sJJ[l][s]; }
    size_t aBS=(size_t)T*m*3;
    int chunks=(m+255)>>8;

    k_bq<<<dim3(32*chunks,SLOTS[l]),256,0,stream>>>(Xin,Xout,bqAll,N,m,r2,Lin,aBS,M,S);

    if(l==0){
      k_part0<<<dim3(M/4,4),256,0,stream>>>(Xin,Xout,bqAll,Wd0,nfh,m,mid,C,N-1,aBS,N,Lin,M,S);
    } else {
      int cw2=cin>>1; if(cw2>256) cw2=256;
      int rpb=256/cw2;
      k_outer<<<dim3((unsigned)(SLOTS[l]*M/rpb)),256,0,stream>>>(
          F[l],Xin,Xout,bqAll,Gh,m,cin,N,Lin,aBS,N-1,M,S);
      k_pg<<<dim3((unsigned)(SLOTS[l]*M/128),(unsigned)(midp[l]/128)),256,0,stream>>>(
          Gh,W2h[l],nfh,3*cin,mid,C,M,S);
    }

    float* sumsL=sumsAll+(size_t)slotBase[l]*4608;
    k_bnstat<<<dim3((C+255)/256,32,T),256,0,stream>>>(nfh,M,C,sumsL,mid,jm4[l],4608);
    k_bnfin<<<dim3((C+255)/256,T),256,0,stream>>>(sumsL,scbAll,C,M,mid,jm4[l],4608,4608);

    size_t oBS=(size_t)T*m*cout;
    size_t ttO=(size_t)m*cout;
    if(l==0)
      k_gemm0<<<dim3(M/64,1,4),256,0,stream>>>(nfh,Wt0,F[1],M,C,cout,m,oBS,ttO,scbAll,4608);
    else if(l<5)
      k_gemm_mfma<true,false,true><<<dim3(M/128,cout/128,T),256,0,stream>>>(
          nfh,Wth[l],nullptr,F[l+1],C,cout,m,oBS,(size_t)M*C,ttO,nullptr,scbAll,4608);
    else
      k_gemm_mfma<false,false,true><<<dim3(M/128,cout/128,T),256,0,stream>>>(
          nfh,Wth[l],nullptr,F[l+1],C,cout,m,oBS,(size_t)M*C,ttO,nullptr,scbAll,4608);
  }

  // final FC (A=F[6] f16, contiguous 4096x2048) -> d_out (bf16 or f32 per flag)
  k_gemm_mfma<false,true,false><<<dim3(4096/128,1024/128,1),256,0,stream>>>(
      F[6],fcwh,fcb,d_out,2048,1024,128,(size_t)128*1024,0,0,flag,nullptr,0);
}

// Round 8
// 2812.232 us; speedup vs baseline: 1.3669x; 1.1290x over previous
//
#include <hip/hip_runtime.h>
#include <hip/hip_bf16.h>
#include <math.h>

typedef __hip_bfloat16 bf16;
typedef _Float16 f16;
typedef _Float16 f16x2 __attribute__((ext_vector_type(2)));
typedef _Float16 f16x8 __attribute__((ext_vector_type(8)));
typedef float f32x4 __attribute__((ext_vector_type(4)));

struct Sched { int tt[5]; int fi[5]; int jj[5]; };
struct CvtF32 { const void* src[4]; float* dst[4]; int n[4]; int blk0[5]; };
struct CvtF16 { const void* src[6]; f16* dst[6]; int n[6]; int blk0[7]; };
struct W2J { const void* wd[5]; const void* wf[5]; f16* dst[5]; int mid[5]; int cin[5]; int n[5]; int blk0[6]; };

// ---------------------------------------------------------------- dtype detect + zero sums (fused, saves a launch)
__global__ void k_detect(const unsigned int* __restrict__ w, int nwords, int* __restrict__ flag,
                         float* __restrict__ zp, int zn){
  if(blockIdx.x==0){
    __shared__ int cnt;
    if(threadIdx.x==0) cnt=0;
    __syncthreads();
    int local=0;
    for(int i=threadIdx.x;i<nwords;i+=256){
      unsigned int v=w[i];
      int e=(v>>7)&0xFF;
      if(e>=0xC0) local++;
    }
    atomicAdd(&cnt, local);
    __syncthreads();
    if(threadIdx.x==0) flag[0] = (cnt > (nwords>>3)) ? 1 : 0;
  } else {
    int i=(blockIdx.x-1)*256+threadIdx.x;
    if(i<zn) zp[i]=0.f;
  }
}

__device__ inline float ldmix(const void* p, size_t i, bool f32m){
  return f32m ? ((const float*)p)[i] : __bfloat162float(((const bf16*)p)[i]);
}

// ---------------------------------------------------------------- fused converts
__global__ void k_cvt_all(CvtF32 J, const int* __restrict__ flag){
  int b=blockIdx.x;
  int j=0;
  while(j<3 && J.blk0[j+1]<=b) j++;
  int i=(b-J.blk0[j])*256+threadIdx.x;
  if(i>=J.n[j]) return;
  bool f32m=*flag!=0;
  J.dst[j][i]=ldmix(J.src[j],i,f32m);
}

__global__ void k_cvth_all(CvtF16 J, const int* __restrict__ flag){
  int b=blockIdx.x;
  int j=0;
  while(j<5 && J.blk0[j+1]<=b) j++;
  int i=(b-J.blk0[j])*256+threadIdx.x;
  if(i>=J.n[j]) return;
  bool f32m=*flag!=0;
  J.dst[j][i]=(f16)ldmix(J.src[j],i,f32m);
}

// W2[o, a*cin+c] = Wd[o,a]*Wf[o,c], all 5 layers in one launch
__global__ void k_w2all(W2J J, const int* __restrict__ flag){
  int b=blockIdx.x;
  int j=0;
  while(j<4 && J.blk0[j+1]<=b) j++;
  int i=(b-J.blk0[j])*256+threadIdx.x;
  if(i>=J.n[j]) return;
  int cin=J.cin[j]; int K3=3*cin;
  int o=i/K3; int rem=i-o*K3; int a=rem/cin; int c=rem-a*cin;
  float v=0.f;
  if(o<J.mid[j]){
    bool f32m=*flag!=0;
    v=ldmix(J.wd[j],(size_t)3*o+a,f32m)*ldmix(J.wf[j],(size_t)o*cin+c,f32m);
  }
  J.dst[j][i]=(f16)v;
}

// ---------------------------------------------------------------- FPS: 256 threads, DPP in-wave argmax (proven floor; see notes)
// FPS floor established empirically (rounds 1/3/4): coord-carry DPP +38%,
// 1-wave no-barrier +61%, LDS spin sync +50%. The 4-wave barrier structure is
// the floor. DO NOT touch the inner loop.
template<int P>
__global__ __launch_bounds__(256) void k_fps2(
    const float* __restrict__ xyz, int L, int N, int m,
    int c0,int c1,int c2,int c3, int T, float* __restrict__ anchors)
{
  __shared__ float4 ptsS[P*256];
  __shared__ unsigned long long keyS[2][4];
  __shared__ float ancS[3*1024];
  int prob=blockIdx.x;
  int b=prob/T, tt=prob%T;
  int f=(tt==0)?c0:(tt==1)?c1:(tt==2)?c2:c3;
  const float* src = xyz + ((size_t)(b*L+f))*N*3;
  float* anc = anchors + ((size_t)(b*T+tt))*m*3;
  int tid=threadIdx.x;
  for(int t=tid;t<N;t+=256)
    ptsS[t]=make_float4(src[3*t],src[3*t+1],src[3*t+2],0.f);
  __syncthreads();
  float px[P],py[P],pz[P],mind[P];
#pragma unroll
  for(int j=0;j<P;j++){
    float4 v=ptsS[tid+j*256];
    px[j]=v.x; py[j]=v.y; pz[j]=v.z; mind[j]=1e10f;
  }
  float4 p0=ptsS[0];
  float lx=p0.x, ly=p0.y, lz=p0.z;
  if(tid==0){ ancS[0]=lx; ancS[1]=ly; ancS[2]=lz; }
  int w=tid>>6;
  for(int it=1; it<m; ++it){
    float bv=-1.f; int bi=0;
#pragma unroll
    for(int j=0;j<P;j++){
#pragma clang fp contract(off)
      float dx=px[j]-lx, dy=py[j]-ly, dz=pz[j]-lz;
      float d2=dx*dx+dy*dy+dz*dz;
      float mv=mind[j]; if(d2<mv) mv=d2; mind[j]=mv;
      if(mv>bv){ bv=mv; bi=tid+j*256; }
    }
    unsigned int hi=__float_as_uint(bv);
    unsigned int lo=0xFFFFFFFFu-(unsigned)bi;
#define DPPSTEP(CTRL) { \
    unsigned int shi=(unsigned)__builtin_amdgcn_update_dpp(0,(int)hi,CTRL,0xF,0xF,true); \
    unsigned int slo=(unsigned)__builtin_amdgcn_update_dpp(0,(int)lo,CTRL,0xF,0xF,true); \
    bool g=(shi>hi)||(shi==hi&&slo>lo); \
    hi=g?shi:hi; lo=g?slo:lo; }
    DPPSTEP(0x111) DPPSTEP(0x112) DPPSTEP(0x114) DPPSTEP(0x118) DPPSTEP(0x142) DPPSTEP(0x143)
#undef DPPSTEP
    if((tid&63)==63)
      keyS[it&1][w]=((unsigned long long)hi<<32)|lo;
    __syncthreads();
    unsigned long long k0=keyS[it&1][0], k1=keyS[it&1][1];
    unsigned long long k2=keyS[it&1][2], k3=keyS[it&1][3];
    unsigned long long ka = k0>k1?k0:k1;
    unsigned long long kb = k2>k3?k2:k3;
    unsigned long long kk = ka>kb?ka:kb;
    int wi = (int)(0xFFFFFFFFu - (unsigned)(kk & 0xFFFFFFFFull));
    float4 wc = ptsS[wi];
    lx=wc.x; ly=wc.y; lz=wc.z;
    if(tid==0){ ancS[3*it]=lx; ancS[3*it+1]=ly; ancS[3*it+2]=lz; }
  }
  __syncthreads();
  for(int t=tid;t<3*m;t+=256) anc[t]=ancS[t];
}

// ---------------------------------------------------------------- Round-13: dual-role kernel {FPS layer l+1 || bq layer l}
// FPS_{l+1} depends only on FPS_l's anchors (coordinate chain); bq_l depends
// on FPS_l but NOT FPS_{l+1}. They are independent -> co-launch as disjoint
// blockIdx ranges. FPS blocks first (long pole, dispatched first); merged
// duration ~= FPS_{l+1}, hiding bq_l under otherwise-idle FPS time.
// FPS body = round-0 proven variant (direct anchor stores); bq body =
// round-7 proven predicated scan. No cross-block deps; no algorithm changes.
template<int P>
__global__ __launch_bounds__(256) void k_fps_bq(
    const float* __restrict__ xyzF, int Lf, int Nf, int mf,
    int c0,int c1,int c2,int c3, int Tf, float* __restrict__ ancOut, int fpsBlocks,
    const float* __restrict__ Xin, const float* __restrict__ Xout,
    int* __restrict__ bqAll, int N, int m, float r2, int Lin, size_t aBS, int M, Sched S, int chunks)
{
  __shared__ float4 ptsS[P*256];
  __shared__ unsigned long long keyS[2][4];
  __shared__ float sp[768];
  if((int)blockIdx.x < fpsBlocks){
    // ---------------- FPS path (layer l+1), round-0 proven body
    int prob=blockIdx.x;
    int b=prob/Tf, tt=prob%Tf;
    int f=(tt==0)?c0:(tt==1)?c1:(tt==2)?c2:c3;
    const float* src = xyzF + ((size_t)(b*Lf+f))*Nf*3;
    float* anc = ancOut + ((size_t)(b*Tf+tt))*mf*3;
    int tid=threadIdx.x;
    for(int t=tid;t<Nf;t+=256)
      ptsS[t]=make_float4(src[3*t],src[3*t+1],src[3*t+2],0.f);
    __syncthreads();
    float px[P],py[P],pz[P],mind[P];
#pragma unroll
    for(int j=0;j<P;j++){
      float4 v=ptsS[tid+j*256];
      px[j]=v.x; py[j]=v.y; pz[j]=v.z; mind[j]=1e10f;
    }
    float4 p0=ptsS[0];
    float lx=p0.x, ly=p0.y, lz=p0.z;
    if(tid==0){ anc[0]=lx; anc[1]=ly; anc[2]=lz; }
    int w=tid>>6;
    for(int it=1; it<mf; ++it){
      float bv=-1.f; int bi=0;
#pragma unroll
      for(int j=0;j<P;j++){
#pragma clang fp contract(off)
        float dx=px[j]-lx, dy=py[j]-ly, dz=pz[j]-lz;
        float d2=dx*dx+dy*dy+dz*dz;
        float mv=mind[j]; if(d2<mv) mv=d2; mind[j]=mv;
        if(mv>bv){ bv=mv; bi=tid+j*256; }
      }
      unsigned int hi=__float_as_uint(bv);
      unsigned int lo=0xFFFFFFFFu-(unsigned)bi;
#define DPPSTEP(CTRL) { \
      unsigned int shi=(unsigned)__builtin_amdgcn_update_dpp(0,(int)hi,CTRL,0xF,0xF,true); \
      unsigned int slo=(unsigned)__builtin_amdgcn_update_dpp(0,(int)lo,CTRL,0xF,0xF,true); \
      bool g=(shi>hi)||(shi==hi&&slo>lo); \
      hi=g?shi:hi; lo=g?slo:lo; }
      DPPSTEP(0x111) DPPSTEP(0x112) DPPSTEP(0x114) DPPSTEP(0x118) DPPSTEP(0x142) DPPSTEP(0x143)
#undef DPPSTEP
      if((tid&63)==63)
        keyS[it&1][w]=((unsigned long long)hi<<32)|lo;
      __syncthreads();
      unsigned long long k0=keyS[it&1][0], k1=keyS[it&1][1];
      unsigned long long k2=keyS[it&1][2], k3=keyS[it&1][3];
      unsigned long long ka = k0>k1?k0:k1;
      unsigned long long kb = k2>k3?k2:k3;
      unsigned long long kk = ka>kb?ka:kb;
      int wi = (int)(0xFFFFFFFFu - (unsigned)(kk & 0xFFFFFFFFull));
      float4 wc = ptsS[wi];
      lx=wc.x; ly=wc.y; lz=wc.z;
      if(tid==0){ anc[3*it]=lx; anc[3*it+1]=ly; anc[3*it+2]=lz; }
    }
  } else {
    // ---------------- bq path (layer l), round-7 proven body, flattened grid
    int fb=(int)blockIdx.x-fpsBlocks;
    int s=fb/(32*chunks);
    int rem=fb-s*(32*chunks);
    int b=rem/chunks;
    int a=(rem-b*chunks)*256+threadIdx.x;
    int tt=S.tt[s], fr=S.fi[s];
    const float* Pb = Xin + ((size_t)b*Lin + fr)*(size_t)N*3;
    bool act = a<m;
    float ax=0,ay=0,az=0;
    int* o = bqAll + ((size_t)s*M + (size_t)b*m + (size_t)(act?a:0))*9;
    if(act){
      const float* A=Xout+(size_t)b*aBS+(size_t)tt*m*3+(size_t)a*3;
      ax=A[0]; ay=A[1]; az=A[2];
    }
    int cnt = act?0:9, first=0;
    for(int base=0; base<N; base+=256){
      for(int t=threadIdx.x; t<768; t+=256) sp[t]=Pb[(size_t)base*3+t];
      __syncthreads();
      for(int q=0;q<256;q++){
#pragma clang fp contract(off)
        float dx=sp[3*q]-ax, dy=sp[3*q+1]-ay, dz=sp[3*q+2]-az;
        float d2=dx*dx+dy*dy+dz*dz;
        if(d2<r2 && cnt<9){
          int p=base+q;
          if(cnt==0) first=p;
          o[cnt]=p; cnt++;
        }
      }
      if(__syncthreads_and(cnt>=9)) break;
    }
    if(act){ for(int k=cnt;k<9;k++) o[k]=first; }
  }
}

// ---------------------------------------------------------------- ball query standalone (layer 5 only; round-7 proven body)
__global__ __launch_bounds__(256) void k_bq(
    const float* __restrict__ Xin, const float* __restrict__ Xout,
    int* __restrict__ bqAll, int N, int m, float r2, int Lin, size_t aBS, int M, Sched S)
{
  int chunks=(m+255)>>8;
  int b=blockIdx.x/chunks;
  int a=(blockIdx.x%chunks)*256+threadIdx.x;
  int s=blockIdx.y;
  int tt=S.tt[s], fr=S.fi[s];
  const float* Pb = Xin + ((size_t)b*Lin + fr)*(size_t)N*3;
  bool act = a<m;
  float ax=0,ay=0,az=0;
  int* o = bqAll + ((size_t)s*M + (size_t)b*m + (size_t)(act?a:0))*9;
  if(act){
    const float* A=Xout+(size_t)b*aBS+(size_t)tt*m*3+(size_t)a*3;
    ax=A[0]; ay=A[1]; az=A[2];
  }
  int cnt = act?0:9, first=0;
  __shared__ float sp[768];
  for(int base=0; base<N; base+=256){
    for(int t=threadIdx.x; t<768; t+=256) sp[t]=Pb[(size_t)base*3+t];
    __syncthreads();
    for(int q=0;q<256;q++){
#pragma clang fp contract(off)
      float dx=sp[3*q]-ax, dy=sp[3*q+1]-ay, dz=sp[3*q+2]-az;
      float d2=dx*dx+dy*dy+dz*dz;
      if(d2<r2 && cnt<9){
        int p=base+q;
        if(cnt==0) first=p;
        o[cnt]=p; cnt++;
      }
    }
    if(__syncthreads_and(cnt>=9)) break;
  }
  if(act){ for(int k=cnt;k<9;k++) o[k]=first; }
}

// ---------------------------------------------------------------- layer 0 (cin=0): nf = sum_k disp_k . Wd  (batched over tt)
__global__ __launch_bounds__(256) void k_part0(
    const float* __restrict__ Xin, const float* __restrict__ Xout,
    const int* __restrict__ bqAll, const float* __restrict__ Wd,
    f16* __restrict__ nfh, int m, int mid, int ld, int nmask,
    size_t aBS, int N, int Lin, int M, Sched S)
{
  int sub = threadIdx.x>>6;
  int o = threadIdx.x&63;
  int row = blockIdx.x*4 + sub;
  int tt = blockIdx.y;                      // l0: slot == tt
  int b = row/m, mm = row - b*m;
  const float* A = Xout + (size_t)b*aBS + (size_t)tt*m*3 + (size_t)mm*3;
  float ax=A[0], ay=A[1], az=A[2];
  float w0=0,w1=0,w2=0;
  if(o<mid){ w0=Wd[3*o]; w1=Wd[3*o+1]; w2=Wd[3*o+2]; }
  int fr=S.fi[tt];
  const int* id = bqAll + ((size_t)tt*M + row)*9;
  const float* Pb = Xin + ((size_t)b*Lin+fr)*(size_t)N*3;
  float acc=0.f;
  for(int k=0;k<9;k++){
    int p=id[k] & nmask;
    const float* q = Pb + (size_t)p*3;
    float dx=q[0]-ax, dy=q[1]-ay, dz=q[2]-az;
    acc += dx*w0+dy*w1+dz*w2;
  }
  if(o<mid) nfh[(size_t)tt*M*ld + (size_t)row*ld + o] = (f16)acc;
}

// ---------------------------------------------------------------- G[r, a*cin+c] = sum_k disp[r,k,a]*fg[r,k,c]  (batched)
__global__ __launch_bounds__(256) void k_outer(
    const f16* __restrict__ feats, const float* __restrict__ Xin,
    const float* __restrict__ Xout, const int* __restrict__ bqAll,
    f16* __restrict__ Gh, int m, int cin, int N, int Lin,
    size_t aBS, int nmask, int M, Sched S)
{
  int cw2 = cin>>1; if(cw2>256) cw2=256;
  int rpb = 256/cw2;
  int tid=threadIdx.x;
  int sub=tid/cw2, lc=tid-sub*cw2;
  int r=blockIdx.x*rpb+sub;
  int Kp=3*cin;
  int s=r/M, mrow=r-s*M;
  int b=mrow/m, mm=mrow-b*m;
  int tt=S.tt[s], fr=S.fi[s];
  const float* A0=Xout+(size_t)b*aBS+(size_t)tt*m*3+(size_t)mm*3;
  float ax=A0[0],ay=A0[1],az=A0[2];
  const float* Pb=Xin+((size_t)b*Lin+fr)*(size_t)N*3;
  const f16* Fb=feats+(((size_t)b*Lin+fr)*(size_t)N)*(size_t)cin;
  const int* id=bqAll+(size_t)r*9;
  int idx[9]; float d0[9],d1[9],d2a[9];
#pragma unroll
  for(int k=0;k<9;k++){
    int p=id[k]&nmask; idx[k]=p;
    const float* q=Pb+(size_t)p*3;
    d0[k]=q[0]-ax; d1[k]=q[1]-ay; d2a[k]=q[2]-az;
  }
  f16* Gr=Gh+(size_t)r*Kp;
  for(int cc=2*lc; cc<cin; cc+=2*cw2){
    float a0=0,a1=0,a2=0,b0=0,b1=0,b2=0;
#pragma unroll
    for(int k=0;k<9;k++){
      f16x2 fv=*(const f16x2*)(Fb+(size_t)idx[k]*cin+cc);
      float f0=(float)fv[0], f1=(float)fv[1];
      a0=fmaf(d0[k],f0,a0); b0=fmaf(d0[k],f1,b0);
      a1=fmaf(d1[k],f0,a1); b1=fmaf(d1[k],f1,b1);
      a2=fmaf(d2a[k],f0,a2); b2=fmaf(d2a[k],f1,b2);
    }
    f16x2 o0={(f16)a0,(f16)b0}, o1={(f16)a1,(f16)b1}, o2={(f16)a2,(f16)b2};
    *(f16x2*)(Gr+cc)=o0; *(f16x2*)(Gr+cin+cc)=o1; *(f16x2*)(Gr+2*cin+cc)=o2;
  }
}

// ---------------------------------------------------------------- pair GEMM: nf[tt][mrow, j*mid+col] = G @ W2^T (batched)
__global__ __launch_bounds__(256) void k_pg(
    const f16* __restrict__ Gh, const f16* __restrict__ W2,
    f16* __restrict__ nfh, int Kp, int mid, int C, int M, Sched S)
{
  __shared__ f16 As[128*40];
  __shared__ f16 Bs[128*40];
  int tid=threadIdx.x;
  int lane=tid&63, w=tid>>6;
  int quad=lane>>4, l15=lane&15;
  int rowOff=(w>>1)*64, colOff=(w&1)*64;
  int rowBase=blockIdx.x*128, colBase=blockIdx.y*128;
  f32x4 acc[4][4];
#pragma unroll
  for(int i=0;i<4;i++)
#pragma unroll
    for(int j=0;j<4;j++) acc[i][j]=(f32x4){0.f,0.f,0.f,0.f};
  int nct=Kp>>5;
  int srow=tid>>1, shalf=tid&1;
  for(int ct=0;ct<nct;ct++){
    __syncthreads();
    {
      const uint4* s=(const uint4*)(Gh+(size_t)(rowBase+srow)*Kp+(ct<<5)+(shalf<<4));
      uint4 u0=s[0], u1=s[1];
      *(uint4*)(As + srow*40 + (shalf<<4))     = u0;
      *(uint4*)(As + srow*40 + (shalf<<4) + 8) = u1;
    }
    {
      const uint4* s=(const uint4*)(W2+(size_t)(colBase+srow)*Kp+(ct<<5)+(shalf<<4));
      uint4 u0=s[0], u1=s[1];
      *(uint4*)(Bs + srow*40 + (shalf<<4))     = u0;
      *(uint4*)(Bs + srow*40 + (shalf<<4) + 8) = u1;
    }
    __syncthreads();
    f16x8 af[4], bf4[4];
#pragma unroll
    for(int rt=0;rt<4;rt++) af[rt]=*(const f16x8*)(As + (rowOff+rt*16+l15)*40 + quad*8);
#pragma unroll
    for(int ctl=0;ctl<4;ctl++) bf4[ctl]=*(const f16x8*)(Bs + (colOff+ctl*16+l15)*40 + quad*8);
#pragma unroll
    for(int rt=0;rt<4;rt++)
#pragma unroll
      for(int ctl=0;ctl<4;ctl++)
        acc[rt][ctl]=__builtin_amdgcn_mfma_f32_16x16x32_f16(af[rt],bf4[ctl],acc[rt][ctl],0,0,0);
  }
#pragma unroll
  for(int rt=0;rt<4;rt++){
#pragma unroll
    for(int r=0;r<4;r++){
      int row=rowBase+rowOff+rt*16+quad*4+r;
      int s=row/M, mrow=row-s*M;
      int tt=S.tt[s], j=S.jj[s];
      f16* base = nfh + (size_t)tt*M*C + (size_t)mrow*C + j*mid;
#pragma unroll
      for(int ctl=0;ctl<4;ctl++){
        int col=colBase+colOff+ctl*16+l15;
        if(col<mid) base[col]=(f16)acc[rt][ctl][r];
      }
    }
  }
}

// ---------------------------------------------------------------- BN stats (batched over tt, jmask skips unwritten slices)
__global__ void k_bnstat(const f16* __restrict__ nfh, int M, int C, float* __restrict__ sumsL,
                         int mid, int4 jm, int sumStride){
  int c = blockIdx.x*256 + threadIdx.x;
  if(c>=C) return;
  int tt=blockIdx.z;
  int jmask = (tt==0)?jm.x:(tt==1)?jm.y:(tt==2)?jm.z:jm.w;
  int j=c/mid;
  if(!((jmask>>j)&1)) return;
  const f16* base=nfh+(size_t)tt*M*C;
  int rows = M>>5;
  int r0 = blockIdx.y*rows, r1 = r0+rows;
  float s=0.f, s2=0.f;
  for(int r=r0;r<r1;r++){
    float v=(float)base[(size_t)r*C+c];
    s+=v; s2+=v*v;
  }
  atomicAdd(&sumsL[tt*sumStride+c], s);
  atomicAdd(&sumsL[tt*sumStride+C+c], s2);
}

__global__ void k_bnfin(const float* __restrict__ sumsL, float* __restrict__ scbAll,
                        int C, int M, int mid, int4 jm, int sumStride, int scbStride){
  int c = blockIdx.x*256 + threadIdx.x;
  if(c>=C) return;
  int tt=blockIdx.y;
  int jmask = (tt==0)?jm.x:(tt==1)?jm.y:(tt==2)?jm.z:jm.w;
  float* scb=scbAll+(size_t)tt*scbStride;
  int j=c/mid;
  if(!((jmask>>j)&1)){ scb[c]=0.f; scb[C+c]=0.f; return; }
  float mean=sumsL[tt*sumStride+c]/(float)M;
  float var=sumsL[tt*sumStride+C+c]/(float)M - mean*mean;
  if(var<0.f) var=0.f;
  float rs=1.0f/sqrtf(var+1e-5f);
  scb[c]=rs; scb[C+c]=-mean*rs;
}

// ---------------------------------------------------------------- MFMA GEMM, A=f16 (opt fused BN+ReLU on A), batched over tt
template<bool RELU, bool DYN, bool BNA>
__global__ __launch_bounds__(256) void k_gemm_mfma(
    const f16* __restrict__ Ag, const f16* __restrict__ Bh,
    const float* __restrict__ bias, void* __restrict__ out,
    int K, int N, int mloc, size_t oBS, size_t ttA, size_t ttO,
    const int* __restrict__ oflag, const float* __restrict__ scbAll, int scbStride)
{
  __shared__ f16 As[128*40];
  __shared__ f16 Bs[128*40];
  int tid=threadIdx.x;
  int lane=tid&63, w=tid>>6;
  int quad=lane>>4, l15=lane&15;
  int rowOff=(w>>1)*64, colOff=(w&1)*64;
  int rowBase=blockIdx.x*128, colBase=blockIdx.y*128;
  int tt=blockIdx.z;
  const f16* A0=Ag+(size_t)tt*ttA;
  const float* scb = BNA ? (scbAll+(size_t)tt*scbStride) : nullptr;
  f32x4 acc[4][4];
#pragma unroll
  for(int i=0;i<4;i++)
#pragma unroll
    for(int j=0;j<4;j++) acc[i][j]=(f32x4){0.f,0.f,0.f,0.f};
  int nct=K>>5;
  int srow=tid>>1, shalf=tid&1;
  for(int ct=0;ct<nct;ct++){
    __syncthreads();
    {
      int c0g=(ct<<5)+(shalf<<4);
      const f16* src=A0+(size_t)(rowBase+srow)*K+c0g;
      if(BNA){
        f16x8 x0=((const f16x8*)src)[0], x1=((const f16x8*)src)[1];
        f16x8 h0,h1;
#pragma unroll
        for(int q=0;q<8;q++){
          h0[q]=(f16)fmaxf(fmaf((float)x0[q],scb[c0g+q],scb[K+c0g+q]),0.f);
          h1[q]=(f16)fmaxf(fmaf((float)x1[q],scb[c0g+8+q],scb[K+c0g+8+q]),0.f);
        }
        *(f16x8*)(As+srow*40+(shalf<<4))=h0;
        *(f16x8*)(As+srow*40+(shalf<<4)+8)=h1;
      } else {
        const uint4* s=(const uint4*)src;
        uint4 u0=s[0],u1=s[1];
        *(uint4*)(As+srow*40+(shalf<<4))=u0;
        *(uint4*)(As+srow*40+(shalf<<4)+8)=u1;
      }
    }
    {
      const uint4* s=(const uint4*)(Bh+(size_t)(colBase+srow)*K+(ct<<5)+(shalf<<4));
      uint4 u0=s[0], u1=s[1];
      *(uint4*)(Bs + srow*40 + (shalf<<4))     = u0;
      *(uint4*)(Bs + srow*40 + (shalf<<4) + 8) = u1;
    }
    __syncthreads();
    f16x8 af[4], bf4[4];
#pragma unroll
    for(int rt=0;rt<4;rt++) af[rt]=*(const f16x8*)(As + (rowOff+rt*16+l15)*40 + quad*8);
#pragma unroll
    for(int ctl=0;ctl<4;ctl++) bf4[ctl]=*(const f16x8*)(Bs + (colOff+ctl*16+l15)*40 + quad*8);
#pragma unroll
    for(int rt=0;rt<4;rt++)
#pragma unroll
      for(int ctl=0;ctl<4;ctl++)
        acc[rt][ctl]=__builtin_amdgcn_mfma_f32_16x16x32_f16(af[rt],bf4[ctl],acc[rt][ctl],0,0,0);
  }
  bool f32m = DYN ? (*oflag!=0) : true;
#pragma unroll
  for(int rt=0;rt<4;rt++){
#pragma unroll
    for(int r=0;r<4;r++){
      int row=rowBase+rowOff+rt*16+quad*4+r;
      int rb=row/mloc, rm=row-rb*mloc;
      size_t obase=(size_t)rb*oBS + (size_t)tt*ttO + (size_t)rm*N;
#pragma unroll
      for(int ctl=0;ctl<4;ctl++){
        int col=colBase+colOff+ctl*16+l15;
        float v=acc[rt][ctl][r];
        if(bias) v+=bias[col];
        if(RELU) v=fmaxf(v,0.f);
        if(DYN){
          if(!f32m) ((bf16*)out)[obase+col]=__float2bfloat16(v);
          else      ((float*)out)[obase+col]=v;
        } else {
          ((f16*)out)[obase+col]=(f16)v;
        }
      }
    }
  }
}

// ---------------------------------------------------------------- f32 GEMM (layer 0 temporal, K=45), BN fused, batched over tt
__global__ __launch_bounds__(256) void k_gemm0(
    const f16* __restrict__ nfh, const float* __restrict__ Wg,
    f16* __restrict__ out, int M, int K, int N, int mloc, size_t oBS, size_t ttO,
    const float* __restrict__ scbAll, int scbStride)
{
  __shared__ alignas(16) float As[16][64];
  __shared__ alignas(16) float Bs[16][64];
  int tid=threadIdx.x, tx=tid&15, ty=tid>>4;
  int rowBase=blockIdx.x*64, colBase=blockIdx.y*64;
  int tt=blockIdx.z;
  const f16* A0=nfh+(size_t)tt*M*K;
  const float* scb=scbAll+(size_t)tt*scbStride;
  float acc[4][4];
#pragma unroll
  for(int i=0;i<4;i++)
#pragma unroll
    for(int j=0;j<4;j++) acc[i][j]=0.f;
  int lrow=tid&63, lcq=tid>>6;
  int nct=(K+15)>>4;
  for(int ct=0;ct<nct;ct++){
    __syncthreads();
    {
      int r=rowBase+lrow, c0=(ct<<4)+(lcq<<2);
#pragma unroll
      for(int q=0;q<4;q++){
        int c=c0+q;
        As[(lcq<<2)+q][lrow] = (c<K)? fmaxf(fmaf((float)A0[(size_t)r*K+c],scb[c],scb[K+c]),0.f) : 0.f;
      }
    }
    {
      int og=colBase+lrow, c0=(ct<<4)+(lcq<<2);
#pragma unroll
      for(int q=0;q<4;q++){
        int c=c0+q;
        Bs[(lcq<<2)+q][lrow] = (c<K)? Wg[(size_t)og*K+c] : 0.f;
      }
    }
    __syncthreads();
#pragma unroll
    for(int c=0;c<16;c++){
      float4 a4=*(const float4*)&As[c][ty<<2];
      float av[4]={a4.x,a4.y,a4.z,a4.w};
      float4 b4=*(const float4*)&Bs[c][tx<<2];
      float bw[4]={b4.x,b4.y,b4.z,b4.w};
#pragma unroll
      for(int i=0;i<4;i++)
#pragma unroll
        for(int j=0;j<4;j++) acc[i][j]+=av[i]*bw[j];
    }
  }
#pragma unroll
  for(int i=0;i<4;i++){
    int r=rowBase+(ty<<2)+i;
    int rb=r/mloc, rm=r-rb*mloc;
    size_t obase=(size_t)rb*oBS + (size_t)blockIdx.z*ttO + (size_t)rm*N;
#pragma unroll
    for(int j=0;j<4;j++){
      int o=colBase+(tx<<2)+j;
      out[obase+o]=(f16)fmaxf(acc[i][j],0.f);
    }
  }
}

// ---------------------------------------------------------------- host
extern "C" void kernel_launch(void* const* d_in, const int* in_sizes, int n_in,
                              void* d_out, int out_size, void* d_ws, size_t ws_size,
                              hipStream_t stream) {
  (void)in_sizes; (void)n_in; (void)out_size; (void)ws_size;

  const int di[6] = {2,4,7,10,13,16};
  const int fi6[6] = {-1,5,8,11,14,17};
  const int ti[6] = {3,6,9,12,15,18};

  const int midv[6]={45,96,192,384,768,1536};
  const int midp[6]={0,128,256,384,768,1536};
  const int cinv[6]={0,64,128,256,512,1024};
  const int coutv[6]={64,128,256,512,1024,2048};
  const int tkv[6]={1,3,3,3,3,1};
  const int Nv[6]={2048,1024,512,512,256,256};
  const int mv[6]={1024,512,512,256,256,128};
  const int Lv[6]={4,4,2,2,1,1};
  const int Tv[6]={4,2,2,1,1,1};
  const float rrv[6]={1.5f,3.f,3.f,6.f,6.f,6.f};

  float* ws=(float*)d_ws;
  size_t off=0;
  auto A=[&](size_t n)->float*{ float* p=ws+off; off+=(n+63)&~(size_t)63; return p; };
  auto Ah=[&](size_t n)->f16*{ return (f16*)A((n+1)/2); };

  int* flag=(int*)A(64);

  f16* W2h[6]; W2h[0]=nullptr;
  for(int l=1;l<6;l++) W2h[l]=Ah((size_t)midp[l]*3*cinv[l]);
  f16* Wth[6]; Wth[0]=nullptr;
  for(int l=1;l<6;l++) Wth[l]=Ah((size_t)coutv[l]*tkv[l]*midv[l]);
  float* Wd0=A(135);
  float* Wt0=A(2880);
  f16* fcwh=Ah(2097152);
  float* fcb=A(1024);

  float* X[7];
  X[0]=A(786432);
  for(int l=0;l<6;l++) X[l+1]=A((size_t)32*Tv[l]*mv[l]*3);

  f16* FA=Ah(8388608);
  f16* FB=Ah(8388608);
  f16* F[7]; F[0]=nullptr;
  for(int l=0;l<6;l++) F[l+1]=(l%2==0)?FA:FB;

  f16* nfh=Ah(18874368);           // max T*M*C (l2/l4: 18.87M)
  float* sumsAll=A(11*4608);
  float* scbAll=A(4*4608);
  f16* Gh=Ah(25165824);            // max SLOTS*M*Kp (l2: 25.2M)
  int* bqAll=(int*)A(1179648);     // max SLOTS*M*9 (l0: 1.18M)

  // ---- setup: detect+zero (fused) + converts + W2 (4 dispatches)
  {
    int zn=11*4608;
    int zb=(zn+255)/256;
    k_detect<<<dim3(1+zb),dim3(256),0,stream>>>((const unsigned int*)d_in[0], 4096, flag, sumsAll, zn);
  }
  {
    CvtF32 J;
    J.src[0]=d_in[0];  J.dst[0]=X[0];  J.n[0]=786432;
    J.src[1]=d_in[3];  J.dst[1]=Wt0;   J.n[1]=2880;
    J.src[2]=d_in[20]; J.dst[2]=fcb;   J.n[2]=1024;
    J.src[3]=d_in[2];  J.dst[3]=Wd0;   J.n[3]=135;
    J.blk0[0]=0; J.blk0[1]=3072; J.blk0[2]=3084; J.blk0[3]=3088; J.blk0[4]=3089;
    k_cvt_all<<<dim3(3089),dim3(256),0,stream>>>(J,flag);
  }
  {
    CvtF16 J;
    int ns[6]={36864,147456,589824,2359296,3145728,2097152};
    const void* ss[6]={d_in[ti[1]],d_in[ti[2]],d_in[ti[3]],d_in[ti[4]],d_in[ti[5]],d_in[19]};
    f16* ds[6]={Wth[1],Wth[2],Wth[3],Wth[4],Wth[5],fcwh};
    int bp=0;
    for(int j2=0;j2<6;j2++){ J.src[j2]=ss[j2]; J.dst[j2]=ds[j2]; J.n[j2]=ns[j2]; J.blk0[j2]=bp; bp+=(ns[j2]+255)/256; }
    J.blk0[6]=bp;
    k_cvth_all<<<dim3((unsigned)bp),dim3(256),0,stream>>>(J,flag);
  }
  {
    W2J J;
    int bp=0;
    for(int l=1;l<6;l++){
      int j2=l-1;
      J.wd[j2]=d_in[di[l]]; J.wf[j2]=d_in[fi6[l]]; J.dst[j2]=W2h[l];
      J.mid[j2]=midv[l]; J.cin[j2]=cinv[l]; J.n[j2]=midp[l]*3*cinv[l];
      J.blk0[j2]=bp; bp+=(J.n[j2]+255)/256;
    }
    J.blk0[5]=bp;
    k_w2all<<<dim3((unsigned)bp),dim3(256),0,stream>>>(J,flag);
  }

  // ---- schedule tables
  const int SLOTS[6]={4,5,4,2,1,1};
  const int sTT[6][5]={{0,1,2,3,0},{0,0,1,1,1},{0,0,1,1,0},{0,0,0,0,0},{0,0,0,0,0},{0,0,0,0,0}};
  const int sFI[6][5]={{0,1,2,3,0},{0,1,1,2,3},{0,1,0,1,0},{0,1,0,0,0},{0,0,0,0,0},{0,0,0,0,0}};
  const int sJJ[6][5]={{0,0,0,0,0},{1,2,0,1,2},{1,2,0,1,0},{1,2,0,0,0},{1,0,0,0,0},{0,0,0,0,0}};
  const int4 jm4[6]={{1,1,1,1},{6,7,0,0},{6,3,0,0},{6,0,0,0},{2,0,0,0},{1,0,0,0}};
  const int Tcenters[6][4]={{0,1,2,3},{0,2,0,0},{0,1,0,0},{0,0,0,0},{0,0,0,0},{0,0,0,0}};
  const int slotBase[6]={0,4,6,8,9,10};

  // FPS for layer 0 (standalone; proven kernel, untouched)
  k_fps2<8><<<dim3(128),dim3(256),0,stream>>>(X[0],4,2048,1024,0,1,2,3,4,X[1]);

  for(int l=0;l<6;l++){
    int N=Nv[l], m=mv[l], Lin=Lv[l], T=Tv[l], cin=cinv[l], mid=midv[l];
    int C=tkv[l]*midv[l], M=32*m, cout=coutv[l];
    float r2=rrv[l]*rrv[l];
    const float* Xin=X[l]; float* Xout=X[l+1];

    Sched S;
    for(int s=0;s<5;s++){ S.tt[s]=sTT[l][s]; S.fi[s]=sFI[l][s]; S.jj[s]=sJJ[l][s]; }
    size_t aBS=(size_t)T*m*3;
    int chunks=(m+255)>>8;

    if(l<5){
      // merged: FPS for layer l+1 (blocks [0,fpsN)) + bq for layer l (rest)
      int ln=l+1;
      int fpsN=32*Tv[ln];
      int bqN=SLOTS[l]*32*chunks;
      int a0=Tcenters[ln][0],a1=Tcenters[ln][1],a2=Tcenters[ln][2],a3=Tcenters[ln][3];
      dim3 g((unsigned)(fpsN+bqN)), blk(256);
      if(Nv[ln]==1024)
        k_fps_bq<4><<<g,blk,0,stream>>>(X[ln],Lv[ln],Nv[ln],mv[ln],a0,a1,a2,a3,Tv[ln],X[ln+1],fpsN,
                                        Xin,Xout,bqAll,N,m,r2,Lin,aBS,M,S,chunks);
      else if(Nv[ln]==512)
        k_fps_bq<2><<<g,blk,0,stream>>>(X[ln],Lv[ln],Nv[ln],mv[ln],a0,a1,a2,a3,Tv[ln],X[ln+1],fpsN,
                                        Xin,Xout,bqAll,N,m,r2,Lin,aBS,M,S,chunks);
      else
        k_fps_bq<1><<<g,blk,0,stream>>>(X[ln],Lv[ln],Nv[ln],mv[ln],a0,a1,a2,a3,Tv[ln],X[ln+1],fpsN,
                                        Xin,Xout,bqAll,N,m,r2,Lin,aBS,M,S,chunks);
    } else {
      k_bq<<<dim3(32*chunks,SLOTS[l]),256,0,stream>>>(Xin,Xout,bqAll,N,m,r2,Lin,aBS,M,S);
    }

    if(l==0){
      k_part0<<<dim3(M/4,4),256,0,stream>>>(Xin,Xout,bqAll,Wd0,nfh,m,mid,C,N-1,aBS,N,Lin,M,S);
    } else {
      int cw2=cin>>1; if(cw2>256) cw2=256;
      int rpb=256/cw2;
      k_outer<<<dim3((unsigned)(SLOTS[l]*M/rpb)),256,0,stream>>>(
          F[l],Xin,Xout,bqAll,Gh,m,cin,N,Lin,aBS,N-1,M,S);
      k_pg<<<dim3((unsigned)(SLOTS[l]*M/128),(unsigned)(midp[l]/128)),256,0,stream>>>(
          Gh,W2h[l],nfh,3*cin,mid,C,M,S);
    }

    float* sumsL=sumsAll+(size_t)slotBase[l]*4608;
    k_bnstat<<<dim3((C+255)/256,32,T),256,0,stream>>>(nfh,M,C,sumsL,mid,jm4[l],4608);
    k_bnfin<<<dim3((C+255)/256,T),256,0,stream>>>(sumsL,scbAll,C,M,mid,jm4[l],4608,4608);

    size_t oBS=(size_t)T*m*cout;
    size_t ttO=(size_t)m*cout;
    if(l==0)
      k_gemm0<<<dim3(M/64,1,4),256,0,stream>>>(nfh,Wt0,F[1],M,C,cout,m,oBS,ttO,scbAll,4608);
    else if(l<5)
      k_gemm_mfma<true,false,true><<<dim3(M/128,cout/128,T),256,0,stream>>>(
          nfh,Wth[l],nullptr,F[l+1],C,cout,m,oBS,(size_t)M*C,ttO,nullptr,scbAll,4608);
    else
      k_gemm_mfma<false,false,true><<<dim3(M/128,cout/128,T),256,0,stream>>>(
          nfh,Wth[l],nullptr,F[l+1],C,cout,m,oBS,(size_t)M*C,ttO,nullptr,scbAll,4608);
  }

  // final FC (A=F[6] f16, contiguous 4096x2048) -> d_out (bf16 or f32 per flag)
  k_gemm_mfma<false,true,false><<<dim3(4096/128,1024/128,1),256,0,stream>>>(
      F[6],fcwh,fcb,d_out,2048,1024,128,(size_t)128*1024,0,0,flag,nullptr,0);
}

// Round 9
// 2682.816 us; speedup vs baseline: 1.4328x; 1.0482x over previous
//
#include <hip/hip_runtime.h>
#include <hip/hip_bf16.h>
#include <math.h>

typedef __hip_bfloat16 bf16;
typedef _Float16 f16;
typedef _Float16 f16x2 __attribute__((ext_vector_type(2)));
typedef _Float16 f16x8 __attribute__((ext_vector_type(8)));
typedef float f32x4 __attribute__((ext_vector_type(4)));

struct Sched { int tt[5]; int fi[5]; int jj[5]; };
struct CvtF32 { const void* src[4]; float* dst[4]; int n[4]; int blk0[5]; };
struct CvtF16 { const void* src[6]; f16* dst[6]; int n[6]; int blk0[7]; };
struct W2J { const void* wd[5]; const void* wf[5]; f16* dst[5]; int mid[5]; int cin[5]; int n[5]; int blk0[6]; };

// ---------------------------------------------------------------- dtype detect + zero sums (fused, saves a launch)
__global__ void k_detect(const unsigned int* __restrict__ w, int nwords, int* __restrict__ flag,
                         float* __restrict__ zp, int zn){
  if(blockIdx.x==0){
    __shared__ int cnt;
    if(threadIdx.x==0) cnt=0;
    __syncthreads();
    int local=0;
    for(int i=threadIdx.x;i<nwords;i+=256){
      unsigned int v=w[i];
      int e=(v>>7)&0xFF;
      if(e>=0xC0) local++;
    }
    atomicAdd(&cnt, local);
    __syncthreads();
    if(threadIdx.x==0) flag[0] = (cnt > (nwords>>3)) ? 1 : 0;
  } else {
    int i=(blockIdx.x-1)*256+threadIdx.x;
    if(i<zn) zp[i]=0.f;
  }
}

__device__ inline float ldmix(const void* p, size_t i, bool f32m){
  return f32m ? ((const float*)p)[i] : __bfloat162float(((const bf16*)p)[i]);
}

// ---------------------------------------------------------------- fused converts
__global__ void k_cvt_all(CvtF32 J, const int* __restrict__ flag){
  int b=blockIdx.x;
  int j=0;
  while(j<3 && J.blk0[j+1]<=b) j++;
  int i=(b-J.blk0[j])*256+threadIdx.x;
  if(i>=J.n[j]) return;
  bool f32m=*flag!=0;
  J.dst[j][i]=ldmix(J.src[j],i,f32m);
}

__global__ void k_cvth_all(CvtF16 J, const int* __restrict__ flag){
  int b=blockIdx.x;
  int j=0;
  while(j<5 && J.blk0[j+1]<=b) j++;
  int i=(b-J.blk0[j])*256+threadIdx.x;
  if(i>=J.n[j]) return;
  bool f32m=*flag!=0;
  J.dst[j][i]=(f16)ldmix(J.src[j],i,f32m);
}

// W2[o, a*cin+c] = Wd[o,a]*Wf[o,c], all 5 layers in one launch
__global__ void k_w2all(W2J J, const int* __restrict__ flag){
  int b=blockIdx.x;
  int j=0;
  while(j<4 && J.blk0[j+1]<=b) j++;
  int i=(b-J.blk0[j])*256+threadIdx.x;
  if(i>=J.n[j]) return;
  int cin=J.cin[j]; int K3=3*cin;
  int o=i/K3; int rem=i-o*K3; int a=rem/cin; int c=rem-a*cin;
  float v=0.f;
  if(o<J.mid[j]){
    bool f32m=*flag!=0;
    v=ldmix(J.wd[j],(size_t)3*o+a,f32m)*ldmix(J.wf[j],(size_t)o*cin+c,f32m);
  }
  J.dst[j][i]=(f16)v;
}

// ---------------------------------------------------------------- FPS: 256 threads, DPP in-wave argmax (proven floor; see notes)
// FPS floor established empirically (rounds 1/3/4): coord-carry DPP +38%,
// 1-wave no-barrier +61%, LDS spin sync +50%. The 4-wave barrier structure is
// the floor. DO NOT touch the inner loop.
template<int P>
__global__ __launch_bounds__(256) void k_fps2(
    const float* __restrict__ xyz, int L, int N, int m,
    int c0,int c1,int c2,int c3, int T, float* __restrict__ anchors)
{
  __shared__ float4 ptsS[P*256];
  __shared__ unsigned long long keyS[2][4];
  __shared__ float ancS[3*1024];
  int prob=blockIdx.x;
  int b=prob/T, tt=prob%T;
  int f=(tt==0)?c0:(tt==1)?c1:(tt==2)?c2:c3;
  const float* src = xyz + ((size_t)(b*L+f))*N*3;
  float* anc = anchors + ((size_t)(b*T+tt))*m*3;
  int tid=threadIdx.x;
  for(int t=tid;t<N;t+=256)
    ptsS[t]=make_float4(src[3*t],src[3*t+1],src[3*t+2],0.f);
  __syncthreads();
  float px[P],py[P],pz[P],mind[P];
#pragma unroll
  for(int j=0;j<P;j++){
    float4 v=ptsS[tid+j*256];
    px[j]=v.x; py[j]=v.y; pz[j]=v.z; mind[j]=1e10f;
  }
  float4 p0=ptsS[0];
  float lx=p0.x, ly=p0.y, lz=p0.z;
  if(tid==0){ ancS[0]=lx; ancS[1]=ly; ancS[2]=lz; }
  int w=tid>>6;
  for(int it=1; it<m; ++it){
    float bv=-1.f; int bi=0;
#pragma unroll
    for(int j=0;j<P;j++){
#pragma clang fp contract(off)
      float dx=px[j]-lx, dy=py[j]-ly, dz=pz[j]-lz;
      float d2=dx*dx+dy*dy+dz*dz;
      float mv=mind[j]; if(d2<mv) mv=d2; mind[j]=mv;
      if(mv>bv){ bv=mv; bi=tid+j*256; }
    }
    unsigned int hi=__float_as_uint(bv);
    unsigned int lo=0xFFFFFFFFu-(unsigned)bi;
#define DPPSTEP(CTRL) { \
    unsigned int shi=(unsigned)__builtin_amdgcn_update_dpp(0,(int)hi,CTRL,0xF,0xF,true); \
    unsigned int slo=(unsigned)__builtin_amdgcn_update_dpp(0,(int)lo,CTRL,0xF,0xF,true); \
    bool g=(shi>hi)||(shi==hi&&slo>lo); \
    hi=g?shi:hi; lo=g?slo:lo; }
    DPPSTEP(0x111) DPPSTEP(0x112) DPPSTEP(0x114) DPPSTEP(0x118) DPPSTEP(0x142) DPPSTEP(0x143)
#undef DPPSTEP
    if((tid&63)==63)
      keyS[it&1][w]=((unsigned long long)hi<<32)|lo;
    __syncthreads();
    unsigned long long k0=keyS[it&1][0], k1=keyS[it&1][1];
    unsigned long long k2=keyS[it&1][2], k3=keyS[it&1][3];
    unsigned long long ka = k0>k1?k0:k1;
    unsigned long long kb = k2>k3?k2:k3;
    unsigned long long kk = ka>kb?ka:kb;
    int wi = (int)(0xFFFFFFFFu - (unsigned)(kk & 0xFFFFFFFFull));
    float4 wc = ptsS[wi];
    lx=wc.x; ly=wc.y; lz=wc.z;
    if(tid==0){ ancS[3*it]=lx; ancS[3*it+1]=ly; ancS[3*it+2]=lz; }
  }
  __syncthreads();
  for(int t=tid;t<3*m;t+=256) anc[t]=ancS[t];
}

// ---------------------------------------------------------------- Round-14: 3-way merged kernel
// [ FPS (layer lf) || outer/part0 (layer lo) || bq (layer lb) ]
// After layer-l's merged kernel completes, FPS_{l+2}, outer_l, and bq_{l+1}
// are all simultaneously ready (dependency walk in journal). Branch on
// blockIdx ranges; FPS blocks dispatched first (long pole, <=64 CUs), the
// other branches fill the otherwise-idle machine. bqAll double-buffered so
// bq (parity lb) writes while outer (parity lo) reads. All bodies are
// verbatim copies of proven kernels; only block-index remapping differs.
template<int P>
__global__ __launch_bounds__(256) void k_mega(
    const float* __restrict__ xyzF, int Lf, int Nf, int mf,
    int c0,int c1,int c2,int c3, int Tf, float* __restrict__ ancOut, int fpsN,
    int oN, int isP0,
    const f16* __restrict__ featsO, const float* __restrict__ XinO, const float* __restrict__ XoutO,
    const int* __restrict__ bqO, f16* __restrict__ GoN, int mO, int cinO, int NO, int LinO,
    size_t aBSO, int MO, Sched SO, const float* __restrict__ WdO, int midO, int ldO,
    const float* __restrict__ XinB, const float* __restrict__ XoutB, int* __restrict__ bqOut,
    int NB, int mB, float r2B, int LinB, size_t aBSB, int MB, Sched SB, int chunksB)
{
  __shared__ float4 ptsS[P*256];
  __shared__ unsigned long long keyS[2][4];
  __shared__ float sp[768];
  int bid=(int)blockIdx.x;
  if(bid < fpsN){
    // ---------------- FPS branch (round-0 proven body, direct anchor stores)
    int prob=bid;
    int b=prob/Tf, tt=prob%Tf;
    int f=(tt==0)?c0:(tt==1)?c1:(tt==2)?c2:c3;
    const float* src = xyzF + ((size_t)(b*Lf+f))*Nf*3;
    float* anc = ancOut + ((size_t)(b*Tf+tt))*mf*3;
    int tid=threadIdx.x;
    for(int t=tid;t<Nf;t+=256)
      ptsS[t]=make_float4(src[3*t],src[3*t+1],src[3*t+2],0.f);
    __syncthreads();
    float px[P],py[P],pz[P],mind[P];
#pragma unroll
    for(int j=0;j<P;j++){
      float4 v=ptsS[tid+j*256];
      px[j]=v.x; py[j]=v.y; pz[j]=v.z; mind[j]=1e10f;
    }
    float4 p0=ptsS[0];
    float lx=p0.x, ly=p0.y, lz=p0.z;
    if(tid==0){ anc[0]=lx; anc[1]=ly; anc[2]=lz; }
    int w=tid>>6;
    for(int it=1; it<mf; ++it){
      float bv=-1.f; int bi=0;
#pragma unroll
      for(int j=0;j<P;j++){
#pragma clang fp contract(off)
        float dx=px[j]-lx, dy=py[j]-ly, dz=pz[j]-lz;
        float d2=dx*dx+dy*dy+dz*dz;
        float mv=mind[j]; if(d2<mv) mv=d2; mind[j]=mv;
        if(mv>bv){ bv=mv; bi=tid+j*256; }
      }
      unsigned int hi=__float_as_uint(bv);
      unsigned int lo=0xFFFFFFFFu-(unsigned)bi;
#define DPPSTEP(CTRL) { \
      unsigned int shi=(unsigned)__builtin_amdgcn_update_dpp(0,(int)hi,CTRL,0xF,0xF,true); \
      unsigned int slo=(unsigned)__builtin_amdgcn_update_dpp(0,(int)lo,CTRL,0xF,0xF,true); \
      bool g=(shi>hi)||(shi==hi&&slo>lo); \
      hi=g?shi:hi; lo=g?slo:lo; }
      DPPSTEP(0x111) DPPSTEP(0x112) DPPSTEP(0x114) DPPSTEP(0x118) DPPSTEP(0x142) DPPSTEP(0x143)
#undef DPPSTEP
      if((tid&63)==63)
        keyS[it&1][w]=((unsigned long long)hi<<32)|lo;
      __syncthreads();
      unsigned long long k0=keyS[it&1][0], k1=keyS[it&1][1];
      unsigned long long k2=keyS[it&1][2], k3=keyS[it&1][3];
      unsigned long long ka = k0>k1?k0:k1;
      unsigned long long kb = k2>k3?k2:k3;
      unsigned long long kk = ka>kb?ka:kb;
      int wi = (int)(0xFFFFFFFFu - (unsigned)(kk & 0xFFFFFFFFull));
      float4 wc = ptsS[wi];
      lx=wc.x; ly=wc.y; lz=wc.z;
      if(tid==0){ anc[3*it]=lx; anc[3*it+1]=ly; anc[3*it+2]=lz; }
    }
  } else if(bid < fpsN + oN){
    int ob = bid - fpsN;
    if(isP0){
      // ---------------- part0 branch (layer 0, round-7 proven body)
      int quarter = MO>>2;
      int tt = ob / quarter, rb = ob - tt*quarter;
      int sub = threadIdx.x>>6;
      int o = threadIdx.x&63;
      int row = rb*4 + sub;
      int b = row/mO, mm = row - b*mO;
      const float* A = XoutO + (size_t)b*aBSO + (size_t)tt*mO*3 + (size_t)mm*3;
      float ax=A[0], ay=A[1], az=A[2];
      float w0=0,w1=0,w2=0;
      if(o<midO){ w0=WdO[3*o]; w1=WdO[3*o+1]; w2=WdO[3*o+2]; }
      int fr=SO.fi[tt];
      int nmask=NO-1;
      const int* id = bqO + ((size_t)tt*MO + row)*9;
      const float* Pb = XinO + ((size_t)b*LinO+fr)*(size_t)NO*3;
      float acc=0.f;
      for(int k=0;k<9;k++){
        int p=id[k] & nmask;
        const float* q = Pb + (size_t)p*3;
        float dx=q[0]-ax, dy=q[1]-ay, dz=q[2]-az;
        acc += dx*w0+dy*w1+dz*w2;
      }
      if(o<midO) GoN[(size_t)tt*MO*ldO + (size_t)row*ldO + o] = (f16)acc;
    } else {
      // ---------------- outer branch (layer lo, round-7 proven body)
      int cw2 = cinO>>1; if(cw2>256) cw2=256;
      int rpb = 256/cw2;
      int tid=threadIdx.x;
      int sub=tid/cw2, lc=tid-sub*cw2;
      int r=ob*rpb+sub;
      int Kp=3*cinO;
      int nmask=NO-1;
      int s=r/MO, mrow=r-s*MO;
      int b=mrow/mO, mm=mrow-b*mO;
      int tt=SO.tt[s], fr=SO.fi[s];
      const float* A0=XoutO+(size_t)b*aBSO+(size_t)tt*mO*3+(size_t)mm*3;
      float ax=A0[0],ay=A0[1],az=A0[2];
      const float* Pb=XinO+((size_t)b*LinO+fr)*(size_t)NO*3;
      const f16* Fb=featsO+(((size_t)b*LinO+fr)*(size_t)NO)*(size_t)cinO;
      const int* id=bqO+(size_t)r*9;
      int idx[9]; float d0[9],d1[9],d2a[9];
#pragma unroll
      for(int k=0;k<9;k++){
        int p=id[k]&nmask; idx[k]=p;
        const float* q=Pb+(size_t)p*3;
        d0[k]=q[0]-ax; d1[k]=q[1]-ay; d2a[k]=q[2]-az;
      }
      f16* Gr=GoN+(size_t)r*Kp;
      for(int cc=2*lc; cc<cinO; cc+=2*cw2){
        float a0=0,a1=0,a2=0,b0=0,b1=0,b2=0;
#pragma unroll
        for(int k=0;k<9;k++){
          f16x2 fv=*(const f16x2*)(Fb+(size_t)idx[k]*cinO+cc);
          float f0=(float)fv[0], f1=(float)fv[1];
          a0=fmaf(d0[k],f0,a0); b0=fmaf(d0[k],f1,b0);
          a1=fmaf(d1[k],f0,a1); b1=fmaf(d1[k],f1,b1);
          a2=fmaf(d2a[k],f0,a2); b2=fmaf(d2a[k],f1,b2);
        }
        f16x2 o0={(f16)a0,(f16)b0}, o1={(f16)a1,(f16)b1}, o2={(f16)a2,(f16)b2};
        *(f16x2*)(Gr+cc)=o0; *(f16x2*)(Gr+cinO+cc)=o1; *(f16x2*)(Gr+2*cinO+cc)=o2;
      }
    }
  } else {
    // ---------------- bq branch (layer lb, round-7 proven body)
    int fb=bid-fpsN-oN;
    int s=fb/(32*chunksB);
    int rem=fb-s*(32*chunksB);
    int b=rem/chunksB;
    int a=(rem-b*chunksB)*256+threadIdx.x;
    int tt=SB.tt[s], fr=SB.fi[s];
    const float* Pb = XinB + ((size_t)b*LinB + fr)*(size_t)NB*3;
    bool act = a<mB;
    float ax=0,ay=0,az=0;
    int* o = bqOut + ((size_t)s*MB + (size_t)b*mB + (size_t)(act?a:0))*9;
    if(act){
      const float* A=XoutB+(size_t)b*aBSB+(size_t)tt*mB*3+(size_t)a*3;
      ax=A[0]; ay=A[1]; az=A[2];
    }
    int cnt = act?0:9, first=0;
    for(int base=0; base<NB; base+=256){
      for(int t=threadIdx.x; t<768; t+=256) sp[t]=Pb[(size_t)base*3+t];
      __syncthreads();
      for(int q=0;q<256;q++){
#pragma clang fp contract(off)
        float dx=sp[3*q]-ax, dy=sp[3*q+1]-ay, dz=sp[3*q+2]-az;
        float d2=dx*dx+dy*dy+dz*dz;
        if(d2<r2B && cnt<9){
          int p=base+q;
          if(cnt==0) first=p;
          o[cnt]=p; cnt++;
        }
      }
      if(__syncthreads_and(cnt>=9)) break;
    }
    if(act){ for(int k=cnt;k<9;k++) o[k]=first; }
  }
}

// ---------------------------------------------------------------- G[r, a*cin+c] standalone (layer 5 only)
__global__ __launch_bounds__(256) void k_outer(
    const f16* __restrict__ feats, const float* __restrict__ Xin,
    const float* __restrict__ Xout, const int* __restrict__ bqAll,
    f16* __restrict__ Gh, int m, int cin, int N, int Lin,
    size_t aBS, int nmask, int M, Sched S)
{
  int cw2 = cin>>1; if(cw2>256) cw2=256;
  int rpb = 256/cw2;
  int tid=threadIdx.x;
  int sub=tid/cw2, lc=tid-sub*cw2;
  int r=blockIdx.x*rpb+sub;
  int Kp=3*cin;
  int s=r/M, mrow=r-s*M;
  int b=mrow/m, mm=mrow-b*m;
  int tt=S.tt[s], fr=S.fi[s];
  const float* A0=Xout+(size_t)b*aBS+(size_t)tt*m*3+(size_t)mm*3;
  float ax=A0[0],ay=A0[1],az=A0[2];
  const float* Pb=Xin+((size_t)b*Lin+fr)*(size_t)N*3;
  const f16* Fb=feats+(((size_t)b*Lin+fr)*(size_t)N)*(size_t)cin;
  const int* id=bqAll+(size_t)r*9;
  int idx[9]; float d0[9],d1[9],d2a[9];
#pragma unroll
  for(int k=0;k<9;k++){
    int p=id[k]&nmask; idx[k]=p;
    const float* q=Pb+(size_t)p*3;
    d0[k]=q[0]-ax; d1[k]=q[1]-ay; d2a[k]=q[2]-az;
  }
  f16* Gr=Gh+(size_t)r*Kp;
  for(int cc=2*lc; cc<cin; cc+=2*cw2){
    float a0=0,a1=0,a2=0,b0=0,b1=0,b2=0;
#pragma unroll
    for(int k=0;k<9;k++){
      f16x2 fv=*(const f16x2*)(Fb+(size_t)idx[k]*cin+cc);
      float f0=(float)fv[0], f1=(float)fv[1];
      a0=fmaf(d0[k],f0,a0); b0=fmaf(d0[k],f1,b0);
      a1=fmaf(d1[k],f0,a1); b1=fmaf(d1[k],f1,b1);
      a2=fmaf(d2a[k],f0,a2); b2=fmaf(d2a[k],f1,b2);
    }
    f16x2 o0={(f16)a0,(f16)b0}, o1={(f16)a1,(f16)b1}, o2={(f16)a2,(f16)b2};
    *(f16x2*)(Gr+cc)=o0; *(f16x2*)(Gr+cin+cc)=o1; *(f16x2*)(Gr+2*cin+cc)=o2;
  }
}

// ---------------------------------------------------------------- pair GEMM: nf[tt][mrow, j*mid+col] = G @ W2^T (batched)
__global__ __launch_bounds__(256) void k_pg(
    const f16* __restrict__ Gh, const f16* __restrict__ W2,
    f16* __restrict__ nfh, int Kp, int mid, int C, int M, Sched S)
{
  __shared__ f16 As[128*40];
  __shared__ f16 Bs[128*40];
  int tid=threadIdx.x;
  int lane=tid&63, w=tid>>6;
  int quad=lane>>4, l15=lane&15;
  int rowOff=(w>>1)*64, colOff=(w&1)*64;
  int rowBase=blockIdx.x*128, colBase=blockIdx.y*128;
  f32x4 acc[4][4];
#pragma unroll
  for(int i=0;i<4;i++)
#pragma unroll
    for(int j=0;j<4;j++) acc[i][j]=(f32x4){0.f,0.f,0.f,0.f};
  int nct=Kp>>5;
  int srow=tid>>1, shalf=tid&1;
  for(int ct=0;ct<nct;ct++){
    __syncthreads();
    {
      const uint4* s=(const uint4*)(Gh+(size_t)(rowBase+srow)*Kp+(ct<<5)+(shalf<<4));
      uint4 u0=s[0], u1=s[1];
      *(uint4*)(As + srow*40 + (shalf<<4))     = u0;
      *(uint4*)(As + srow*40 + (shalf<<4) + 8) = u1;
    }
    {
      const uint4* s=(const uint4*)(W2+(size_t)(colBase+srow)*Kp+(ct<<5)+(shalf<<4));
      uint4 u0=s[0], u1=s[1];
      *(uint4*)(Bs + srow*40 + (shalf<<4))     = u0;
      *(uint4*)(Bs + srow*40 + (shalf<<4) + 8) = u1;
    }
    __syncthreads();
    f16x8 af[4], bf4[4];
#pragma unroll
    for(int rt=0;rt<4;rt++) af[rt]=*(const f16x8*)(As + (rowOff+rt*16+l15)*40 + quad*8);
#pragma unroll
    for(int ctl=0;ctl<4;ctl++) bf4[ctl]=*(const f16x8*)(Bs + (colOff+ctl*16+l15)*40 + quad*8);
#pragma unroll
    for(int rt=0;rt<4;rt++)
#pragma unroll
      for(int ctl=0;ctl<4;ctl++)
        acc[rt][ctl]=__builtin_amdgcn_mfma_f32_16x16x32_f16(af[rt],bf4[ctl],acc[rt][ctl],0,0,0);
  }
#pragma unroll
  for(int rt=0;rt<4;rt++){
#pragma unroll
    for(int r=0;r<4;r++){
      int row=rowBase+rowOff+rt*16+quad*4+r;
      int s=row/M, mrow=row-s*M;
      int tt=S.tt[s], j=S.jj[s];
      f16* base = nfh + (size_t)tt*M*C + (size_t)mrow*C + j*mid;
#pragma unroll
      for(int ctl=0;ctl<4;ctl++){
        int col=colBase+colOff+ctl*16+l15;
        if(col<mid) base[col]=(f16)acc[rt][ctl][r];
      }
    }
  }
}

// ---------------------------------------------------------------- BN stats (batched over tt, jmask skips unwritten slices)
__global__ void k_bnstat(const f16* __restrict__ nfh, int M, int C, float* __restrict__ sumsL,
                         int mid, int4 jm, int sumStride){
  int c = blockIdx.x*256 + threadIdx.x;
  if(c>=C) return;
  int tt=blockIdx.z;
  int jmask = (tt==0)?jm.x:(tt==1)?jm.y:(tt==2)?jm.z:jm.w;
  int j=c/mid;
  if(!((jmask>>j)&1)) return;
  const f16* base=nfh+(size_t)tt*M*C;
  int rows = M>>5;
  int r0 = blockIdx.y*rows, r1 = r0+rows;
  float s=0.f, s2=0.f;
  for(int r=r0;r<r1;r++){
    float v=(float)base[(size_t)r*C+c];
    s+=v; s2+=v*v;
  }
  atomicAdd(&sumsL[tt*sumStride+c], s);
  atomicAdd(&sumsL[tt*sumStride+C+c], s2);
}

__global__ void k_bnfin(const float* __restrict__ sumsL, float* __restrict__ scbAll,
                        int C, int M, int mid, int4 jm, int sumStride, int scbStride){
  int c = blockIdx.x*256 + threadIdx.x;
  if(c>=C) return;
  int tt=blockIdx.y;
  int jmask = (tt==0)?jm.x:(tt==1)?jm.y:(tt==2)?jm.z:jm.w;
  float* scb=scbAll+(size_t)tt*scbStride;
  int j=c/mid;
  if(!((jmask>>j)&1)){ scb[c]=0.f; scb[C+c]=0.f; return; }
  float mean=sumsL[tt*sumStride+c]/(float)M;
  float var=sumsL[tt*sumStride+C+c]/(float)M - mean*mean;
  if(var<0.f) var=0.f;
  float rs=1.0f/sqrtf(var+1e-5f);
  scb[c]=rs; scb[C+c]=-mean*rs;
}

// ---------------------------------------------------------------- MFMA GEMM, A=f16 (opt fused BN+ReLU on A), batched over tt
template<bool RELU, bool DYN, bool BNA>
__global__ __launch_bounds__(256) void k_gemm_mfma(
    const f16* __restrict__ Ag, const f16* __restrict__ Bh,
    const float* __restrict__ bias, void* __restrict__ out,
    int K, int N, int mloc, size_t oBS, size_t ttA, size_t ttO,
    const int* __restrict__ oflag, const float* __restrict__ scbAll, int scbStride)
{
  __shared__ f16 As[128*40];
  __shared__ f16 Bs[128*40];
  int tid=threadIdx.x;
  int lane=tid&63, w=tid>>6;
  int quad=lane>>4, l15=lane&15;
  int rowOff=(w>>1)*64, colOff=(w&1)*64;
  int rowBase=blockIdx.x*128, colBase=blockIdx.y*128;
  int tt=blockIdx.z;
  const f16* A0=Ag+(size_t)tt*ttA;
  const float* scb = BNA ? (scbAll+(size_t)tt*scbStride) : nullptr;
  f32x4 acc[4][4];
#pragma unroll
  for(int i=0;i<4;i++)
#pragma unroll
    for(int j=0;j<4;j++) acc[i][j]=(f32x4){0.f,0.f,0.f,0.f};
  int nct=K>>5;
  int srow=tid>>1, shalf=tid&1;
  for(int ct=0;ct<nct;ct++){
    __syncthreads();
    {
      int c0g=(ct<<5)+(shalf<<4);
      const f16* src=A0+(size_t)(rowBase+srow)*K+c0g;
      if(BNA){
        f16x8 x0=((const f16x8*)src)[0], x1=((const f16x8*)src)[1];
        f16x8 h0,h1;
#pragma unroll
        for(int q=0;q<8;q++){
          h0[q]=(f16)fmaxf(fmaf((float)x0[q],scb[c0g+q],scb[K+c0g+q]),0.f);
          h1[q]=(f16)fmaxf(fmaf((float)x1[q],scb[c0g+8+q],scb[K+c0g+8+q]),0.f);
        }
        *(f16x8*)(As+srow*40+(shalf<<4))=h0;
        *(f16x8*)(As+srow*40+(shalf<<4)+8)=h1;
      } else {
        const uint4* s=(const uint4*)src;
        uint4 u0=s[0],u1=s[1];
        *(uint4*)(As+srow*40+(shalf<<4))=u0;
        *(uint4*)(As+srow*40+(shalf<<4)+8)=u1;
      }
    }
    {
      const uint4* s=(const uint4*)(Bh+(size_t)(colBase+srow)*K+(ct<<5)+(shalf<<4));
      uint4 u0=s[0], u1=s[1];
      *(uint4*)(Bs + srow*40 + (shalf<<4))     = u0;
      *(uint4*)(Bs + srow*40 + (shalf<<4) + 8) = u1;
    }
    __syncthreads();
    f16x8 af[4], bf4[4];
#pragma unroll
    for(int rt=0;rt<4;rt++) af[rt]=*(const f16x8*)(As + (rowOff+rt*16+l15)*40 + quad*8);
#pragma unroll
    for(int ctl=0;ctl<4;ctl++) bf4[ctl]=*(const f16x8*)(Bs + (colOff+ctl*16+l15)*40 + quad*8);
#pragma unroll
    for(int rt=0;rt<4;rt++)
#pragma unroll
      for(int ctl=0;ctl<4;ctl++)
        acc[rt][ctl]=__builtin_amdgcn_mfma_f32_16x16x32_f16(af[rt],bf4[ctl],acc[rt][ctl],0,0,0);
  }
  bool f32m = DYN ? (*oflag!=0) : true;
#pragma unroll
  for(int rt=0;rt<4;rt++){
#pragma unroll
    for(int r=0;r<4;r++){
      int row=rowBase+rowOff+rt*16+quad*4+r;
      int rb=row/mloc, rm=row-rb*mloc;
      size_t obase=(size_t)rb*oBS + (size_t)tt*ttO + (size_t)rm*N;
#pragma unroll
      for(int ctl=0;ctl<4;ctl++){
        int col=colBase+colOff+ctl*16+l15;
        float v=acc[rt][ctl][r];
        if(bias) v+=bias[col];
        if(RELU) v=fmaxf(v,0.f);
        if(DYN){
          if(!f32m) ((bf16*)out)[obase+col]=__float2bfloat16(v);
          else      ((float*)out)[obase+col]=v;
        } else {
          ((f16*)out)[obase+col]=(f16)v;
        }
      }
    }
  }
}

// ---------------------------------------------------------------- f32 GEMM (layer 0 temporal, K=45), BN fused, batched over tt
__global__ __launch_bounds__(256) void k_gemm0(
    const f16* __restrict__ nfh, const float* __restrict__ Wg,
    f16* __restrict__ out, int M, int K, int N, int mloc, size_t oBS, size_t ttO,
    const float* __restrict__ scbAll, int scbStride)
{
  __shared__ alignas(16) float As[16][64];
  __shared__ alignas(16) float Bs[16][64];
  int tid=threadIdx.x, tx=tid&15, ty=tid>>4;
  int rowBase=blockIdx.x*64, colBase=blockIdx.y*64;
  int tt=blockIdx.z;
  const f16* A0=nfh+(size_t)tt*M*K;
  const float* scb=scbAll+(size_t)tt*scbStride;
  float acc[4][4];
#pragma unroll
  for(int i=0;i<4;i++)
#pragma unroll
    for(int j=0;j<4;j++) acc[i][j]=0.f;
  int lrow=tid&63, lcq=tid>>6;
  int nct=(K+15)>>4;
  for(int ct=0;ct<nct;ct++){
    __syncthreads();
    {
      int r=rowBase+lrow, c0=(ct<<4)+(lcq<<2);
#pragma unroll
      for(int q=0;q<4;q++){
        int c=c0+q;
        As[(lcq<<2)+q][lrow] = (c<K)? fmaxf(fmaf((float)A0[(size_t)r*K+c],scb[c],scb[K+c]),0.f) : 0.f;
      }
    }
    {
      int og=colBase+lrow, c0=(ct<<4)+(lcq<<2);
#pragma unroll
      for(int q=0;q<4;q++){
        int c=c0+q;
        Bs[(lcq<<2)+q][lrow] = (c<K)? Wg[(size_t)og*K+c] : 0.f;
      }
    }
    __syncthreads();
#pragma unroll
    for(int c=0;c<16;c++){
      float4 a4=*(const float4*)&As[c][ty<<2];
      float av[4]={a4.x,a4.y,a4.z,a4.w};
      float4 b4=*(const float4*)&Bs[c][tx<<2];
      float bw[4]={b4.x,b4.y,b4.z,b4.w};
#pragma unroll
      for(int i=0;i<4;i++)
#pragma unroll
        for(int j=0;j<4;j++) acc[i][j]+=av[i]*bw[j];
    }
  }
#pragma unroll
  for(int i=0;i<4;i++){
    int r=rowBase+(ty<<2)+i;
    int rb=r/mloc, rm=r-rb*mloc;
    size_t obase=(size_t)rb*oBS + (size_t)blockIdx.z*ttO + (size_t)rm*N;
#pragma unroll
    for(int j=0;j<4;j++){
      int o=colBase+(tx<<2)+j;
      out[obase+o]=(f16)fmaxf(acc[i][j],0.f);
    }
  }
}

// ---------------------------------------------------------------- host
extern "C" void kernel_launch(void* const* d_in, const int* in_sizes, int n_in,
                              void* d_out, int out_size, void* d_ws, size_t ws_size,
                              hipStream_t stream) {
  (void)in_sizes; (void)n_in; (void)out_size; (void)ws_size;

  const int di[6] = {2,4,7,10,13,16};
  const int fi6[6] = {-1,5,8,11,14,17};
  const int ti[6] = {3,6,9,12,15,18};

  const int midv[6]={45,96,192,384,768,1536};
  const int midp[6]={0,128,256,384,768,1536};
  const int cinv[6]={0,64,128,256,512,1024};
  const int coutv[6]={64,128,256,512,1024,2048};
  const int tkv[6]={1,3,3,3,3,1};
  const int Nv[6]={2048,1024,512,512,256,256};
  const int mv[6]={1024,512,512,256,256,128};
  const int Lv[6]={4,4,2,2,1,1};
  const int Tv[6]={4,2,2,1,1,1};
  const float rrv[6]={1.5f,3.f,3.f,6.f,6.f,6.f};

  float* ws=(float*)d_ws;
  size_t off=0;
  auto A=[&](size_t n)->float*{ float* p=ws+off; off+=(n+63)&~(size_t)63; return p; };
  auto Ah=[&](size_t n)->f16*{ return (f16*)A((n+1)/2); };

  int* flag=(int*)A(64);

  f16* W2h[6]; W2h[0]=nullptr;
  for(int l=1;l<6;l++) W2h[l]=Ah((size_t)midp[l]*3*cinv[l]);
  f16* Wth[6]; Wth[0]=nullptr;
  for(int l=1;l<6;l++) Wth[l]=Ah((size_t)coutv[l]*tkv[l]*midv[l]);
  float* Wd0=A(135);
  float* Wt0=A(2880);
  f16* fcwh=Ah(2097152);
  float* fcb=A(1024);

  float* X[7];
  X[0]=A(786432);
  for(int l=0;l<6;l++) X[l+1]=A((size_t)32*Tv[l]*mv[l]*3);

  f16* FA=Ah(8388608);
  f16* FB=Ah(8388608);
  f16* F[7]; F[0]=nullptr;
  for(int l=0;l<6;l++) F[l+1]=(l%2==0)?FA:FB;

  f16* nfh=Ah(18874368);           // max T*M*C (l2/l4: 18.87M)
  float* sumsAll=A(11*4608);
  float* scbAll=A(4*4608);
  f16* Gh=Ah(25165824);            // max SLOTS*M*Kp (l2: 25.2M)
  int* bqA=(int*)A(1179648);       // double-buffered bq indices (parity by layer)
  int* bqB=(int*)A(1179648);
  int* bqBuf[2]={bqA,bqB};

  // ---- setup: detect+zero (fused) + converts + W2 (4 dispatches)
  {
    int zn=11*4608;
    int zb=(zn+255)/256;
    k_detect<<<dim3(1+zb),dim3(256),0,stream>>>((const unsigned int*)d_in[0], 4096, flag, sumsAll, zn);
  }
  {
    CvtF32 J;
    J.src[0]=d_in[0];  J.dst[0]=X[0];  J.n[0]=786432;
    J.src[1]=d_in[3];  J.dst[1]=Wt0;   J.n[1]=2880;
    J.src[2]=d_in[20]; J.dst[2]=fcb;   J.n[2]=1024;
    J.src[3]=d_in[2];  J.dst[3]=Wd0;   J.n[3]=135;
    J.blk0[0]=0; J.blk0[1]=3072; J.blk0[2]=3084; J.blk0[3]=3088; J.blk0[4]=3089;
    k_cvt_all<<<dim3(3089),dim3(256),0,stream>>>(J,flag);
  }
  {
    CvtF16 J;
    int ns[6]={36864,147456,589824,2359296,3145728,2097152};
    const void* ss[6]={d_in[ti[1]],d_in[ti[2]],d_in[ti[3]],d_in[ti[4]],d_in[ti[5]],d_in[19]};
    f16* ds[6]={Wth[1],Wth[2],Wth[3],Wth[4],Wth[5],fcwh};
    int bp=0;
    for(int j2=0;j2<6;j2++){ J.src[j2]=ss[j2]; J.dst[j2]=ds[j2]; J.n[j2]=ns[j2]; J.blk0[j2]=bp; bp+=(ns[j2]+255)/256; }
    J.blk0[6]=bp;
    k_cvth_all<<<dim3((unsigned)bp),dim3(256),0,stream>>>(J,flag);
  }
  {
    W2J J;
    int bp=0;
    for(int l=1;l<6;l++){
      int j2=l-1;
      J.wd[j2]=d_in[di[l]]; J.wf[j2]=d_in[fi6[l]]; J.dst[j2]=W2h[l];
      J.mid[j2]=midv[l]; J.cin[j2]=cinv[l]; J.n[j2]=midp[l]*3*cinv[l];
      J.blk0[j2]=bp; bp+=(J.n[j2]+255)/256;
    }
    J.blk0[5]=bp;
    k_w2all<<<dim3((unsigned)bp),dim3(256),0,stream>>>(J,flag);
  }

  // ---- schedule tables
  const int SLOTS[6]={4,5,4,2,1,1};
  const int sTT[6][5]={{0,1,2,3,0},{0,0,1,1,1},{0,0,1,1,0},{0,0,0,0,0},{0,0,0,0,0},{0,0,0,0,0}};
  const int sFI[6][5]={{0,1,2,3,0},{0,1,1,2,3},{0,1,0,1,0},{0,1,0,0,0},{0,0,0,0,0},{0,0,0,0,0}};
  const int sJJ[6][5]={{0,0,0,0,0},{1,2,0,1,2},{1,2,0,1,0},{1,2,0,0,0},{1,0,0,0,0},{0,0,0,0,0}};
  const int4 jm4[6]={{1,1,1,1},{6,7,0,0},{6,3,0,0},{6,0,0,0},{2,0,0,0},{1,0,0,0}};
  const int Tcenters[6][4]={{0,1,2,3},{0,2,0,0},{0,1,0,0},{0,0,0,0},{0,0,0,0},{0,0,0,0}};
  const int slotBase[6]={0,4,6,8,9,10};

  Sched Sl[6];
  for(int l=0;l<6;l++)
    for(int s=0;s<5;s++){ Sl[l].tt[s]=sTT[l][s]; Sl[l].fi[s]=sFI[l][s]; Sl[l].jj[s]=sJJ[l][s]; }

  auto bqGeo=[&](int lb, int& bqN, int& chunks){
    chunks=(mv[lb]+255)>>8;
    bqN=SLOTS[lb]*32*chunks;
  };

  // FPS_0 (standalone; proven kernel, untouched)
  k_fps2<8><<<dim3(128),dim3(256),0,stream>>>(X[0],4,2048,1024,0,1,2,3,4,X[1]);

  // pre-loop merged: [FPS_1 || bq_0 -> bqA]
  {
    int bqN,chunks; bqGeo(0,bqN,chunks);
    int fpsN=32*Tv[1];
    k_mega<4><<<dim3((unsigned)(fpsN+bqN)),dim3(256),0,stream>>>(
        X[1],Lv[1],Nv[1],mv[1],Tcenters[1][0],Tcenters[1][1],Tcenters[1][2],Tcenters[1][3],Tv[1],X[2],fpsN,
        0,0, FA,X[0],X[1],bqA,nfh,mv[0],1,Nv[0],Lv[0],(size_t)Tv[0]*mv[0]*3,32*mv[0],Sl[0],Wd0,1,1,
        X[0],X[1],bqBuf[0],Nv[0],mv[0],rrv[0]*rrv[0],Lv[0],(size_t)Tv[0]*mv[0]*3,32*mv[0],Sl[0],chunks);
  }

  for(int l=0;l<6;l++){
    int N=Nv[l], m=mv[l], Lin=Lv[l], T=Tv[l], cin=cinv[l], mid=midv[l];
    int C=tkv[l]*midv[l], M=32*m, cout=coutv[l];
    size_t aBS=(size_t)T*m*3;

    if(l<5){
      // merged: [FPS_{l+2} (if l<=3) || outer_l/part0_l (reads bqBuf[l&1]) || bq_{l+1} -> bqBuf[(l+1)&1]]
      int lb=l+1;
      int bqN,chunksB; bqGeo(lb,bqN,chunksB);
      size_t aBSB=(size_t)Tv[lb]*mv[lb]*3;
      int MB=32*mv[lb];
      int oN, isP0;
      if(l==0){ isP0=1; oN=M; }                       // (M/4)*4 part0 blocks
      else{
        isP0=0;
        int cw2=cin>>1; if(cw2>256) cw2=256;
        int rpb=256/cw2;
        oN=SLOTS[l]*M/rpb;
      }
      const f16* featsO=(l==0)?FA:F[l];
      f16* GoN=(l==0)?nfh:Gh;
      int fpsN=0, lf=l+2;
      if(lf<=5) fpsN=32*Tv[lf];
      int a0=0,a1=0,a2=0,a3=0;
      if(lf<=5){ a0=Tcenters[lf][0]; a1=Tcenters[lf][1]; a2=Tcenters[lf][2]; a3=Tcenters[lf][3]; }
      const float* xyzF=(lf<=5)?X[lf]:X[5];
      float* ancOut=(lf<=5)?X[lf+1]:X[6];
      int Lf=(lf<=5)?Lv[lf]:1, Nf=(lf<=5)?Nv[lf]:256, mf=(lf<=5)?mv[lf]:1, Tf=(lf<=5)?Tv[lf]:1;
      dim3 g((unsigned)(fpsN+oN+bqN)), blk(256);
      if(lf<=5 && Nv[lf]==512)
        k_mega<2><<<g,blk,0,stream>>>(xyzF,Lf,Nf,mf,a0,a1,a2,a3,Tf,ancOut,fpsN,
            oN,isP0, featsO,X[l],X[l+1],bqBuf[l&1],GoN,m,cin,N,Lin,aBS,M,Sl[l],Wd0,mid,C,
            X[lb],X[lb+1],bqBuf[lb&1],Nv[lb],mv[lb],rrv[lb]*rrv[lb],Lv[lb],aBSB,MB,Sl[lb],chunksB);
      else
        k_mega<1><<<g,blk,0,stream>>>(xyzF,Lf,Nf,mf,a0,a1,a2,a3,Tf,ancOut,fpsN,
            oN,isP0, featsO,X[l],X[l+1],bqBuf[l&1],GoN,m,cin,N,Lin,aBS,M,Sl[l],Wd0,mid,C,
            X[lb],X[lb+1],bqBuf[lb&1],Nv[lb],mv[lb],rrv[lb]*rrv[lb],Lv[lb],aBSB,MB,Sl[lb],chunksB);
    } else {
      // l==5: outer standalone (reads bqBuf[1])
      int cw2=cin>>1; if(cw2>256) cw2=256;
      int rpb=256/cw2;
      k_outer<<<dim3((unsigned)(SLOTS[l]*M/rpb)),256,0,stream>>>(
          F[l],X[l],X[l+1],bqBuf[l&1],Gh,m,cin,N,Lin,aBS,N-1,M,Sl[l]);
    }

    if(l>=1)
      k_pg<<<dim3((unsigned)(SLOTS[l]*M/128),(unsigned)(midp[l]/128)),256,0,stream>>>(
          Gh,W2h[l],nfh,3*cin,mid,C,M,Sl[l]);

    float* sumsL=sumsAll+(size_t)slotBase[l]*4608;
    k_bnstat<<<dim3((C+255)/256,32,T),256,0,stream>>>(nfh,M,C,sumsL,mid,jm4[l],4608);
    k_bnfin<<<dim3((C+255)/256,T),256,0,stream>>>(sumsL,scbAll,C,M,mid,jm4[l],4608,4608);

    size_t oBS=(size_t)T*m*cout;
    size_t ttO=(size_t)m*cout;
    if(l==0)
      k_gemm0<<<dim3(M/64,1,4),256,0,stream>>>(nfh,Wt0,F[1],M,C,cout,m,oBS,ttO,scbAll,4608);
    else if(l<5)
      k_gemm_mfma<true,false,true><<<dim3(M/128,cout/128,T),256,0,stream>>>(
          nfh,Wth[l],nullptr,F[l+1],C,cout,m,oBS,(size_t)M*C,ttO,nullptr,scbAll,4608);
    else
      k_gemm_mfma<false,false,true><<<dim3(M/128,cout/128,T),256,0,stream>>>(
          nfh,Wth[l],nullptr,F[l+1],C,cout,m,oBS,(size_t)M*C,ttO,nullptr,scbAll,4608);
  }

  // final FC (A=F[6] f16, contiguous 4096x2048) -> d_out (bf16 or f32 per flag)
  k_gemm_mfma<false,true,false><<<dim3(4096/128,1024/128,1),256,0,stream>>>(
      F[6],fcwh,fcb,d_out,2048,1024,128,(size_t)128*1024,0,0,flag,nullptr,0);
}

// Round 10
// 2191.096 us; speedup vs baseline: 1.7544x; 1.2244x over previous
//
#include <hip/hip_runtime.h>
#include <hip/hip_bf16.h>
#include <math.h>

typedef __hip_bfloat16 bf16;
typedef _Float16 f16;
typedef _Float16 f16x2 __attribute__((ext_vector_type(2)));
typedef _Float16 f16x8 __attribute__((ext_vector_type(8)));
typedef float f32x4 __attribute__((ext_vector_type(4)));

struct Sched { int tt[5]; int fi[5]; int jj[5]; };
struct CvtF32 { const void* src[4]; float* dst[4]; int n[4]; int blk0[5]; };
struct CvtF16 { const void* src[6]; f16* dst[6]; int n[6]; int blk0[7]; };
struct W2J { const void* wd[5]; const void* wf[5]; f16* dst[5]; int mid[5]; int cin[5]; int n[5]; int blk0[6]; };

// ---------------------------------------------------------------- dtype detect + zero sums (fused)
__global__ void k_detect(const unsigned int* __restrict__ w, int nwords, int* __restrict__ flag,
                         float* __restrict__ zp, int zn){
  if(blockIdx.x==0){
    __shared__ int cnt;
    if(threadIdx.x==0) cnt=0;
    __syncthreads();
    int local=0;
    for(int i=threadIdx.x;i<nwords;i+=256){
      unsigned int v=w[i];
      int e=(v>>7)&0xFF;
      if(e>=0xC0) local++;
    }
    atomicAdd(&cnt, local);
    __syncthreads();
    if(threadIdx.x==0) flag[0] = (cnt > (nwords>>3)) ? 1 : 0;
  } else {
    int i=(blockIdx.x-1)*256+threadIdx.x;
    if(i<zn) zp[i]=0.f;
  }
}

__device__ inline float ldmix(const void* p, size_t i, bool f32m){
  return f32m ? ((const float*)p)[i] : __bfloat162float(((const bf16*)p)[i]);
}

// ---------------------------------------------------------------- f32 converts (X[0] + small weights; must precede FPS_0)
__global__ void k_cvt_all(CvtF32 J, const int* __restrict__ flag){
  int b=blockIdx.x;
  int j=0;
  while(j<3 && J.blk0[j+1]<=b) j++;
  int i=(b-J.blk0[j])*256+threadIdx.x;
  if(i>=J.n[j]) return;
  bool f32m=*flag!=0;
  J.dst[j][i]=ldmix(J.src[j],i,f32m);
}

// ---------------------------------------------------------------- Round-15: FPS_0 merged with weight converts
// [ FPS layer 0 (128 blocks, round-2 proven body) || cvth (f16 weight cvt) || w2all ]
// cvth/w2all outputs are first consumed at pg_1/gemm_1 (far later) -> free to
// ride under FPS_0's 568us. Bodies verbatim from the proven standalone kernels.
__global__ __launch_bounds__(256) void k_fps0m(
    const float* __restrict__ xyz, float* __restrict__ anchors,
    CvtF16 J16, W2J JW, const int* __restrict__ flag, int cvtB)
{
  __shared__ float4 ptsS[8*256];
  __shared__ unsigned long long keyS[2][4];
  __shared__ float ancS[3*1024];
  int bid=(int)blockIdx.x;
  if(bid<128){
    const int L=4, N=2048, m=1024, T=4;
    int prob=bid;
    int b=prob/T, tt=prob%T;
    int f=tt;
    const float* src = xyz + ((size_t)(b*L+f))*N*3;
    float* anc = anchors + ((size_t)(b*T+tt))*m*3;
    int tid=threadIdx.x;
    for(int t=tid;t<N;t+=256)
      ptsS[t]=make_float4(src[3*t],src[3*t+1],src[3*t+2],0.f);
    __syncthreads();
    float px[8],py[8],pz[8],mind[8];
#pragma unroll
    for(int j=0;j<8;j++){
      float4 v=ptsS[tid+j*256];
      px[j]=v.x; py[j]=v.y; pz[j]=v.z; mind[j]=1e10f;
    }
    float4 p0=ptsS[0];
    float lx=p0.x, ly=p0.y, lz=p0.z;
    if(tid==0){ ancS[0]=lx; ancS[1]=ly; ancS[2]=lz; }
    int w=tid>>6;
    for(int it=1; it<m; ++it){
      float bv=-1.f; int bi=0;
#pragma unroll
      for(int j=0;j<8;j++){
#pragma clang fp contract(off)
        float dx=px[j]-lx, dy=py[j]-ly, dz=pz[j]-lz;
        float d2=dx*dx+dy*dy+dz*dz;
        float mv=mind[j]; if(d2<mv) mv=d2; mind[j]=mv;
        if(mv>bv){ bv=mv; bi=tid+j*256; }
      }
      unsigned int hi=__float_as_uint(bv);
      unsigned int lo=0xFFFFFFFFu-(unsigned)bi;
#define DPPSTEP(CTRL) { \
      unsigned int shi=(unsigned)__builtin_amdgcn_update_dpp(0,(int)hi,CTRL,0xF,0xF,true); \
      unsigned int slo=(unsigned)__builtin_amdgcn_update_dpp(0,(int)lo,CTRL,0xF,0xF,true); \
      bool g=(shi>hi)||(shi==hi&&slo>lo); \
      hi=g?shi:hi; lo=g?slo:lo; }
      DPPSTEP(0x111) DPPSTEP(0x112) DPPSTEP(0x114) DPPSTEP(0x118) DPPSTEP(0x142) DPPSTEP(0x143)
#undef DPPSTEP
      if((tid&63)==63)
        keyS[it&1][w]=((unsigned long long)hi<<32)|lo;
      __syncthreads();
      unsigned long long k0=keyS[it&1][0], k1=keyS[it&1][1];
      unsigned long long k2=keyS[it&1][2], k3=keyS[it&1][3];
      unsigned long long ka = k0>k1?k0:k1;
      unsigned long long kb = k2>k3?k2:k3;
      unsigned long long kk = ka>kb?ka:kb;
      int wi = (int)(0xFFFFFFFFu - (unsigned)(kk & 0xFFFFFFFFull));
      float4 wc = ptsS[wi];
      lx=wc.x; ly=wc.y; lz=wc.z;
      if(tid==0){ ancS[3*it]=lx; ancS[3*it+1]=ly; ancS[3*it+2]=lz; }
    }
    __syncthreads();
    for(int t=tid;t<3*m;t+=256) anc[t]=ancS[t];
  } else if(bid < 128+cvtB){
    int b=bid-128;
    int j=0;
    while(j<5 && J16.blk0[j+1]<=b) j++;
    int i=(b-J16.blk0[j])*256+threadIdx.x;
    if(i>=J16.n[j]) return;
    bool f32m=*flag!=0;
    J16.dst[j][i]=(f16)ldmix(J16.src[j],i,f32m);
  } else {
    int b=bid-128-cvtB;
    int j=0;
    while(j<4 && JW.blk0[j+1]<=b) j++;
    int i=(b-JW.blk0[j])*256+threadIdx.x;
    if(i>=JW.n[j]) return;
    int cin=JW.cin[j]; int K3=3*cin;
    int o=i/K3; int rem=i-o*K3; int a=rem/cin; int c=rem-a*cin;
    float v=0.f;
    if(o<JW.mid[j]){
      bool f32m=*flag!=0;
      v=ldmix(JW.wd[j],(size_t)3*o+a,f32m)*ldmix(JW.wf[j],(size_t)o*cin+c,f32m);
    }
    JW.dst[j][i]=(f16)v;
  }
}

// ---------------------------------------------------------------- 3-way merged kernel (round-14 proven)
// [ FPS (layer lf) || outer/part0 (layer lo) || bq (layer lb) ]
template<int P>
__global__ __launch_bounds__(256) void k_mega(
    const float* __restrict__ xyzF, int Lf, int Nf, int mf,
    int c0,int c1,int c2,int c3, int Tf, float* __restrict__ ancOut, int fpsN,
    int oN, int isP0,
    const f16* __restrict__ featsO, const float* __restrict__ XinO, const float* __restrict__ XoutO,
    const int* __restrict__ bqO, f16* __restrict__ GoN, int mO, int cinO, int NO, int LinO,
    size_t aBSO, int MO, Sched SO, const float* __restrict__ WdO, int midO, int ldO,
    const float* __restrict__ XinB, const float* __restrict__ XoutB, int* __restrict__ bqOut,
    int NB, int mB, float r2B, int LinB, size_t aBSB, int MB, Sched SB, int chunksB)
{
  __shared__ float4 ptsS[P*256];
  __shared__ unsigned long long keyS[2][4];
  __shared__ float sp[768];
  int bid=(int)blockIdx.x;
  if(bid < fpsN){
    int prob=bid;
    int b=prob/Tf, tt=prob%Tf;
    int f=(tt==0)?c0:(tt==1)?c1:(tt==2)?c2:c3;
    const float* src = xyzF + ((size_t)(b*Lf+f))*Nf*3;
    float* anc = ancOut + ((size_t)(b*Tf+tt))*mf*3;
    int tid=threadIdx.x;
    for(int t=tid;t<Nf;t+=256)
      ptsS[t]=make_float4(src[3*t],src[3*t+1],src[3*t+2],0.f);
    __syncthreads();
    float px[P],py[P],pz[P],mind[P];
#pragma unroll
    for(int j=0;j<P;j++){
      float4 v=ptsS[tid+j*256];
      px[j]=v.x; py[j]=v.y; pz[j]=v.z; mind[j]=1e10f;
    }
    float4 p0=ptsS[0];
    float lx=p0.x, ly=p0.y, lz=p0.z;
    if(tid==0){ anc[0]=lx; anc[1]=ly; anc[2]=lz; }
    int w=tid>>6;
    for(int it=1; it<mf; ++it){
      float bv=-1.f; int bi=0;
#pragma unroll
      for(int j=0;j<P;j++){
#pragma clang fp contract(off)
        float dx=px[j]-lx, dy=py[j]-ly, dz=pz[j]-lz;
        float d2=dx*dx+dy*dy+dz*dz;
        float mv=mind[j]; if(d2<mv) mv=d2; mind[j]=mv;
        if(mv>bv){ bv=mv; bi=tid+j*256; }
      }
      unsigned int hi=__float_as_uint(bv);
      unsigned int lo=0xFFFFFFFFu-(unsigned)bi;
#define DPPSTEP(CTRL) { \
      unsigned int shi=(unsigned)__builtin_amdgcn_update_dpp(0,(int)hi,CTRL,0xF,0xF,true); \
      unsigned int slo=(unsigned)__builtin_amdgcn_update_dpp(0,(int)lo,CTRL,0xF,0xF,true); \
      bool g=(shi>hi)||(shi==hi&&slo>lo); \
      hi=g?shi:hi; lo=g?slo:lo; }
      DPPSTEP(0x111) DPPSTEP(0x112) DPPSTEP(0x114) DPPSTEP(0x118) DPPSTEP(0x142) DPPSTEP(0x143)
#undef DPPSTEP
      if((tid&63)==63)
        keyS[it&1][w]=((unsigned long long)hi<<32)|lo;
      __syncthreads();
      unsigned long long k0=keyS[it&1][0], k1=keyS[it&1][1];
      unsigned long long k2=keyS[it&1][2], k3=keyS[it&1][3];
      unsigned long long ka = k0>k1?k0:k1;
      unsigned long long kb = k2>k3?k2:k3;
      unsigned long long kk = ka>kb?ka:kb;
      int wi = (int)(0xFFFFFFFFu - (unsigned)(kk & 0xFFFFFFFFull));
      float4 wc = ptsS[wi];
      lx=wc.x; ly=wc.y; lz=wc.z;
      if(tid==0){ anc[3*it]=lx; anc[3*it+1]=ly; anc[3*it+2]=lz; }
    }
  } else if(bid < fpsN + oN){
    int ob = bid - fpsN;
    if(isP0){
      int quarter = MO>>2;
      int tt = ob / quarter, rb = ob - tt*quarter;
      int sub = threadIdx.x>>6;
      int o = threadIdx.x&63;
      int row = rb*4 + sub;
      int b = row/mO, mm = row - b*mO;
      const float* A = XoutO + (size_t)b*aBSO + (size_t)tt*mO*3 + (size_t)mm*3;
      float ax=A[0], ay=A[1], az=A[2];
      float w0=0,w1=0,w2=0;
      if(o<midO){ w0=WdO[3*o]; w1=WdO[3*o+1]; w2=WdO[3*o+2]; }
      int fr=SO.fi[tt];
      int nmask=NO-1;
      const int* id = bqO + ((size_t)tt*MO + row)*9;
      const float* Pb = XinO + ((size_t)b*LinO+fr)*(size_t)NO*3;
      float acc=0.f;
      for(int k=0;k<9;k++){
        int p=id[k] & nmask;
        const float* q = Pb + (size_t)p*3;
        float dx=q[0]-ax, dy=q[1]-ay, dz=q[2]-az;
        acc += dx*w0+dy*w1+dz*w2;
      }
      if(o<midO) GoN[(size_t)tt*MO*ldO + (size_t)row*ldO + o] = (f16)acc;
    } else {
      int cw2 = cinO>>1; if(cw2>256) cw2=256;
      int rpb = 256/cw2;
      int tid=threadIdx.x;
      int sub=tid/cw2, lc=tid-sub*cw2;
      int r=ob*rpb+sub;
      int Kp=3*cinO;
      int nmask=NO-1;
      int s=r/MO, mrow=r-s*MO;
      int b=mrow/mO, mm=mrow-b*mO;
      int tt=SO.tt[s], fr=SO.fi[s];
      const float* A0=XoutO+(size_t)b*aBSO+(size_t)tt*mO*3+(size_t)mm*3;
      float ax=A0[0],ay=A0[1],az=A0[2];
      const float* Pb=XinO+((size_t)b*LinO+fr)*(size_t)NO*3;
      const f16* Fb=featsO+(((size_t)b*LinO+fr)*(size_t)NO)*(size_t)cinO;
      const int* id=bqO+(size_t)r*9;
      int idx[9]; float d0[9],d1[9],d2a[9];
#pragma unroll
      for(int k=0;k<9;k++){
        int p=id[k]&nmask; idx[k]=p;
        const float* q=Pb+(size_t)p*3;
        d0[k]=q[0]-ax; d1[k]=q[1]-ay; d2a[k]=q[2]-az;
      }
      f16* Gr=GoN+(size_t)r*Kp;
      for(int cc=2*lc; cc<cinO; cc+=2*cw2){
        float a0=0,a1=0,a2=0,b0=0,b1=0,b2=0;
#pragma unroll
        for(int k=0;k<9;k++){
          f16x2 fv=*(const f16x2*)(Fb+(size_t)idx[k]*cinO+cc);
          float f0=(float)fv[0], f1=(float)fv[1];
          a0=fmaf(d0[k],f0,a0); b0=fmaf(d0[k],f1,b0);
          a1=fmaf(d1[k],f0,a1); b1=fmaf(d1[k],f1,b1);
          a2=fmaf(d2a[k],f0,a2); b2=fmaf(d2a[k],f1,b2);
        }
        f16x2 o0={(f16)a0,(f16)b0}, o1={(f16)a1,(f16)b1}, o2={(f16)a2,(f16)b2};
        *(f16x2*)(Gr+cc)=o0; *(f16x2*)(Gr+cinO+cc)=o1; *(f16x2*)(Gr+2*cinO+cc)=o2;
      }
    }
  } else {
    int fb=bid-fpsN-oN;
    int s=fb/(32*chunksB);
    int rem=fb-s*(32*chunksB);
    int b=rem/chunksB;
    int a=(rem-b*chunksB)*256+threadIdx.x;
    int tt=SB.tt[s], fr=SB.fi[s];
    const float* Pb = XinB + ((size_t)b*LinB + fr)*(size_t)NB*3;
    bool act = a<mB;
    float ax=0,ay=0,az=0;
    int* o = bqOut + ((size_t)s*MB + (size_t)b*mB + (size_t)(act?a:0))*9;
    if(act){
      const float* A=XoutB+(size_t)b*aBSB+(size_t)tt*mB*3+(size_t)a*3;
      ax=A[0]; ay=A[1]; az=A[2];
    }
    int cnt = act?0:9, first=0;
    for(int base=0; base<NB; base+=256){
      for(int t=threadIdx.x; t<768; t+=256) sp[t]=Pb[(size_t)base*3+t];
      __syncthreads();
      for(int q=0;q<256;q++){
#pragma clang fp contract(off)
        float dx=sp[3*q]-ax, dy=sp[3*q+1]-ay, dz=sp[3*q+2]-az;
        float d2=dx*dx+dy*dy+dz*dz;
        if(d2<r2B && cnt<9){
          int p=base+q;
          if(cnt==0) first=p;
          o[cnt]=p; cnt++;
        }
      }
      if(__syncthreads_and(cnt>=9)) break;
    }
    if(act){ for(int k=cnt;k<9;k++) o[k]=first; }
  }
}

// ---------------------------------------------------------------- G[r, a*cin+c] standalone (layer 5 only)
__global__ __launch_bounds__(256) void k_outer(
    const f16* __restrict__ feats, const float* __restrict__ Xin,
    const float* __restrict__ Xout, const int* __restrict__ bqAll,
    f16* __restrict__ Gh, int m, int cin, int N, int Lin,
    size_t aBS, int nmask, int M, Sched S)
{
  int cw2 = cin>>1; if(cw2>256) cw2=256;
  int rpb = 256/cw2;
  int tid=threadIdx.x;
  int sub=tid/cw2, lc=tid-sub*cw2;
  int r=blockIdx.x*rpb+sub;
  int Kp=3*cin;
  int s=r/M, mrow=r-s*M;
  int b=mrow/m, mm=mrow-b*m;
  int tt=S.tt[s], fr=S.fi[s];
  const float* A0=Xout+(size_t)b*aBS+(size_t)tt*m*3+(size_t)mm*3;
  float ax=A0[0],ay=A0[1],az=A0[2];
  const float* Pb=Xin+((size_t)b*Lin+fr)*(size_t)N*3;
  const f16* Fb=feats+(((size_t)b*Lin+fr)*(size_t)N)*(size_t)cin;
  const int* id=bqAll+(size_t)r*9;
  int idx[9]; float d0[9],d1[9],d2a[9];
#pragma unroll
  for(int k=0;k<9;k++){
    int p=id[k]&nmask; idx[k]=p;
    const float* q=Pb+(size_t)p*3;
    d0[k]=q[0]-ax; d1[k]=q[1]-ay; d2a[k]=q[2]-az;
  }
  f16* Gr=Gh+(size_t)r*Kp;
  for(int cc=2*lc; cc<cin; cc+=2*cw2){
    float a0=0,a1=0,a2=0,b0=0,b1=0,b2=0;
#pragma unroll
    for(int k=0;k<9;k++){
      f16x2 fv=*(const f16x2*)(Fb+(size_t)idx[k]*cin+cc);
      float f0=(float)fv[0], f1=(float)fv[1];
      a0=fmaf(d0[k],f0,a0); b0=fmaf(d0[k],f1,b0);
      a1=fmaf(d1[k],f0,a1); b1=fmaf(d1[k],f1,b1);
      a2=fmaf(d2a[k],f0,a2); b2=fmaf(d2a[k],f1,b2);
    }
    f16x2 o0={(f16)a0,(f16)b0}, o1={(f16)a1,(f16)b1}, o2={(f16)a2,(f16)b2};
    *(f16x2*)(Gr+cc)=o0; *(f16x2*)(Gr+cin+cc)=o1; *(f16x2*)(Gr+2*cin+cc)=o2;
  }
}

// ---------------------------------------------------------------- pair GEMM + fused BN stats (round-15)
// nf[tt][mrow, j*mid+col] = G @ W2^T; per-column sums of the f16-rounded
// stored values are reduced in-register (quad butterfly via shfl_xor 16/32)
// and atomically accumulated -> replaces k_bnstat for l>=1. Summation is over
// exactly the written (tt,j) slices, matching the old jmask semantics.
__global__ __launch_bounds__(256) void k_pg(
    const f16* __restrict__ Gh, const f16* __restrict__ W2,
    f16* __restrict__ nfh, int Kp, int mid, int C, int M, Sched S,
    float* __restrict__ sumsL, int sumStride)
{
  __shared__ f16 As[128*40];
  __shared__ f16 Bs[128*40];
  int tid=threadIdx.x;
  int lane=tid&63, w=tid>>6;
  int quad=lane>>4, l15=lane&15;
  int rowOff=(w>>1)*64, colOff=(w&1)*64;
  int rowBase=blockIdx.x*128, colBase=blockIdx.y*128;
  f32x4 acc[4][4];
#pragma unroll
  for(int i=0;i<4;i++)
#pragma unroll
    for(int j=0;j<4;j++) acc[i][j]=(f32x4){0.f,0.f,0.f,0.f};
  int nct=Kp>>5;
  int srow=tid>>1, shalf=tid&1;
  for(int ct=0;ct<nct;ct++){
    __syncthreads();
    {
      const uint4* s=(const uint4*)(Gh+(size_t)(rowBase+srow)*Kp+(ct<<5)+(shalf<<4));
      uint4 u0=s[0], u1=s[1];
      *(uint4*)(As + srow*40 + (shalf<<4))     = u0;
      *(uint4*)(As + srow*40 + (shalf<<4) + 8) = u1;
    }
    {
      const uint4* s=(const uint4*)(W2+(size_t)(colBase+srow)*Kp+(ct<<5)+(shalf<<4));
      uint4 u0=s[0], u1=s[1];
      *(uint4*)(Bs + srow*40 + (shalf<<4))     = u0;
      *(uint4*)(Bs + srow*40 + (shalf<<4) + 8) = u1;
    }
    __syncthreads();
    f16x8 af[4], bf4[4];
#pragma unroll
    for(int rt=0;rt<4;rt++) af[rt]=*(const f16x8*)(As + (rowOff+rt*16+l15)*40 + quad*8);
#pragma unroll
    for(int ctl=0;ctl<4;ctl++) bf4[ctl]=*(const f16x8*)(Bs + (colOff+ctl*16+l15)*40 + quad*8);
#pragma unroll
    for(int rt=0;rt<4;rt++)
#pragma unroll
      for(int ctl=0;ctl<4;ctl++)
        acc[rt][ctl]=__builtin_amdgcn_mfma_f32_16x16x32_f16(af[rt],bf4[ctl],acc[rt][ctl],0,0,0);
  }
  // block is within one slot (M multiple of 128)
  int s0=rowBase/M;
  int tt0=S.tt[s0], j0=S.jj[s0];
  // fused BN stats on the f16-rounded values
#pragma unroll
  for(int ctl=0;ctl<4;ctl++){
    int gcol=colBase+colOff+ctl*16+l15;
    float cs=0.f, cq=0.f;
#pragma unroll
    for(int rt=0;rt<4;rt++)
#pragma unroll
      for(int r=0;r<4;r++){
        float v=(float)(f16)acc[rt][ctl][r];
        cs+=v; cq+=v*v;
      }
    cs+=__shfl_xor(cs,16); cq+=__shfl_xor(cq,16);
    cs+=__shfl_xor(cs,32); cq+=__shfl_xor(cq,32);
    if(quad==0 && gcol<mid){
      atomicAdd(&sumsL[tt0*sumStride + j0*mid + gcol], cs);
      atomicAdd(&sumsL[tt0*sumStride + C + j0*mid + gcol], cq);
    }
  }
#pragma unroll
  for(int rt=0;rt<4;rt++){
#pragma unroll
    for(int r=0;r<4;r++){
      int row=rowBase+rowOff+rt*16+quad*4+r;
      int s=row/M, mrow=row-s*M;
      int tt=S.tt[s], j=S.jj[s];
      f16* base = nfh + (size_t)tt*M*C + (size_t)mrow*C + j*mid;
#pragma unroll
      for(int ctl=0;ctl<4;ctl++){
        int col=colBase+colOff+ctl*16+l15;
        if(col<mid) base[col]=(f16)acc[rt][ctl][r];
      }
    }
  }
}

// ---------------------------------------------------------------- BN stats (layer 0 only: part0-written nfh)
__global__ void k_bnstat(const f16* __restrict__ nfh, int M, int C, float* __restrict__ sumsL,
                         int mid, int4 jm, int sumStride){
  int c = blockIdx.x*256 + threadIdx.x;
  if(c>=C) return;
  int tt=blockIdx.z;
  int jmask = (tt==0)?jm.x:(tt==1)?jm.y:(tt==2)?jm.z:jm.w;
  int j=c/mid;
  if(!((jmask>>j)&1)) return;
  const f16* base=nfh+(size_t)tt*M*C;
  int rows = M>>5;
  int r0 = blockIdx.y*rows, r1 = r0+rows;
  float s=0.f, s2=0.f;
  for(int r=r0;r<r1;r++){
    float v=(float)base[(size_t)r*C+c];
    s+=v; s2+=v*v;
  }
  atomicAdd(&sumsL[tt*sumStride+c], s);
  atomicAdd(&sumsL[tt*sumStride+C+c], s2);
}

// ---------------------------------------------------------------- MFMA GEMM, BN finalize fused (round-15)
// BNA path: converts raw (sum, sum2) -> (rs, b) cooperatively into LDS at
// block start (replaces k_bnfin). sum2==0 => rs=0 reproduces the old jmask
// zeroing (unwritten slices have exactly-zero sums; garbage*0 killed by fmaxf).
template<bool RELU, bool DYN, bool BNA>
__global__ __launch_bounds__(256) void k_gemm_mfma(
    const f16* __restrict__ Ag, const f16* __restrict__ Bh,
    const float* __restrict__ bias, void* __restrict__ out,
    int K, int N, int mloc, size_t oBS, size_t ttA, size_t ttO,
    const int* __restrict__ oflag, const float* __restrict__ sumsAll, int sumStride, float invM)
{
  __shared__ f16 As[128*40];
  __shared__ f16 Bs[128*40];
  __shared__ float scbL[BNA?2*2304:2];
  int tid=threadIdx.x;
  int lane=tid&63, w=tid>>6;
  int quad=lane>>4, l15=lane&15;
  int rowOff=(w>>1)*64, colOff=(w&1)*64;
  int rowBase=blockIdx.x*128, colBase=blockIdx.y*128;
  int tt=blockIdx.z;
  const f16* A0=Ag+(size_t)tt*ttA;
  if(BNA){
    const float* sm=sumsAll+(size_t)tt*sumStride;
    for(int c=tid;c<K;c+=256){
      float s1=sm[c], s2=sm[K+c];
      float mean=s1*invM;
      float var=s2*invM-mean*mean; if(var<0.f) var=0.f;
      float rs=(s2==0.f)?0.f:(1.0f/sqrtf(var+1e-5f));
      scbL[c]=rs; scbL[K+c]=-mean*rs;
    }
  }
  f32x4 acc[4][4];
#pragma unroll
  for(int i=0;i<4;i++)
#pragma unroll
    for(int j=0;j<4;j++) acc[i][j]=(f32x4){0.f,0.f,0.f,0.f};
  int nct=K>>5;
  int srow=tid>>1, shalf=tid&1;
  for(int ct=0;ct<nct;ct++){
    __syncthreads();
    {
      int c0g=(ct<<5)+(shalf<<4);
      const f16* src=A0+(size_t)(rowBase+srow)*K+c0g;
      if(BNA){
        f16x8 x0=((const f16x8*)src)[0], x1=((const f16x8*)src)[1];
        f16x8 h0,h1;
#pragma unroll
        for(int q=0;q<8;q++){
          h0[q]=(f16)fmaxf(fmaf((float)x0[q],scbL[c0g+q],scbL[K+c0g+q]),0.f);
          h1[q]=(f16)fmaxf(fmaf((float)x1[q],scbL[c0g+8+q],scbL[K+c0g+8+q]),0.f);
        }
        *(f16x8*)(As+srow*40+(shalf<<4))=h0;
        *(f16x8*)(As+srow*40+(shalf<<4)+8)=h1;
      } else {
        const uint4* s=(const uint4*)src;
        uint4 u0=s[0],u1=s[1];
        *(uint4*)(As+srow*40+(shalf<<4))=u0;
        *(uint4*)(As+srow*40+(shalf<<4)+8)=u1;
      }
    }
    {
      const uint4* s=(const uint4*)(Bh+(size_t)(colBase+srow)*K+(ct<<5)+(shalf<<4));
      uint4 u0=s[0], u1=s[1];
      *(uint4*)(Bs + srow*40 + (shalf<<4))     = u0;
      *(uint4*)(Bs + srow*40 + (shalf<<4) + 8) = u1;
    }
    __syncthreads();
    f16x8 af[4], bf4[4];
#pragma unroll
    for(int rt=0;rt<4;rt++) af[rt]=*(const f16x8*)(As + (rowOff+rt*16+l15)*40 + quad*8);
#pragma unroll
    for(int ctl=0;ctl<4;ctl++) bf4[ctl]=*(const f16x8*)(Bs + (colOff+ctl*16+l15)*40 + quad*8);
#pragma unroll
    for(int rt=0;rt<4;rt++)
#pragma unroll
      for(int ctl=0;ctl<4;ctl++)
        acc[rt][ctl]=__builtin_amdgcn_mfma_f32_16x16x32_f16(af[rt],bf4[ctl],acc[rt][ctl],0,0,0);
  }
  bool f32m = DYN ? (*oflag!=0) : true;
#pragma unroll
  for(int rt=0;rt<4;rt++){
#pragma unroll
    for(int r=0;r<4;r++){
      int row=rowBase+rowOff+rt*16+quad*4+r;
      int rb=row/mloc, rm=row-rb*mloc;
      size_t obase=(size_t)rb*oBS + (size_t)tt*ttO + (size_t)rm*N;
#pragma unroll
      for(int ctl=0;ctl<4;ctl++){
        int col=colBase+colOff+ctl*16+l15;
        float v=acc[rt][ctl][r];
        if(bias) v+=bias[col];
        if(RELU) v=fmaxf(v,0.f);
        if(DYN){
          if(!f32m) ((bf16*)out)[obase+col]=__float2bfloat16(v);
          else      ((float*)out)[obase+col]=v;
        } else {
          ((f16*)out)[obase+col]=(f16)v;
        }
      }
    }
  }
}

// ---------------------------------------------------------------- f32 GEMM (layer 0 temporal, K=45), BN finalize fused
__global__ __launch_bounds__(256) void k_gemm0(
    const f16* __restrict__ nfh, const float* __restrict__ Wg,
    f16* __restrict__ out, int M, int K, int N, int mloc, size_t oBS, size_t ttO,
    const float* __restrict__ sumsAll, int sumStride, float invM)
{
  __shared__ alignas(16) float As[16][64];
  __shared__ alignas(16) float Bs[16][64];
  __shared__ float scbL[128];
  int tid=threadIdx.x, tx=tid&15, ty=tid>>4;
  int rowBase=blockIdx.x*64, colBase=blockIdx.y*64;
  int tt=blockIdx.z;
  const f16* A0=nfh+(size_t)tt*M*K;
  {
    const float* sm=sumsAll+(size_t)tt*sumStride;
    for(int c=tid;c<K;c+=256){
      float s1=sm[c], s2=sm[K+c];
      float mean=s1*invM;
      float var=s2*invM-mean*mean; if(var<0.f) var=0.f;
      float rs=(s2==0.f)?0.f:(1.0f/sqrtf(var+1e-5f));
      scbL[c]=rs; scbL[K+c]=-mean*rs;
    }
  }
  float acc[4][4];
#pragma unroll
  for(int i=0;i<4;i++)
#pragma unroll
    for(int j=0;j<4;j++) acc[i][j]=0.f;
  int lrow=tid&63, lcq=tid>>6;
  int nct=(K+15)>>4;
  for(int ct=0;ct<nct;ct++){
    __syncthreads();
    {
      int r=rowBase+lrow, c0=(ct<<4)+(lcq<<2);
#pragma unroll
      for(int q=0;q<4;q++){
        int c=c0+q;
        As[(lcq<<2)+q][lrow] = (c<K)? fmaxf(fmaf((float)A0[(size_t)r*K+c],scbL[c],scbL[K+c]),0.f) : 0.f;
      }
    }
    {
      int og=colBase+lrow, c0=(ct<<4)+(lcq<<2);
#pragma unroll
      for(int q=0;q<4;q++){
        int c=c0+q;
        Bs[(lcq<<2)+q][lrow] = (c<K)? Wg[(size_t)og*K+c] : 0.f;
      }
    }
    __syncthreads();
#pragma unroll
    for(int c=0;c<16;c++){
      float4 a4=*(const float4*)&As[c][ty<<2];
      float av[4]={a4.x,a4.y,a4.z,a4.w};
      float4 b4=*(const float4*)&Bs[c][tx<<2];
      float bw[4]={b4.x,b4.y,b4.z,b4.w};
#pragma unroll
      for(int i=0;i<4;i++)
#pragma unroll
        for(int j=0;j<4;j++) acc[i][j]+=av[i]*bw[j];
    }
  }
#pragma unroll
  for(int i=0;i<4;i++){
    int r=rowBase+(ty<<2)+i;
    int rb=r/mloc, rm=r-rb*mloc;
    size_t obase=(size_t)rb*oBS + (size_t)blockIdx.z*ttO + (size_t)rm*N;
#pragma unroll
    for(int j=0;j<4;j++){
      int o=colBase+(tx<<2)+j;
      out[obase+o]=(f16)fmaxf(acc[i][j],0.f);
    }
  }
}

// ---------------------------------------------------------------- host
extern "C" void kernel_launch(void* const* d_in, const int* in_sizes, int n_in,
                              void* d_out, int out_size, void* d_ws, size_t ws_size,
                              hipStream_t stream) {
  (void)in_sizes; (void)n_in; (void)out_size; (void)ws_size;

  const int di[6] = {2,4,7,10,13,16};
  const int fi6[6] = {-1,5,8,11,14,17};
  const int ti[6] = {3,6,9,12,15,18};

  const int midv[6]={45,96,192,384,768,1536};
  const int midp[6]={0,128,256,384,768,1536};
  const int cinv[6]={0,64,128,256,512,1024};
  const int coutv[6]={64,128,256,512,1024,2048};
  const int tkv[6]={1,3,3,3,3,1};
  const int Nv[6]={2048,1024,512,512,256,256};
  const int mv[6]={1024,512,512,256,256,128};
  const int Lv[6]={4,4,2,2,1,1};
  const int Tv[6]={4,2,2,1,1,1};
  const float rrv[6]={1.5f,3.f,3.f,6.f,6.f,6.f};

  float* ws=(float*)d_ws;
  size_t off=0;
  auto A=[&](size_t n)->float*{ float* p=ws+off; off+=(n+63)&~(size_t)63; return p; };
  auto Ah=[&](size_t n)->f16*{ return (f16*)A((n+1)/2); };

  int* flag=(int*)A(64);

  f16* W2h[6]; W2h[0]=nullptr;
  for(int l=1;l<6;l++) W2h[l]=Ah((size_t)midp[l]*3*cinv[l]);
  f16* Wth[6]; Wth[0]=nullptr;
  for(int l=1;l<6;l++) Wth[l]=Ah((size_t)coutv[l]*tkv[l]*midv[l]);
  float* Wd0=A(135);
  float* Wt0=A(2880);
  f16* fcwh=Ah(2097152);
  float* fcb=A(1024);

  float* X[7];
  X[0]=A(786432);
  for(int l=0;l<6;l++) X[l+1]=A((size_t)32*Tv[l]*mv[l]*3);

  f16* FA=Ah(8388608);
  f16* FB=Ah(8388608);
  f16* F[7]; F[0]=nullptr;
  for(int l=0;l<6;l++) F[l+1]=(l%2==0)?FA:FB;

  f16* nfh=Ah(18874368);           // max T*M*C (l2/l4: 18.87M)
  float* sumsAll=A(11*4608);
  f16* Gh=Ah(25165824);            // max SLOTS*M*Kp (l2: 25.2M)
  int* bqA=(int*)A(1179648);       // double-buffered bq indices (parity by layer)
  int* bqB=(int*)A(1179648);
  int* bqBuf[2]={bqA,bqB};

  // ---- setup: detect+zero (fused) + f32 converts (2 dispatches)
  {
    int zn=11*4608;
    int zb=(zn+255)/256;
    k_detect<<<dim3(1+zb),dim3(256),0,stream>>>((const unsigned int*)d_in[0], 4096, flag, sumsAll, zn);
  }
  {
    CvtF32 J;
    J.src[0]=d_in[0];  J.dst[0]=X[0];  J.n[0]=786432;
    J.src[1]=d_in[3];  J.dst[1]=Wt0;   J.n[1]=2880;
    J.src[2]=d_in[20]; J.dst[2]=fcb;   J.n[2]=1024;
    J.src[3]=d_in[2];  J.dst[3]=Wd0;   J.n[3]=135;
    J.blk0[0]=0; J.blk0[1]=3072; J.blk0[2]=3084; J.blk0[3]=3088; J.blk0[4]=3089;
    k_cvt_all<<<dim3(3089),dim3(256),0,stream>>>(J,flag);
  }

  // f16 converts + W2 built as structs, executed inside the FPS_0 launch
  CvtF16 J16; int bp16=0;
  {
    int ns[6]={36864,147456,589824,2359296,3145728,2097152};
    const void* ss[6]={d_in[ti[1]],d_in[ti[2]],d_in[ti[3]],d_in[ti[4]],d_in[ti[5]],d_in[19]};
    f16* ds[6]={Wth[1],Wth[2],Wth[3],Wth[4],Wth[5],fcwh};
    for(int j2=0;j2<6;j2++){ J16.src[j2]=ss[j2]; J16.dst[j2]=ds[j2]; J16.n[j2]=ns[j2]; J16.blk0[j2]=bp16; bp16+=(ns[j2]+255)/256; }
    J16.blk0[6]=bp16;
  }
  W2J JW; int bpw2=0;
  {
    for(int l=1;l<6;l++){
      int j2=l-1;
      JW.wd[j2]=d_in[di[l]]; JW.wf[j2]=d_in[fi6[l]]; JW.dst[j2]=W2h[l];
      JW.mid[j2]=midv[l]; JW.cin[j2]=cinv[l]; JW.n[j2]=midp[l]*3*cinv[l];
      JW.blk0[j2]=bpw2; bpw2+=(JW.n[j2]+255)/256;
    }
    JW.blk0[5]=bpw2;
  }

  // ---- schedule tables
  const int SLOTS[6]={4,5,4,2,1,1};
  const int sTT[6][5]={{0,1,2,3,0},{0,0,1,1,1},{0,0,1,1,0},{0,0,0,0,0},{0,0,0,0,0},{0,0,0,0,0}};
  const int sFI[6][5]={{0,1,2,3,0},{0,1,1,2,3},{0,1,0,1,0},{0,1,0,0,0},{0,0,0,0,0},{0,0,0,0,0}};
  const int sJJ[6][5]={{0,0,0,0,0},{1,2,0,1,2},{1,2,0,1,0},{1,2,0,0,0},{1,0,0,0,0},{0,0,0,0,0}};
  const int4 jm4l0={1,1,1,1};
  const int Tcenters[6][4]={{0,1,2,3},{0,2,0,0},{0,1,0,0},{0,0,0,0},{0,0,0,0},{0,0,0,0}};
  const int slotBase[6]={0,4,6,8,9,10};

  Sched Sl[6];
  for(int l=0;l<6;l++)
    for(int s=0;s<5;s++){ Sl[l].tt[s]=sTT[l][s]; Sl[l].fi[s]=sFI[l][s]; Sl[l].jj[s]=sJJ[l][s]; }

  auto bqGeo=[&](int lb, int& bqN, int& chunks){
    chunks=(mv[lb]+255)>>8;
    bqN=SLOTS[lb]*32*chunks;
  };

  // FPS_0 merged with weight converts
  k_fps0m<<<dim3((unsigned)(128+bp16+bpw2)),dim3(256),0,stream>>>(X[0],X[1],J16,JW,flag,bp16);

  // pre-loop merged: [FPS_1 || bq_0 -> bqA]
  {
    int bqN,chunks; bqGeo(0,bqN,chunks);
    int fpsN=32*Tv[1];
    k_mega<4><<<dim3((unsigned)(fpsN+bqN)),dim3(256),0,stream>>>(
        X[1],Lv[1],Nv[1],mv[1],Tcenters[1][0],Tcenters[1][1],Tcenters[1][2],Tcenters[1][3],Tv[1],X[2],fpsN,
        0,0, FA,X[0],X[1],bqA,nfh,mv[0],1,Nv[0],Lv[0],(size_t)Tv[0]*mv[0]*3,32*mv[0],Sl[0],Wd0,1,1,
        X[0],X[1],bqBuf[0],Nv[0],mv[0],rrv[0]*rrv[0],Lv[0],(size_t)Tv[0]*mv[0]*3,32*mv[0],Sl[0],chunks);
  }

  for(int l=0;l<6;l++){
    int N=Nv[l], m=mv[l], Lin=Lv[l], T=Tv[l], cin=cinv[l], mid=midv[l];
    int C=tkv[l]*midv[l], M=32*m, cout=coutv[l];
    size_t aBS=(size_t)T*m*3;
    float* sumsL=sumsAll+(size_t)slotBase[l]*4608;

    if(l<5){
      // merged: [FPS_{l+2} (if l<=3) || outer_l/part0_l (reads bqBuf[l&1]) || bq_{l+1} -> bqBuf[(l+1)&1]]
      int lb=l+1;
      int bqN,chunksB; bqGeo(lb,bqN,chunksB);
      size_t aBSB=(size_t)Tv[lb]*mv[lb]*3;
      int MB=32*mv[lb];
      int oN, isP0;
      if(l==0){ isP0=1; oN=M; }
      else{
        isP0=0;
        int cw2=cin>>1; if(cw2>256) cw2=256;
        int rpb=256/cw2;
        oN=SLOTS[l]*M/rpb;
      }
      const f16* featsO=(l==0)?FA:F[l];
      f16* GoN=(l==0)?nfh:Gh;
      int fpsN=0, lf=l+2;
      if(lf<=5) fpsN=32*Tv[lf];
      int a0=0,a1=0,a2=0,a3=0;
      if(lf<=5){ a0=Tcenters[lf][0]; a1=Tcenters[lf][1]; a2=Tcenters[lf][2]; a3=Tcenters[lf][3]; }
      const float* xyzF=(lf<=5)?X[lf]:X[5];
      float* ancOut=(lf<=5)?X[lf+1]:X[6];
      int Lf=(lf<=5)?Lv[lf]:1, Nf=(lf<=5)?Nv[lf]:256, mf=(lf<=5)?mv[lf]:1, Tf=(lf<=5)?Tv[lf]:1;
      dim3 g((unsigned)(fpsN+oN+bqN)), blk(256);
      if(lf<=5 && Nv[lf]==512)
        k_mega<2><<<g,blk,0,stream>>>(xyzF,Lf,Nf,mf,a0,a1,a2,a3,Tf,ancOut,fpsN,
            oN,isP0, featsO,X[l],X[l+1],bqBuf[l&1],GoN,m,cin,N,Lin,aBS,M,Sl[l],Wd0,mid,C,
            X[lb],X[lb+1],bqBuf[lb&1],Nv[lb],mv[lb],rrv[lb]*rrv[lb],Lv[lb],aBSB,MB,Sl[lb],chunksB);
      else
        k_mega<1><<<g,blk,0,stream>>>(xyzF,Lf,Nf,mf,a0,a1,a2,a3,Tf,ancOut,fpsN,
            oN,isP0, featsO,X[l],X[l+1],bqBuf[l&1],GoN,m,cin,N,Lin,aBS,M,Sl[l],Wd0,mid,C,
            X[lb],X[lb+1],bqBuf[lb&1],Nv[lb],mv[lb],rrv[lb]*rrv[lb],Lv[lb],aBSB,MB,Sl[lb],chunksB);
    } else {
      // l==5: outer standalone (reads bqBuf[1])
      int cw2=cin>>1; if(cw2>256) cw2=256;
      int rpb=256/cw2;
      k_outer<<<dim3((unsigned)(SLOTS[l]*M/rpb)),256,0,stream>>>(
          F[l],X[l],X[l+1],bqBuf[l&1],Gh,m,cin,N,Lin,aBS,N-1,M,Sl[l]);
    }

    if(l>=1)
      k_pg<<<dim3((unsigned)(SLOTS[l]*M/128),(unsigned)(midp[l]/128)),256,0,stream>>>(
          Gh,W2h[l],nfh,3*cin,mid,C,M,Sl[l],sumsL,4608);
    else
      k_bnstat<<<dim3((C+255)/256,32,T),256,0,stream>>>(nfh,M,C,sumsL,mid,jm4l0,4608);

    size_t oBS=(size_t)T*m*cout;
    size_t ttO=(size_t)m*cout;
    float invM=1.0f/(float)M;
    if(l==0)
      k_gemm0<<<dim3(M/64,1,4),256,0,stream>>>(nfh,Wt0,F[1],M,C,cout,m,oBS,ttO,sumsL,4608,invM);
    else if(l<5)
      k_gemm_mfma<true,false,true><<<dim3(M/128,cout/128,T),256,0,stream>>>(
          nfh,Wth[l],nullptr,F[l+1],C,cout,m,oBS,(size_t)M*C,ttO,nullptr,sumsL,4608,invM);
    else
      k_gemm_mfma<false,false,true><<<dim3(M/128,cout/128,T),256,0,stream>>>(
          nfh,Wth[l],nullptr,F[l+1],C,cout,m,oBS,(size_t)M*C,ttO,nullptr,sumsL,4608,invM);
  }

  // final FC (A=F[6] f16, contiguous 4096x2048) -> d_out (bf16 or f32 per flag)
  k_gemm_mfma<false,true,false><<<dim3(4096/128,1024/128,1),256,0,stream>>>(
      F[6],fcwh,fcb,d_out,2048,1024,128,(size_t)128*1024,0,0,flag,nullptr,0,0.f);
}